// Round 1
// 1726.302 us; speedup vs baseline: 1.1223x; 1.1223x over previous
//
#include <hip/hip_runtime.h>

#define E_EDGES 65536
#define N_NODES 4096

// ---- workspace layout (float offsets) ----
// [0,678)   w3j tensors, [678] C2, [679] C3  (reserve 1024)
#define WS_W     1024                       // E*64   w = x@Ww/8
#define WS_Y     (WS_W + E_EDGES*64)        // E*16   Y
#define WS_CNT   (WS_Y + E_EDGES*16)        // 4096 int
#define WS_OFF   (WS_CNT + N_NODES)         // 4096 int
#define WS_CUR   (WS_OFF + N_NODES)         // 4096 int
#define WS_SORT  (WS_CUR + N_NODES)         // E int
#define WS_A     (WS_SORT + E_EDGES)        // N*1024  node accumulator (eps folded)
#define WS_WLT   (WS_A + N_NODES*1024)      // 2*20480 Wl1^T | Wl2^T  [64][320]
// high-water: WS_WLT + 40960 = 9,556,992 floats ~= 38.2 MB

// key order: (0,0,0),(1,1,0),(2,2,0),(0,1,1),(1,0,1),(1,2,1),(2,1,1),(3,2,1),
//            (0,2,2),(1,1,2),(2,0,2),(2,2,2),(3,1,2),(2,1,3)
__constant__ int gK_L1[14] = {0,1,2,0,1,1,2,3,0,1,2,2,3,2};
__constant__ int gK_L2[14] = {0,1,2,1,0,2,1,2,2,1,0,2,1,1};
__constant__ int gK_L3[14] = {0,0,0,1,1,1,1,1,2,2,2,2,2,3};
__constant__ int gK_OFF[14]= {0,1,10,35,44,53,98,143,248,273,318,343,468,573};
__constant__ double gFact[8] = {1.,1.,2.,6.,24.,120.,720.,5040.};

// w3j offsets (compile-time)
#define O_W000 0
#define O_W110 1
#define O_W220 10
#define O_W011 35
#define O_W101 44
#define O_W121 53
#define O_W211 98
#define O_W321 143
#define O_W022 248
#define O_W112 273
#define O_W202 318
#define O_W222 343
#define O_W312 468
#define O_W213 573

__device__ double su2_cg(int j1,int j2,int j3,int m1,int m2,int m3){
  if (m3 != m1+m2) return 0.0;
  double pref = sqrt((double)(2*j3+1)*gFact[j3+j1-j2]*gFact[j3-j1+j2]*gFact[j1+j2-j3]/gFact[j1+j2+j3+1]);
  pref *= sqrt(gFact[j3+m3]*gFact[j3-m3]*gFact[j1-m1]*gFact[j1+m1]*gFact[j2-m2]*gFact[j2+m2]);
  double s=0.0;
  for(int k=0;k<=j1+j2-j3;k++){
    int d1=j1+j2-j3-k, d2=j1-m1-k, d3=j2+m2-k, d4=j3-j2+m1+k, d5=j3-j1-m2+k;
    if(d1<0||d2<0||d3<0||d4<0||d5<0) continue;
    double den=gFact[k]*gFact[d1]*gFact[d2]*gFact[d3]*gFact[d4]*gFact[d5];
    s += (k&1)? (-1.0/den) : (1.0/den);
  }
  return pref*s;
}

__device__ void fill_qmat(int l, double2* q){  // 7x7 row-major, rows=m-basis, cols=real-basis
  for(int i=0;i<49;i++){ q[i].x=0.0; q[i].y=0.0; }
  const double is2 = 0.7071067811865475244;
  for(int m=-l;m<0;m++){
    q[(l+m)*7+(l-m)].x = is2;     // q[l+m, l+|m|] = 1/sqrt2
    q[(l+m)*7+(l+m)].y = -is2;    // q[l+m, l-|m|] = -1j/sqrt2
  }
  q[l*7+l].x = 1.0;
  for(int m=1;m<=l;m++){
    double sg = (m&1)? -1.0 : 1.0;
    q[(l+m)*7+(l+m)].x = sg*is2;
    q[(l+m)*7+(l-m)].y = sg*is2;
  }
  double pr, pi;  // (-i)^l
  switch(l&3){ case 0: pr=1;pi=0;break; case 1: pr=0;pi=-1;break; case 2: pr=-1;pi=0;break; default: pr=0;pi=1;break; }
  for(int i=0;i<49;i++){
    double a=q[i].x, b=q[i].y;
    q[i].x = a*pr - b*pi;
    q[i].y = a*pi + b*pr;
  }
}

__global__ __launch_bounds__(128) void k_w3j(float* __restrict__ ws){
  __shared__ double2 q1[49], q2[49], q3[49];
  __shared__ double C[125], Cr[125];
  __shared__ double red[128];
  int bid = blockIdx.x, t = threadIdx.x;
  int l1=gK_L1[bid], l2=gK_L2[bid], l3=gK_L3[bid];
  int n1=2*l1+1, n2=2*l2+1, n3=2*l3+1, ntot=n1*n2*n3;
  if(t==0){
    fill_qmat(l1,q1); fill_qmat(l2,q2); fill_qmat(l3,q3);
    for(int i=0;i<49;i++) q3[i].y = -q3[i].y;   // conj
  }
  __syncthreads();
  for(int idx=t; idx<ntot; idx+=128){
    int a = idx/(n2*n3), r=idx%(n2*n3), b=r/n3, c=r%n3;
    C[idx] = su2_cg(l1,l2,l3, a-l1, b-l2, c-l3);
  }
  __syncthreads();
  for(int idx=t; idx<ntot; idx+=128){
    int i = idx/(n2*n3), r=idx%(n2*n3), j=r/n3, k=r%n3;
    double ar=0.0;
    for(int a=0;a<n1;a++) for(int b=0;b<n2;b++){
      double2 qa=q1[a*7+i], qb=q2[b*7+j];
      double pr = qa.x*qb.x - qa.y*qb.y;
      double pi = qa.x*qb.y + qa.y*qb.x;
      for(int c=0;c<n3;c++){
        double2 qc=q3[c*7+k];
        double tr = pr*qc.x - pi*qc.y;
        ar += tr*C[(a*n2+b)*n3+c];
      }
    }
    Cr[idx]=ar;
  }
  __syncthreads();
  double ss=0.0;
  for(int idx=t; idx<ntot; idx+=128) ss += Cr[idx]*Cr[idx];
  red[t]=ss; __syncthreads();
  for(int st=64; st>0; st>>=1){ if(t<st) red[t]+=red[t+st]; __syncthreads(); }
  double inv = 1.0/sqrt(red[0]);
  for(int idx=t; idx<ntot; idx+=128) ws[gK_OFF[bid]+idx] = (float)(Cr[idx]*inv);
}

__global__ void k_c2c3(float* __restrict__ ws){
  const float* w112 = ws + O_W112;
  const float* w213 = ws + O_W213;
  double u0=0.3, u1=-0.4, u2=sqrt(0.75);
  double s3=sqrt(3.0);
  double y1[3]={s3*u0, s3*u1, s3*u2};
  double y2r[5]={0,0,0,0,0};
  for(int i=0;i<3;i++) for(int j=0;j<3;j++) for(int k=0;k<5;k++)
    y2r[k] += y1[i]*y1[j]*(double)w112[(i*3+j)*5+k];
  double nn=0; for(int k=0;k<5;k++) nn += y2r[k]*y2r[k];
  double c2 = sqrt(5.0)/sqrt(nn);
  double y2[5]; for(int k=0;k<5;k++) y2[k]=c2*y2r[k];
  double y3r[7]={0,0,0,0,0,0,0};
  for(int i=0;i<5;i++) for(int j=0;j<3;j++) for(int n=0;n<7;n++)
    y3r[n] += y2[i]*y1[j]*(double)w213[(i*3+j)*7+n];
  nn=0; for(int n=0;n<7;n++) nn += y3r[n]*y3r[n];
  double c3 = sqrt(7.0)/sqrt(nn);
  ws[678]=(float)c2; ws[679]=(float)c3;
}

__global__ void k_zero(int* __restrict__ cnt){
  int i = blockIdx.x*256 + threadIdx.x;
  if(i < N_NODES) cnt[i]=0;
}
__global__ void k_count(const int* __restrict__ senders, int* __restrict__ cnt){
  int e = blockIdx.x*256 + threadIdx.x;
  if(e < E_EDGES) atomicAdd(&cnt[senders[e]], 1);
}
__global__ __launch_bounds__(1024) void k_scan(const int* __restrict__ cnt, int* __restrict__ off, int* __restrict__ cur){
  __shared__ int part[1024];
  int t = threadIdx.x;
  int c0=cnt[4*t], c1=cnt[4*t+1], c2=cnt[4*t+2], c3=cnt[4*t+3];
  int l0=0, l1=c0, l2=c0+c1, l3=c0+c1+c2;
  int sum=l3+c3;
  part[t]=sum; __syncthreads();
  for(int st=1; st<1024; st<<=1){
    int v = part[t];
    int add = (t>=st)? part[t-st] : 0;
    __syncthreads();
    part[t] = v + add;
    __syncthreads();
  }
  int pref = (t>0)? part[t-1] : 0;
  off[4*t]=pref+l0; off[4*t+1]=pref+l1; off[4*t+2]=pref+l2; off[4*t+3]=pref+l3;
  cur[4*t]=pref+l0; cur[4*t+1]=pref+l1; cur[4*t+2]=pref+l2; cur[4*t+3]=pref+l3;
}
__global__ void k_scatter(const int* __restrict__ senders, int* __restrict__ cur, int* __restrict__ sorted){
  int e = blockIdx.x*256 + threadIdx.x;
  if(e < E_EDGES){
    int pos = atomicAdd(&cur[senders[e]], 1);
    sorted[pos] = e;
  }
}

// transpose Wl1/Wl2 (320x64) -> [64][320] so phase-2 threads stream coalesced float4 rows
__global__ __launch_bounds__(256) void k_wlT(const float* __restrict__ Wl1, const float* __restrict__ Wl2,
                                             float* __restrict__ wlT){
  int idx = blockIdx.x*256 + threadIdx.x;      // 160 blocks * 256 = 40960
  int m = idx / 20480;
  int r = idx - m*20480;
  int v = r >> 6, u = r & 63;
  const float* W = m ? Wl2 : Wl1;
  wlT[m*20480 + u*320 + v] = W[v*64 + u];
}

// per edge: w = x@Ww/8 (lane=mul), Y[16] spherical harmonics
__global__ __launch_bounds__(256) void k_edge_pre(
    const float* __restrict__ vectors, const float* __restrict__ x,
    const float* __restrict__ Ww, float* __restrict__ ws){
  int wv = threadIdx.x >> 6, lane = threadIdx.x & 63;
  int e = blockIdx.x*4 + wv;
  const float* w112 = ws + O_W112;
  const float* w213 = ws + O_W213;
  float C2v = ws[678], C3v = ws[679];
  float v0=vectors[e*3], v1=vectors[e*3+1], v2=vectors[e*3+2];
  float len = sqrtf(v0*v0+v1*v1+v2*v2);
  float inv = 1.0f/(len + 1e-12f);
  float s3 = 1.7320508075688772f;
  float y1v[3] = { s3*v0*inv, s3*v1*inv, s3*v2*inv };
  float y2[5];
  #pragma unroll
  for(int k=0;k<5;k++){
    float a=0.f;
    #pragma unroll
    for(int i=0;i<3;i++)
      #pragma unroll
      for(int j=0;j<3;j++) a += y1v[i]*y1v[j]*w112[(i*3+j)*5+k];
    y2[k]=C2v*a;
  }
  float y3[7];
  #pragma unroll
  for(int n=0;n<7;n++){
    float a=0.f;
    #pragma unroll
    for(int i=0;i<5;i++)
      #pragma unroll
      for(int j=0;j<3;j++) a += y2[i]*y1v[j]*w213[(i*3+j)*7+n];
    y3[n]=C3v*a;
  }
  // w
  float acc=0.f;
  for(int k=0;k<64;k++) acc += x[e*64+k]*Ww[k*64+lane];
  ws[WS_W + e*64 + lane] = acc*0.125f;
  if(lane==0){
    float* Yp = ws + WS_Y + e*16;
    Yp[0]=1.0f;
    Yp[1]=y1v[0]; Yp[2]=y1v[1]; Yp[3]=y1v[2];
    Yp[4]=y2[0]; Yp[5]=y2[1]; Yp[6]=y2[2]; Yp[7]=y2[3]; Yp[8]=y2[4];
    Yp[9]=y3[0]; Yp[10]=y3[1]; Yp[11]=y3[2]; Yp[12]=y3[3]; Yp[13]=y3[4]; Yp[15]=y3[6]; Yp[14]=y3[5];
  }
}

// per node: A[n][m][k] = eps * sum_e w[e][m]*Y[e][k]
__global__ __launch_bounds__(64) void k_node_acc(
    const float* __restrict__ ws_w, const float* __restrict__ ws_y,
    const int* __restrict__ sorted, const int* __restrict__ off, const int* __restrict__ cnt,
    float* __restrict__ A){
  int n = blockIdx.x, m = threadIdx.x;
  float acc[16];
  #pragma unroll
  for(int k=0;k<16;k++) acc[k]=0.f;
  int o = off[n], c = cnt[n];
  for(int j=0;j<c;j++){
    int e = sorted[o+j];
    float wm = ws_w[e*64+m];
    const float* Yp = ws_y + e*16;
    #pragma unroll
    for(int k=0;k<16;k++) acc[k] += wm*Yp[k];
  }
  float4* outp = (float4*)(A + n*1024 + m*16);
  outp[0] = make_float4(acc[0]*0.25f, acc[1]*0.25f, acc[2]*0.25f, acc[3]*0.25f);
  outp[1] = make_float4(acc[4]*0.25f, acc[5]*0.25f, acc[6]*0.25f, acc[7]*0.25f);
  outp[2] = make_float4(acc[8]*0.25f, acc[9]*0.25f, acc[10]*0.25f, acc[11]*0.25f);
  outp[3] = make_float4(acc[12]*0.25f, acc[13]*0.25f, acc[14]*0.25f, acc[15]*0.25f);
}

// main fused kernel: 4 edges per block (sorted order for A-gather locality)
// LDS ~50.0 KB -> 3 blocks/CU (vs 64 KB -> 2 before); barriers per block: 23 -> 4.
// pd layout: [col=edge*8+i][v=path*64+mul], stride 324 (16B-aligned rows).
//   phase-1 writes: lane stride-1 -> conflict-free.
//   phase-2 reads:  wave-uniform ds_read_b128 broadcast -> conflict-free.
__global__ __launch_bounds__(256, 3) void k_main(
    const float* __restrict__ vectors, const float* __restrict__ x, const float* __restrict__ V,
    const int* __restrict__ senders,
    const float* __restrict__ W1, const float* __restrict__ W2, const float* __restrict__ W3,
    const float* __restrict__ wlT,
    const float* __restrict__ ws, const int* __restrict__ sorted,
    float* __restrict__ out){
  __shared__ __align__(16) float lds_pd[32*324];   // 41472 B
  __shared__ float lds_h[4*257];                   // 4112 B  h_in = [x | S]
  __shared__ float lds_mlp[2*4*65];                // 2080 B  MLP h1/h2 scratch
  __shared__ float lds_w3j[573];                   // 2292 B
  __shared__ float lds_env[4];
  __shared__ int   lds_eid[4];

  int t = threadIdx.x;
  for(int i=t;i<573;i+=256) lds_w3j[i]=ws[i];
  int wv = t>>6, lane = t&63;
  int eid = sorted[blockIdx.x*4 + wv];
  if(lane==0) lds_eid[wv]=eid;
  __syncthreads();

  const float* lw = lds_w3j;
  // ---- phase 1: per-edge (one wave per edge) ----
  {
    float v0=vectors[eid*3], v1=vectors[eid*3+1], v2=vectors[eid*3+2];
    float d = sqrtf(v0*v0+v1*v1+v2*v2);
    float d2=d*d, d4=d2*d2, d6=d4*d2, d7=d6*d, d8=d7*d;
    float env = 1.0f - 28.0f*d6 + 48.0f*d7 - 21.0f*d8;
    env = (d < 1.0f) ? env : 0.0f;
    if(lane==0) lds_env[wv]=env;
  }
  int snd = senders[eid];
  const float4* Ap4 = (const float4*)(ws + WS_A + snd*1024 + lane*16);
  float4 a0=Ap4[0], a1=Ap4[1], a2=Ap4[2], a3=Ap4[3];
  float wY[16] = {a0.x,a0.y,a0.z,a0.w, a1.x,a1.y,a1.z,a1.w,
                  a2.x,a2.y,a2.z,a2.w, a3.x,a3.y,a3.z,a3.w};
  const float* Vp = V + eid*576;
  float V0 = Vp[lane];
  float V1f[3], V2f[5];
  #pragma unroll
  for(int i=0;i<3;i++) V1f[i]=Vp[64+lane*3+i];
  #pragma unroll
  for(int j=0;j<5;j++) V2f[j]=Vp[256+lane*5+j];
  lds_h[wv*257 + lane] = x[eid*64+lane];
  // scalar channel S
  float s0 = wY[0]*V0*lw[O_W000];
  float s1 = 0.f;
  #pragma unroll
  for(int i=0;i<3;i++)
    #pragma unroll
    for(int j=0;j<3;j++) s1 += wY[1+i]*V1f[j]*lw[O_W110 + i*3+j];
  float s2 = 0.f;
  #pragma unroll
  for(int i=0;i<5;i++)
    #pragma unroll
    for(int j=0;j<5;j++) s2 += wY[4+i]*V2f[j]*lw[O_W220 + i*5+j];
  lds_h[wv*257+64+lane]=s0;
  lds_h[wv*257+128+lane]=s1;
  lds_h[wv*257+192+lane]=s2;
  // P paths (l3=1): i=0..2.  D paths (l3=2): j=0..4.
  float P0[3]={0,0,0}, P1[3]={0,0,0}, P2[3]={0,0,0}, P3[3]={0,0,0}, P4[3]={0,0,0};
  float D0[5]={0,0,0,0,0}, D1[5]={0,0,0,0,0}, D2[5]={0,0,0,0,0}, D3[5]={0,0,0,0,0}, D4[5]={0,0,0,0,0};
  #pragma unroll
  for(int b=0;b<3;b++){ float pb=wY[0]*V1f[b];
    #pragma unroll
    for(int i=0;i<3;i++) P0[i]+= pb*lw[O_W011 + b*3+i]; }
  #pragma unroll
  for(int a=0;a<3;a++){ float pa=wY[1+a]*V0;
    #pragma unroll
    for(int i=0;i<3;i++) P1[i]+= pa*lw[O_W101 + a*3+i]; }
  #pragma unroll
  for(int a=0;a<3;a++)
    #pragma unroll
    for(int b=0;b<5;b++){ float p=wY[1+a]*V2f[b];
      #pragma unroll
      for(int i=0;i<3;i++) P2[i]+= p*lw[O_W121 + (a*5+b)*3+i]; }
  #pragma unroll
  for(int a=0;a<5;a++)
    #pragma unroll
    for(int b=0;b<3;b++){ float p=wY[4+a]*V1f[b];
      #pragma unroll
      for(int i=0;i<3;i++) P3[i]+= p*lw[O_W211 + (a*3+b)*3+i]; }
  #pragma unroll
  for(int a=0;a<7;a++)
    #pragma unroll
    for(int b=0;b<5;b++){ float p=wY[9+a]*V2f[b];
      #pragma unroll
      for(int i=0;i<3;i++) P4[i]+= p*lw[O_W321 + (a*5+b)*3+i]; }
  #pragma unroll
  for(int b=0;b<5;b++){ float pb=wY[0]*V2f[b];
    #pragma unroll
    for(int j=0;j<5;j++) D0[j]+= pb*lw[O_W022 + b*5+j]; }
  #pragma unroll
  for(int a=0;a<3;a++)
    #pragma unroll
    for(int b=0;b<3;b++){ float p=wY[1+a]*V1f[b];
      #pragma unroll
      for(int j=0;j<5;j++) D1[j]+= p*lw[O_W112 + (a*3+b)*5+j]; }
  #pragma unroll
  for(int a=0;a<5;a++){ float pa=wY[4+a]*V0;
    #pragma unroll
    for(int j=0;j<5;j++) D2[j]+= pa*lw[O_W202 + a*5+j]; }
  #pragma unroll
  for(int a=0;a<5;a++)
    #pragma unroll
    for(int b=0;b<5;b++){ float p=wY[4+a]*V2f[b];
      #pragma unroll
      for(int j=0;j<5;j++) D3[j]+= p*lw[O_W222 + (a*5+b)*5+j]; }
  #pragma unroll
  for(int a=0;a<7;a++)
    #pragma unroll
    for(int b=0;b<3;b++){ float p=wY[9+a]*V1f[b];
      #pragma unroll
      for(int j=0;j<5;j++) D4[j]+= p*lw[O_W312 + (a*3+b)*5+j]; }
  // stage into lds_pd[col][v] (fold sqrt(2*l3+1)); lane stride-1 -> conflict-free
  {
    const float SQ3 = 1.7320508075688772f, SQ5 = 2.2360679774997896f;
    int rb = wv*8;
    #pragma unroll
    for(int i=0;i<3;i++){
      lds_pd[(rb+i)*324 + 0*64+lane] = SQ3*P0[i];
      lds_pd[(rb+i)*324 + 1*64+lane] = SQ3*P1[i];
      lds_pd[(rb+i)*324 + 2*64+lane] = SQ3*P2[i];
      lds_pd[(rb+i)*324 + 3*64+lane] = SQ3*P3[i];
      lds_pd[(rb+i)*324 + 4*64+lane] = SQ3*P4[i];
    }
    #pragma unroll
    for(int j=0;j<5;j++){
      lds_pd[(rb+3+j)*324 + 0*64+lane] = SQ5*D0[j];
      lds_pd[(rb+3+j)*324 + 1*64+lane] = SQ5*D1[j];
      lds_pd[(rb+3+j)*324 + 2*64+lane] = SQ5*D2[j];
      lds_pd[(rb+3+j)*324 + 3*64+lane] = SQ5*D3[j];
      lds_pd[(rb+3+j)*324 + 4*64+lane] = SQ5*D4[j];
    }
  }
  __syncthreads();

  // ---- MLP (block-level; thread = (edge, feature)) ----
  {
    int eL = t>>6, f = t&63;
    float acc=0.f;
    for(int k=0;k<256;k++) acc += lds_h[eL*257+k]*W1[k*64+f];
    acc *= (1.0f/16.0f);
    float h1 = acc/(1.0f+__expf(-acc));
    float* lh1 = lds_mlp;
    lh1[eL*65+f] = h1;
    __syncthreads();
    acc=0.f;
    for(int k=0;k<64;k++) acc += lh1[eL*65+k]*W2[k*64+f];
    acc *= 0.125f;
    float h2 = acc/(1.0f+__expf(-acc));
    float* lh2 = lds_mlp + 4*65;
    lh2[eL*65+f] = h2;
    __syncthreads();
    acc=0.f;
    for(int k=0;k<64;k++) acc += lh2[eL*65+k]*W3[k*64+f];
    acc *= 0.125f;
    out[lds_eid[eL]*576 + f] = lds_env[eL]*acc;
  }

  // ---- phase 2: projections, thread = (edge, u). No barriers, no staging. ----
  // acc_i[u] = sum_v pd[e*8+i][v] * Wl{1,2}^T[u][v]
  {
    int e2 = t>>6, u = t&63;
    const float* pdb = lds_pd + (e2*8)*324;   // rows i=0..7, stride 324 (16B aligned)
    const float* w1r = wlT + u*320;           // Wl1^T row
    const float* w2r = wlT + 20480 + u*320;   // Wl2^T row
    float acc[8] = {0,0,0,0,0,0,0,0};
    #pragma unroll 2
    for(int v0=0; v0<320; v0+=4){
      float4 w1 = *(const float4*)(w1r + v0);
      float4 w2 = *(const float4*)(w2r + v0);
      float4 p0 = *(const float4*)(pdb + 0*324 + v0);
      float4 p1 = *(const float4*)(pdb + 1*324 + v0);
      float4 p2 = *(const float4*)(pdb + 2*324 + v0);
      float4 p3 = *(const float4*)(pdb + 3*324 + v0);
      float4 p4 = *(const float4*)(pdb + 4*324 + v0);
      float4 p5 = *(const float4*)(pdb + 5*324 + v0);
      float4 p6 = *(const float4*)(pdb + 6*324 + v0);
      float4 p7 = *(const float4*)(pdb + 7*324 + v0);
      acc[0] += p0.x*w1.x + p0.y*w1.y + p0.z*w1.z + p0.w*w1.w;
      acc[1] += p1.x*w1.x + p1.y*w1.y + p1.z*w1.z + p1.w*w1.w;
      acc[2] += p2.x*w1.x + p2.y*w1.y + p2.z*w1.z + p2.w*w1.w;
      acc[3] += p3.x*w2.x + p3.y*w2.y + p3.z*w2.z + p3.w*w2.w;
      acc[4] += p4.x*w2.x + p4.y*w2.y + p4.z*w2.z + p4.w*w2.w;
      acc[5] += p5.x*w2.x + p5.y*w2.y + p5.z*w2.z + p5.w*w2.w;
      acc[6] += p6.x*w2.x + p6.y*w2.y + p6.z*w2.z + p6.w*w2.w;
      acc[7] += p7.x*w2.x + p7.y*w2.y + p7.z*w2.z + p7.w*w2.w;
    }
    const float sc = 0.05590169943749474f;  // 1/sqrt(320)
    int eid2 = lds_eid[e2];
    float* op = out + eid2*576;
    op[64  + u*3 + 0] = acc[0]*sc;
    op[64  + u*3 + 1] = acc[1]*sc;
    op[64  + u*3 + 2] = acc[2]*sc;
    op[256 + u*5 + 0] = acc[3]*sc;
    op[256 + u*5 + 1] = acc[4]*sc;
    op[256 + u*5 + 2] = acc[5]*sc;
    op[256 + u*5 + 3] = acc[6]*sc;
    op[256 + u*5 + 4] = acc[7]*sc;
  }
}

extern "C" void kernel_launch(void* const* d_in, const int* in_sizes, int n_in,
                              void* d_out, int out_size, void* d_ws, size_t ws_size,
                              hipStream_t stream) {
  const float* vectors=(const float*)d_in[0];
  const float* x      =(const float*)d_in[1];
  const float* V      =(const float*)d_in[2];
  const int*   senders=(const int*)  d_in[3];
  const float* Ww     =(const float*)d_in[4];
  const float* W1     =(const float*)d_in[5];
  const float* W2     =(const float*)d_in[6];
  const float* W3     =(const float*)d_in[7];
  const float* Wl1    =(const float*)d_in[8];
  const float* Wl2    =(const float*)d_in[9];
  float* ws  = (float*)d_ws;
  float* out = (float*)d_out;
  int* cnt    = (int*)(ws + WS_CNT);
  int* off    = (int*)(ws + WS_OFF);
  int* cur    = (int*)(ws + WS_CUR);
  int* sorted = (int*)(ws + WS_SORT);
  float* wlT  = ws + WS_WLT;

  k_w3j   <<<14, 128, 0, stream>>>(ws);
  k_c2c3  <<<1, 1, 0, stream>>>(ws);
  k_zero  <<<16, 256, 0, stream>>>(cnt);
  k_count <<<E_EDGES/256, 256, 0, stream>>>(senders, cnt);
  k_scan  <<<1, 1024, 0, stream>>>(cnt, off, cur);
  k_scatter<<<E_EDGES/256, 256, 0, stream>>>(senders, cur, sorted);
  k_wlT   <<<160, 256, 0, stream>>>(Wl1, Wl2, wlT);
  k_edge_pre<<<E_EDGES/4, 256, 0, stream>>>(vectors, x, Ww, ws);
  k_node_acc<<<N_NODES, 64, 0, stream>>>(ws + WS_W, ws + WS_Y, sorted, off, cnt, ws + WS_A);
  k_main  <<<E_EDGES/4, 256, 0, stream>>>(vectors, x, V, senders, W1, W2, W3, wlT,
                                          ws, sorted, out);
}

// Round 2
// 1293.956 us; speedup vs baseline: 1.4973x; 1.3341x over previous
//
#include <hip/hip_runtime.h>

#define E_EDGES 65536
#define N_NODES 4096

// ---- workspace layout (float offsets) ----
// [0,678)   w3j tensors, [678] C2, [679] C3  (reserve 1024)
#define WS_W     1024                       // E*64   w = x@Ww/8
#define WS_Y     (WS_W + E_EDGES*64)        // E*16   Y
#define WS_CNT   (WS_Y + E_EDGES*16)        // 4096 int
#define WS_OFF   (WS_CNT + N_NODES)         // 4096 int
#define WS_CUR   (WS_OFF + N_NODES)         // 4096 int
#define WS_SORT  (WS_CUR + N_NODES)         // E int
#define WS_A     (WS_SORT + E_EDGES)        // N*1024  node accumulator (eps folded)
// high-water: WS_A + 4096*1024 = 9,516,032 floats ~= 38.1 MB

// key order: (0,0,0),(1,1,0),(2,2,0),(0,1,1),(1,0,1),(1,2,1),(2,1,1),(3,2,1),
//            (0,2,2),(1,1,2),(2,0,2),(2,2,2),(3,1,2),(2,1,3)
__constant__ int gK_L1[14] = {0,1,2,0,1,1,2,3,0,1,2,2,3,2};
__constant__ int gK_L2[14] = {0,1,2,1,0,2,1,2,2,1,0,2,1,1};
__constant__ int gK_L3[14] = {0,0,0,1,1,1,1,1,2,2,2,2,2,3};
__constant__ int gK_OFF[14]= {0,1,10,35,44,53,98,143,248,273,318,343,468,573};
__constant__ double gFact[8] = {1.,1.,2.,6.,24.,120.,720.,5040.};

// w3j offsets (compile-time)
#define O_W000 0
#define O_W110 1
#define O_W220 10
#define O_W011 35
#define O_W101 44
#define O_W121 53
#define O_W211 98
#define O_W321 143
#define O_W022 248
#define O_W112 273
#define O_W202 318
#define O_W222 343
#define O_W312 468
#define O_W213 573

__device__ double su2_cg(int j1,int j2,int j3,int m1,int m2,int m3){
  if (m3 != m1+m2) return 0.0;
  double pref = sqrt((double)(2*j3+1)*gFact[j3+j1-j2]*gFact[j3-j1+j2]*gFact[j1+j2-j3]/gFact[j1+j2+j3+1]);
  pref *= sqrt(gFact[j3+m3]*gFact[j3-m3]*gFact[j1-m1]*gFact[j1+m1]*gFact[j2-m2]*gFact[j2+m2]);
  double s=0.0;
  for(int k=0;k<=j1+j2-j3;k++){
    int d1=j1+j2-j3-k, d2=j1-m1-k, d3=j2+m2-k, d4=j3-j2+m1+k, d5=j3-j1-m2+k;
    if(d1<0||d2<0||d3<0||d4<0||d5<0) continue;
    double den=gFact[k]*gFact[d1]*gFact[d2]*gFact[d3]*gFact[d4]*gFact[d5];
    s += (k&1)? (-1.0/den) : (1.0/den);
  }
  return pref*s;
}

__device__ void fill_qmat(int l, double2* q){  // 7x7 row-major, rows=m-basis, cols=real-basis
  for(int i=0;i<49;i++){ q[i].x=0.0; q[i].y=0.0; }
  const double is2 = 0.7071067811865475244;
  for(int m=-l;m<0;m++){
    q[(l+m)*7+(l-m)].x = is2;     // q[l+m, l+|m|] = 1/sqrt2
    q[(l+m)*7+(l+m)].y = -is2;    // q[l+m, l-|m|] = -1j/sqrt2
  }
  q[l*7+l].x = 1.0;
  for(int m=1;m<=l;m++){
    double sg = (m&1)? -1.0 : 1.0;
    q[(l+m)*7+(l+m)].x = sg*is2;
    q[(l+m)*7+(l-m)].y = sg*is2;
  }
  double pr, pi;  // (-i)^l
  switch(l&3){ case 0: pr=1;pi=0;break; case 1: pr=0;pi=-1;break; case 2: pr=-1;pi=0;break; default: pr=0;pi=1;break; }
  for(int i=0;i<49;i++){
    double a=q[i].x, b=q[i].y;
    q[i].x = a*pr - b*pi;
    q[i].y = a*pi + b*pr;
  }
}

__global__ __launch_bounds__(128) void k_w3j(float* __restrict__ ws){
  __shared__ double2 q1[49], q2[49], q3[49];
  __shared__ double C[125], Cr[125];
  __shared__ double red[128];
  int bid = blockIdx.x, t = threadIdx.x;
  int l1=gK_L1[bid], l2=gK_L2[bid], l3=gK_L3[bid];
  int n1=2*l1+1, n2=2*l2+1, n3=2*l3+1, ntot=n1*n2*n3;
  if(t==0){
    fill_qmat(l1,q1); fill_qmat(l2,q2); fill_qmat(l3,q3);
    for(int i=0;i<49;i++) q3[i].y = -q3[i].y;   // conj
  }
  __syncthreads();
  for(int idx=t; idx<ntot; idx+=128){
    int a = idx/(n2*n3), r=idx%(n2*n3), b=r/n3, c=r%n3;
    C[idx] = su2_cg(l1,l2,l3, a-l1, b-l2, c-l3);
  }
  __syncthreads();
  for(int idx=t; idx<ntot; idx+=128){
    int i = idx/(n2*n3), r=idx%(n2*n3), j=r/n3, k=r%n3;
    double ar=0.0;
    for(int a=0;a<n1;a++) for(int b=0;b<n2;b++){
      double2 qa=q1[a*7+i], qb=q2[b*7+j];
      double pr = qa.x*qb.x - qa.y*qb.y;
      double pi = qa.x*qb.y + qa.y*qb.x;
      for(int c=0;c<n3;c++){
        double2 qc=q3[c*7+k];
        double tr = pr*qc.x - pi*qc.y;
        ar += tr*C[(a*n2+b)*n3+c];
      }
    }
    Cr[idx]=ar;
  }
  __syncthreads();
  double ss=0.0;
  for(int idx=t; idx<ntot; idx+=128) ss += Cr[idx]*Cr[idx];
  red[t]=ss; __syncthreads();
  for(int st=64; st>0; st>>=1){ if(t<st) red[t]+=red[t+st]; __syncthreads(); }
  double inv = 1.0/sqrt(red[0]);
  for(int idx=t; idx<ntot; idx+=128) ws[gK_OFF[bid]+idx] = (float)(Cr[idx]*inv);
}

__global__ void k_c2c3(float* __restrict__ ws){
  const float* w112 = ws + O_W112;
  const float* w213 = ws + O_W213;
  double u0=0.3, u1=-0.4, u2=sqrt(0.75);
  double s3=sqrt(3.0);
  double y1[3]={s3*u0, s3*u1, s3*u2};
  double y2r[5]={0,0,0,0,0};
  for(int i=0;i<3;i++) for(int j=0;j<3;j++) for(int k=0;k<5;k++)
    y2r[k] += y1[i]*y1[j]*(double)w112[(i*3+j)*5+k];
  double nn=0; for(int k=0;k<5;k++) nn += y2r[k]*y2r[k];
  double c2 = sqrt(5.0)/sqrt(nn);
  double y2[5]; for(int k=0;k<5;k++) y2[k]=c2*y2r[k];
  double y3r[7]={0,0,0,0,0,0,0};
  for(int i=0;i<5;i++) for(int j=0;j<3;j++) for(int n=0;n<7;n++)
    y3r[n] += y2[i]*y1[j]*(double)w213[(i*3+j)*7+n];
  nn=0; for(int n=0;n<7;n++) nn += y3r[n]*y3r[n];
  double c3 = sqrt(7.0)/sqrt(nn);
  ws[678]=(float)c2; ws[679]=(float)c3;
}

__global__ void k_zero(int* __restrict__ cnt){
  int i = blockIdx.x*256 + threadIdx.x;
  if(i < N_NODES) cnt[i]=0;
}
__global__ void k_count(const int* __restrict__ senders, int* __restrict__ cnt){
  int e = blockIdx.x*256 + threadIdx.x;
  if(e < E_EDGES) atomicAdd(&cnt[senders[e]], 1);
}
__global__ __launch_bounds__(1024) void k_scan(const int* __restrict__ cnt, int* __restrict__ off, int* __restrict__ cur){
  __shared__ int part[1024];
  int t = threadIdx.x;
  int c0=cnt[4*t], c1=cnt[4*t+1], c2=cnt[4*t+2], c3=cnt[4*t+3];
  int l0=0, l1=c0, l2=c0+c1, l3=c0+c1+c2;
  int sum=l3+c3;
  part[t]=sum; __syncthreads();
  for(int st=1; st<1024; st<<=1){
    int v = part[t];
    int add = (t>=st)? part[t-st] : 0;
    __syncthreads();
    part[t] = v + add;
    __syncthreads();
  }
  int pref = (t>0)? part[t-1] : 0;
  off[4*t]=pref+l0; off[4*t+1]=pref+l1; off[4*t+2]=pref+l2; off[4*t+3]=pref+l3;
  cur[4*t]=pref+l0; cur[4*t+1]=pref+l1; cur[4*t+2]=pref+l2; cur[4*t+3]=pref+l3;
}
__global__ void k_scatter(const int* __restrict__ senders, int* __restrict__ cur, int* __restrict__ sorted){
  int e = blockIdx.x*256 + threadIdx.x;
  if(e < E_EDGES){
    int pos = atomicAdd(&cur[senders[e]], 1);
    sorted[pos] = e;
  }
}

// per edge: w = x@Ww/8 (lane=mul), Y[16] spherical harmonics
__global__ __launch_bounds__(256) void k_edge_pre(
    const float* __restrict__ vectors, const float* __restrict__ x,
    const float* __restrict__ Ww, float* __restrict__ ws){
  int wv = threadIdx.x >> 6, lane = threadIdx.x & 63;
  int e = blockIdx.x*4 + wv;
  const float* w112 = ws + O_W112;
  const float* w213 = ws + O_W213;
  float C2v = ws[678], C3v = ws[679];
  float v0=vectors[e*3], v1=vectors[e*3+1], v2=vectors[e*3+2];
  float len = sqrtf(v0*v0+v1*v1+v2*v2);
  float inv = 1.0f/(len + 1e-12f);
  float s3 = 1.7320508075688772f;
  float y1v[3] = { s3*v0*inv, s3*v1*inv, s3*v2*inv };
  float y2[5];
  #pragma unroll
  for(int k=0;k<5;k++){
    float a=0.f;
    #pragma unroll
    for(int i=0;i<3;i++)
      #pragma unroll
      for(int j=0;j<3;j++) a += y1v[i]*y1v[j]*w112[(i*3+j)*5+k];
    y2[k]=C2v*a;
  }
  float y3[7];
  #pragma unroll
  for(int n=0;n<7;n++){
    float a=0.f;
    #pragma unroll
    for(int i=0;i<5;i++)
      #pragma unroll
      for(int j=0;j<3;j++) a += y2[i]*y1v[j]*w213[(i*3+j)*7+n];
    y3[n]=C3v*a;
  }
  // w
  float acc=0.f;
  for(int k=0;k<64;k++) acc += x[e*64+k]*Ww[k*64+lane];
  ws[WS_W + e*64 + lane] = acc*0.125f;
  if(lane==0){
    float* Yp = ws + WS_Y + e*16;
    Yp[0]=1.0f;
    Yp[1]=y1v[0]; Yp[2]=y1v[1]; Yp[3]=y1v[2];
    Yp[4]=y2[0]; Yp[5]=y2[1]; Yp[6]=y2[2]; Yp[7]=y2[3]; Yp[8]=y2[4];
    Yp[9]=y3[0]; Yp[10]=y3[1]; Yp[11]=y3[2]; Yp[12]=y3[3]; Yp[13]=y3[4]; Yp[15]=y3[6]; Yp[14]=y3[5];
  }
}

// per node: A[n][m][k] = eps * sum_e w[e][m]*Y[e][k]
__global__ __launch_bounds__(64) void k_node_acc(
    const float* __restrict__ ws_w, const float* __restrict__ ws_y,
    const int* __restrict__ sorted, const int* __restrict__ off, const int* __restrict__ cnt,
    float* __restrict__ A){
  int n = blockIdx.x, m = threadIdx.x;
  float acc[16];
  #pragma unroll
  for(int k=0;k<16;k++) acc[k]=0.f;
  int o = off[n], c = cnt[n];
  for(int j=0;j<c;j++){
    int e = sorted[o+j];
    float wm = ws_w[e*64+m];
    const float* Yp = ws_y + e*16;
    #pragma unroll
    for(int k=0;k<16;k++) acc[k] += wm*Yp[k];
  }
  float4* outp = (float4*)(A + n*1024 + m*16);
  outp[0] = make_float4(acc[0]*0.25f, acc[1]*0.25f, acc[2]*0.25f, acc[3]*0.25f);
  outp[1] = make_float4(acc[4]*0.25f, acc[5]*0.25f, acc[6]*0.25f, acc[7]*0.25f);
  outp[2] = make_float4(acc[8]*0.25f, acc[9]*0.25f, acc[10]*0.25f, acc[11]*0.25f);
  outp[3] = make_float4(acc[12]*0.25f, acc[13]*0.25f, acc[14]*0.25f, acc[15]*0.25f);
}

// main fused kernel: 4 edges per block (sorted order for A-gather locality)
// LDS ~50.0 KB -> 3 blocks/CU; barriers per block: 4.
// pd layout: [col=edge*8+i][v=path*64+mul], stride 324 (16B-aligned rows).
//   phase-1 writes: lane stride-1 -> conflict-free.
//   phase-2 reads:  wave-uniform ds_read_b128 broadcast -> conflict-free.
// phase-2 weights: ORIGINAL Wl[v][64] layout -> lane u reads Wl[v*64+u]:
//   64 lanes x 4B contiguous = ~2 lines/instr (vs 64-line gather of the
//   transposed layout -> 16-32x fewer memory-pipe line transactions).
__global__ __launch_bounds__(256, 3) void k_main(
    const float* __restrict__ vectors, const float* __restrict__ x, const float* __restrict__ V,
    const int* __restrict__ senders,
    const float* __restrict__ W1, const float* __restrict__ W2, const float* __restrict__ W3,
    const float* __restrict__ Wl1, const float* __restrict__ Wl2,
    const float* __restrict__ ws, const int* __restrict__ sorted,
    float* __restrict__ out){
  __shared__ __align__(16) float lds_pd[32*324];   // 41472 B
  __shared__ float lds_h[4*257];                   // 4112 B  h_in = [x | S]
  __shared__ float lds_mlp[2*4*65];                // 2080 B  MLP h1/h2 scratch
  __shared__ float lds_w3j[573];                   // 2292 B
  __shared__ float lds_env[4];
  __shared__ int   lds_eid[4];

  int t = threadIdx.x;
  for(int i=t;i<573;i+=256) lds_w3j[i]=ws[i];
  int wv = t>>6, lane = t&63;
  int eid = sorted[blockIdx.x*4 + wv];
  if(lane==0) lds_eid[wv]=eid;
  __syncthreads();

  const float* lw = lds_w3j;
  // ---- phase 1: per-edge (one wave per edge) ----
  {
    float v0=vectors[eid*3], v1=vectors[eid*3+1], v2=vectors[eid*3+2];
    float d = sqrtf(v0*v0+v1*v1+v2*v2);
    float d2=d*d, d4=d2*d2, d6=d4*d2, d7=d6*d, d8=d7*d;
    float env = 1.0f - 28.0f*d6 + 48.0f*d7 - 21.0f*d8;
    env = (d < 1.0f) ? env : 0.0f;
    if(lane==0) lds_env[wv]=env;
  }
  int snd = senders[eid];
  const float4* Ap4 = (const float4*)(ws + WS_A + snd*1024 + lane*16);
  float4 a0=Ap4[0], a1=Ap4[1], a2=Ap4[2], a3=Ap4[3];
  float wY[16] = {a0.x,a0.y,a0.z,a0.w, a1.x,a1.y,a1.z,a1.w,
                  a2.x,a2.y,a2.z,a2.w, a3.x,a3.y,a3.z,a3.w};
  const float* Vp = V + eid*576;
  float V0 = Vp[lane];
  float V1f[3], V2f[5];
  #pragma unroll
  for(int i=0;i<3;i++) V1f[i]=Vp[64+lane*3+i];
  #pragma unroll
  for(int j=0;j<5;j++) V2f[j]=Vp[256+lane*5+j];
  lds_h[wv*257 + lane] = x[eid*64+lane];
  // scalar channel S
  float s0 = wY[0]*V0*lw[O_W000];
  float s1 = 0.f;
  #pragma unroll
  for(int i=0;i<3;i++)
    #pragma unroll
    for(int j=0;j<3;j++) s1 += wY[1+i]*V1f[j]*lw[O_W110 + i*3+j];
  float s2 = 0.f;
  #pragma unroll
  for(int i=0;i<5;i++)
    #pragma unroll
    for(int j=0;j<5;j++) s2 += wY[4+i]*V2f[j]*lw[O_W220 + i*5+j];
  lds_h[wv*257+64+lane]=s0;
  lds_h[wv*257+128+lane]=s1;
  lds_h[wv*257+192+lane]=s2;
  // P paths (l3=1): i=0..2.  D paths (l3=2): j=0..4.
  float P0[3]={0,0,0}, P1[3]={0,0,0}, P2[3]={0,0,0}, P3[3]={0,0,0}, P4[3]={0,0,0};
  float D0[5]={0,0,0,0,0}, D1[5]={0,0,0,0,0}, D2[5]={0,0,0,0,0}, D3[5]={0,0,0,0,0}, D4[5]={0,0,0,0,0};
  #pragma unroll
  for(int b=0;b<3;b++){ float pb=wY[0]*V1f[b];
    #pragma unroll
    for(int i=0;i<3;i++) P0[i]+= pb*lw[O_W011 + b*3+i]; }
  #pragma unroll
  for(int a=0;a<3;a++){ float pa=wY[1+a]*V0;
    #pragma unroll
    for(int i=0;i<3;i++) P1[i]+= pa*lw[O_W101 + a*3+i]; }
  #pragma unroll
  for(int a=0;a<3;a++)
    #pragma unroll
    for(int b=0;b<5;b++){ float p=wY[1+a]*V2f[b];
      #pragma unroll
      for(int i=0;i<3;i++) P2[i]+= p*lw[O_W121 + (a*5+b)*3+i]; }
  #pragma unroll
  for(int a=0;a<5;a++)
    #pragma unroll
    for(int b=0;b<3;b++){ float p=wY[4+a]*V1f[b];
      #pragma unroll
      for(int i=0;i<3;i++) P3[i]+= p*lw[O_W211 + (a*3+b)*3+i]; }
  #pragma unroll
  for(int a=0;a<7;a++)
    #pragma unroll
    for(int b=0;b<5;b++){ float p=wY[9+a]*V2f[b];
      #pragma unroll
      for(int i=0;i<3;i++) P4[i]+= p*lw[O_W321 + (a*5+b)*3+i]; }
  #pragma unroll
  for(int b=0;b<5;b++){ float pb=wY[0]*V2f[b];
    #pragma unroll
    for(int j=0;j<5;j++) D0[j]+= pb*lw[O_W022 + b*5+j]; }
  #pragma unroll
  for(int a=0;a<3;a++)
    #pragma unroll
    for(int b=0;b<3;b++){ float p=wY[1+a]*V1f[b];
      #pragma unroll
      for(int j=0;j<5;j++) D1[j]+= p*lw[O_W112 + (a*3+b)*5+j]; }
  #pragma unroll
  for(int a=0;a<5;a++){ float pa=wY[4+a]*V0;
    #pragma unroll
    for(int j=0;j<5;j++) D2[j]+= pa*lw[O_W202 + a*5+j]; }
  #pragma unroll
  for(int a=0;a<5;a++)
    #pragma unroll
    for(int b=0;b<5;b++){ float p=wY[4+a]*V2f[b];
      #pragma unroll
      for(int j=0;j<5;j++) D3[j]+= p*lw[O_W222 + (a*5+b)*5+j]; }
  #pragma unroll
  for(int a=0;a<7;a++)
    #pragma unroll
    for(int b=0;b<3;b++){ float p=wY[9+a]*V1f[b];
      #pragma unroll
      for(int j=0;j<5;j++) D4[j]+= p*lw[O_W312 + (a*3+b)*5+j]; }
  // stage into lds_pd[col][v] (fold sqrt(2*l3+1)); lane stride-1 -> conflict-free
  {
    const float SQ3 = 1.7320508075688772f, SQ5 = 2.2360679774997896f;
    int rb = wv*8;
    #pragma unroll
    for(int i=0;i<3;i++){
      lds_pd[(rb+i)*324 + 0*64+lane] = SQ3*P0[i];
      lds_pd[(rb+i)*324 + 1*64+lane] = SQ3*P1[i];
      lds_pd[(rb+i)*324 + 2*64+lane] = SQ3*P2[i];
      lds_pd[(rb+i)*324 + 3*64+lane] = SQ3*P3[i];
      lds_pd[(rb+i)*324 + 4*64+lane] = SQ3*P4[i];
    }
    #pragma unroll
    for(int j=0;j<5;j++){
      lds_pd[(rb+3+j)*324 + 0*64+lane] = SQ5*D0[j];
      lds_pd[(rb+3+j)*324 + 1*64+lane] = SQ5*D1[j];
      lds_pd[(rb+3+j)*324 + 2*64+lane] = SQ5*D2[j];
      lds_pd[(rb+3+j)*324 + 3*64+lane] = SQ5*D3[j];
      lds_pd[(rb+3+j)*324 + 4*64+lane] = SQ5*D4[j];
    }
  }
  __syncthreads();

  // ---- MLP (block-level; thread = (edge, feature)) ----
  {
    int eL = t>>6, f = t&63;
    float acc=0.f;
    for(int k=0;k<256;k++) acc += lds_h[eL*257+k]*W1[k*64+f];
    acc *= (1.0f/16.0f);
    float h1 = acc/(1.0f+__expf(-acc));
    float* lh1 = lds_mlp;
    lh1[eL*65+f] = h1;
    __syncthreads();
    acc=0.f;
    for(int k=0;k<64;k++) acc += lh1[eL*65+k]*W2[k*64+f];
    acc *= 0.125f;
    float h2 = acc/(1.0f+__expf(-acc));
    float* lh2 = lds_mlp + 4*65;
    lh2[eL*65+f] = h2;
    __syncthreads();
    acc=0.f;
    for(int k=0;k<64;k++) acc += lh2[eL*65+k]*W3[k*64+f];
    acc *= 0.125f;
    out[lds_eid[eL]*576 + f] = lds_env[eL]*acc;
  }

  // ---- phase 2: projections, thread = (edge, u). No barriers, no staging. ----
  // acc_i[u] = sum_v pd[e*8+i][v] * Wl{1,2}[v][u]   (coalesced weight columns)
  {
    int e2 = t>>6, u = t&63;
    const float* pdb = lds_pd + (e2*8)*324;   // rows i=0..7, stride 324 (16B aligned)
    const float* w1c = Wl1 + u;               // column u, row stride 64 floats (256B)
    const float* w2c = Wl2 + u;
    float acc0=0.f,acc1=0.f,acc2=0.f,acc3=0.f,acc4=0.f,acc5=0.f,acc6=0.f,acc7=0.f;
    #pragma unroll 4
    for(int v0=0; v0<320; v0+=4){
      // 8 coalesced weight loads (64 lanes x 4B contiguous each)
      float wa0 = w1c[(v0+0)*64];
      float wa1 = w1c[(v0+1)*64];
      float wa2 = w1c[(v0+2)*64];
      float wa3 = w1c[(v0+3)*64];
      float wb0 = w2c[(v0+0)*64];
      float wb1 = w2c[(v0+1)*64];
      float wb2 = w2c[(v0+2)*64];
      float wb3 = w2c[(v0+3)*64];
      // 8 wave-uniform broadcast reads of pd (conflict-free)
      float4 p0 = *(const float4*)(pdb + 0*324 + v0);
      float4 p1 = *(const float4*)(pdb + 1*324 + v0);
      float4 p2 = *(const float4*)(pdb + 2*324 + v0);
      float4 p3 = *(const float4*)(pdb + 3*324 + v0);
      float4 p4 = *(const float4*)(pdb + 4*324 + v0);
      float4 p5 = *(const float4*)(pdb + 5*324 + v0);
      float4 p6 = *(const float4*)(pdb + 6*324 + v0);
      float4 p7 = *(const float4*)(pdb + 7*324 + v0);
      acc0 += p0.x*wa0 + p0.y*wa1 + p0.z*wa2 + p0.w*wa3;
      acc1 += p1.x*wa0 + p1.y*wa1 + p1.z*wa2 + p1.w*wa3;
      acc2 += p2.x*wa0 + p2.y*wa1 + p2.z*wa2 + p2.w*wa3;
      acc3 += p3.x*wb0 + p3.y*wb1 + p3.z*wb2 + p3.w*wb3;
      acc4 += p4.x*wb0 + p4.y*wb1 + p4.z*wb2 + p4.w*wb3;
      acc5 += p5.x*wb0 + p5.y*wb1 + p5.z*wb2 + p5.w*wb3;
      acc6 += p6.x*wb0 + p6.y*wb1 + p6.z*wb2 + p6.w*wb3;
      acc7 += p7.x*wb0 + p7.y*wb1 + p7.z*wb2 + p7.w*wb3;
    }
    const float sc = 0.05590169943749474f;  // 1/sqrt(320)
    int eid2 = lds_eid[e2];
    float* op = out + eid2*576;
    op[64  + u*3 + 0] = acc0*sc;
    op[64  + u*3 + 1] = acc1*sc;
    op[64  + u*3 + 2] = acc2*sc;
    op[256 + u*5 + 0] = acc3*sc;
    op[256 + u*5 + 1] = acc4*sc;
    op[256 + u*5 + 2] = acc5*sc;
    op[256 + u*5 + 3] = acc6*sc;
    op[256 + u*5 + 4] = acc7*sc;
  }
}

extern "C" void kernel_launch(void* const* d_in, const int* in_sizes, int n_in,
                              void* d_out, int out_size, void* d_ws, size_t ws_size,
                              hipStream_t stream) {
  const float* vectors=(const float*)d_in[0];
  const float* x      =(const float*)d_in[1];
  const float* V      =(const float*)d_in[2];
  const int*   senders=(const int*)  d_in[3];
  const float* Ww     =(const float*)d_in[4];
  const float* W1     =(const float*)d_in[5];
  const float* W2     =(const float*)d_in[6];
  const float* W3     =(const float*)d_in[7];
  const float* Wl1    =(const float*)d_in[8];
  const float* Wl2    =(const float*)d_in[9];
  float* ws  = (float*)d_ws;
  float* out = (float*)d_out;
  int* cnt    = (int*)(ws + WS_CNT);
  int* off    = (int*)(ws + WS_OFF);
  int* cur    = (int*)(ws + WS_CUR);
  int* sorted = (int*)(ws + WS_SORT);

  k_w3j   <<<14, 128, 0, stream>>>(ws);
  k_c2c3  <<<1, 1, 0, stream>>>(ws);
  k_zero  <<<16, 256, 0, stream>>>(cnt);
  k_count <<<E_EDGES/256, 256, 0, stream>>>(senders, cnt);
  k_scan  <<<1, 1024, 0, stream>>>(cnt, off, cur);
  k_scatter<<<E_EDGES/256, 256, 0, stream>>>(senders, cur, sorted);
  k_edge_pre<<<E_EDGES/4, 256, 0, stream>>>(vectors, x, Ww, ws);
  k_node_acc<<<N_NODES, 64, 0, stream>>>(ws + WS_W, ws + WS_Y, sorted, off, cnt, ws + WS_A);
  k_main  <<<E_EDGES/4, 256, 0, stream>>>(vectors, x, V, senders, W1, W2, W3, Wl1, Wl2,
                                          ws, sorted, out);
}

// Round 3
// 759.512 us; speedup vs baseline: 2.5509x; 1.7037x over previous
//
#include <hip/hip_runtime.h>

#define E_EDGES 65536
#define N_NODES 4096

// ---- workspace layout (float offsets) ----
// [0,678)   w3j tensors, [678] C2, [679] C3  (reserve 1024)
#define WS_W     1024                       // E*64   w = x@Ww/8  (dead after k_node_acc; reused for packed weights)
#define WS_Y     (WS_W + E_EDGES*64)        // E*16   Y
#define WS_CNT   (WS_Y + E_EDGES*16)        // 4096 int
#define WS_OFF   (WS_CNT + N_NODES)         // 4096 int
#define WS_CUR   (WS_OFF + N_NODES)         // 4096 int
#define WS_SORT  (WS_CUR + N_NODES)         // E int
#define WS_A     (WS_SORT + E_EDGES)        // N*1024  node accumulator (eps folded)
// high-water: WS_A + 4096*1024 = 9,516,032 floats ~= 38.1 MB

typedef __bf16 bf16x8 __attribute__((ext_vector_type(8)));
typedef float  f32x4  __attribute__((ext_vector_type(4)));

// key order: (0,0,0),(1,1,0),(2,2,0),(0,1,1),(1,0,1),(1,2,1),(2,1,1),(3,2,1),
//            (0,2,2),(1,1,2),(2,0,2),(2,2,2),(3,1,2),(2,1,3)
__constant__ int gK_L1[14] = {0,1,2,0,1,1,2,3,0,1,2,2,3,2};
__constant__ int gK_L2[14] = {0,1,2,1,0,2,1,2,2,1,0,2,1,1};
__constant__ int gK_L3[14] = {0,0,0,1,1,1,1,1,2,2,2,2,2,3};
__constant__ int gK_OFF[14]= {0,1,10,35,44,53,98,143,248,273,318,343,468,573};
__constant__ double gFact[8] = {1.,1.,2.,6.,24.,120.,720.,5040.};

// w3j offsets (compile-time)
#define O_W000 0
#define O_W110 1
#define O_W220 10
#define O_W011 35
#define O_W101 44
#define O_W121 53
#define O_W211 98
#define O_W321 143
#define O_W022 248
#define O_W112 273
#define O_W202 318
#define O_W222 343
#define O_W312 468
#define O_W213 573

__device__ double su2_cg(int j1,int j2,int j3,int m1,int m2,int m3){
  if (m3 != m1+m2) return 0.0;
  double pref = sqrt((double)(2*j3+1)*gFact[j3+j1-j2]*gFact[j3-j1+j2]*gFact[j1+j2-j3]/gFact[j1+j2+j3+1]);
  pref *= sqrt(gFact[j3+m3]*gFact[j3-m3]*gFact[j1-m1]*gFact[j1+m1]*gFact[j2-m2]*gFact[j2+m2]);
  double s=0.0;
  for(int k=0;k<=j1+j2-j3;k++){
    int d1=j1+j2-j3-k, d2=j1-m1-k, d3=j2+m2-k, d4=j3-j2+m1+k, d5=j3-j1-m2+k;
    if(d1<0||d2<0||d3<0||d4<0||d5<0) continue;
    double den=gFact[k]*gFact[d1]*gFact[d2]*gFact[d3]*gFact[d4]*gFact[d5];
    s += (k&1)? (-1.0/den) : (1.0/den);
  }
  return pref*s;
}

__device__ void fill_qmat(int l, double2* q){  // 7x7 row-major, rows=m-basis, cols=real-basis
  for(int i=0;i<49;i++){ q[i].x=0.0; q[i].y=0.0; }
  const double is2 = 0.7071067811865475244;
  for(int m=-l;m<0;m++){
    q[(l+m)*7+(l-m)].x = is2;     // q[l+m, l+|m|] = 1/sqrt2
    q[(l+m)*7+(l+m)].y = -is2;    // q[l+m, l-|m|] = -1j/sqrt2
  }
  q[l*7+l].x = 1.0;
  for(int m=1;m<=l;m++){
    double sg = (m&1)? -1.0 : 1.0;
    q[(l+m)*7+(l+m)].x = sg*is2;
    q[(l+m)*7+(l-m)].y = sg*is2;
  }
  double pr, pi;  // (-i)^l
  switch(l&3){ case 0: pr=1;pi=0;break; case 1: pr=0;pi=-1;break; case 2: pr=-1;pi=0;break; default: pr=0;pi=1;break; }
  for(int i=0;i<49;i++){
    double a=q[i].x, b=q[i].y;
    q[i].x = a*pr - b*pi;
    q[i].y = a*pi + b*pr;
  }
}

__global__ __launch_bounds__(128) void k_w3j(float* __restrict__ ws){
  __shared__ double2 q1[49], q2[49], q3[49];
  __shared__ double C[125], Cr[125];
  __shared__ double red[128];
  int bid = blockIdx.x, t = threadIdx.x;
  int l1=gK_L1[bid], l2=gK_L2[bid], l3=gK_L3[bid];
  int n1=2*l1+1, n2=2*l2+1, n3=2*l3+1, ntot=n1*n2*n3;
  if(t==0){
    fill_qmat(l1,q1); fill_qmat(l2,q2); fill_qmat(l3,q3);
    for(int i=0;i<49;i++) q3[i].y = -q3[i].y;   // conj
  }
  __syncthreads();
  for(int idx=t; idx<ntot; idx+=128){
    int a = idx/(n2*n3), r=idx%(n2*n3), b=r/n3, c=r%n3;
    C[idx] = su2_cg(l1,l2,l3, a-l1, b-l2, c-l3);
  }
  __syncthreads();
  for(int idx=t; idx<ntot; idx+=128){
    int i = idx/(n2*n3), r=idx%(n2*n3), j=r/n3, k=r%n3;
    double ar=0.0;
    for(int a=0;a<n1;a++) for(int b=0;b<n2;b++){
      double2 qa=q1[a*7+i], qb=q2[b*7+j];
      double pr = qa.x*qb.x - qa.y*qb.y;
      double pi = qa.x*qb.y + qa.y*qb.x;
      for(int c=0;c<n3;c++){
        double2 qc=q3[c*7+k];
        double tr = pr*qc.x - pi*qc.y;
        ar += tr*C[(a*n2+b)*n3+c];
      }
    }
    Cr[idx]=ar;
  }
  __syncthreads();
  double ss=0.0;
  for(int idx=t; idx<ntot; idx+=128) ss += Cr[idx]*Cr[idx];
  red[t]=ss; __syncthreads();
  for(int st=64; st>0; st>>=1){ if(t<st) red[t]+=red[t+st]; __syncthreads(); }
  double inv = 1.0/sqrt(red[0]);
  for(int idx=t; idx<ntot; idx+=128) ws[gK_OFF[bid]+idx] = (float)(Cr[idx]*inv);
}

__global__ void k_c2c3(float* __restrict__ ws){
  const float* w112 = ws + O_W112;
  const float* w213 = ws + O_W213;
  double u0=0.3, u1=-0.4, u2=sqrt(0.75);
  double s3=sqrt(3.0);
  double y1[3]={s3*u0, s3*u1, s3*u2};
  double y2r[5]={0,0,0,0,0};
  for(int i=0;i<3;i++) for(int j=0;j<3;j++) for(int k=0;k<5;k++)
    y2r[k] += y1[i]*y1[j]*(double)w112[(i*3+j)*5+k];
  double nn=0; for(int k=0;k<5;k++) nn += y2r[k]*y2r[k];
  double c2 = sqrt(5.0)/sqrt(nn);
  double y2[5]; for(int k=0;k<5;k++) y2[k]=c2*y2r[k];
  double y3r[7]={0,0,0,0,0,0,0};
  for(int i=0;i<5;i++) for(int j=0;j<3;j++) for(int n=0;n<7;n++)
    y3r[n] += y2[i]*y1[j]*(double)w213[(i*3+j)*7+n];
  nn=0; for(int n=0;n<7;n++) nn += y3r[n]*y3r[n];
  double c3 = sqrt(7.0)/sqrt(nn);
  ws[678]=(float)c2; ws[679]=(float)c3;
}

__global__ void k_zero(int* __restrict__ cnt){
  int i = blockIdx.x*256 + threadIdx.x;
  if(i < N_NODES) cnt[i]=0;
}
__global__ void k_count(const int* __restrict__ senders, int* __restrict__ cnt){
  int e = blockIdx.x*256 + threadIdx.x;
  if(e < E_EDGES) atomicAdd(&cnt[senders[e]], 1);
}
__global__ __launch_bounds__(1024) void k_scan(const int* __restrict__ cnt, int* __restrict__ off, int* __restrict__ cur){
  __shared__ int part[1024];
  int t = threadIdx.x;
  int c0=cnt[4*t], c1=cnt[4*t+1], c2=cnt[4*t+2], c3=cnt[4*t+3];
  int l0=0, l1=c0, l2=c0+c1, l3=c0+c1+c2;
  int sum=l3+c3;
  part[t]=sum; __syncthreads();
  for(int st=1; st<1024; st<<=1){
    int v = part[t];
    int add = (t>=st)? part[t-st] : 0;
    __syncthreads();
    part[t] = v + add;
    __syncthreads();
  }
  int pref = (t>0)? part[t-1] : 0;
  off[4*t]=pref+l0; off[4*t+1]=pref+l1; off[4*t+2]=pref+l2; off[4*t+3]=pref+l3;
  cur[4*t]=pref+l0; cur[4*t+1]=pref+l1; cur[4*t+2]=pref+l2; cur[4*t+3]=pref+l3;
}
__global__ void k_scatter(const int* __restrict__ senders, int* __restrict__ cur, int* __restrict__ sorted){
  int e = blockIdx.x*256 + threadIdx.x;
  if(e < E_EDGES){
    int pos = atomicAdd(&cur[senders[e]], 1);
    sorted[pos] = e;
  }
}

// pack Wl1/Wl2 into bf16 hi/lo MFMA B-fragments.
// layout: [mp(4)][ks(10)][nt(4)][lane(64)][8 bf16], mp = matrix*2 + part.
// frag convention (MUST match A-pack in k_main): col = nt*16 + (lane&15),
// k = ks*32 + (lane>>4)*8 + j.  (consistent A/B k-mapping => correct dot
// product under any HW k-permutation.)
__global__ __launch_bounds__(256) void k_wpack(const float* __restrict__ Wl1, const float* __restrict__ Wl2,
                                               float* __restrict__ wpk){
  int idx = blockIdx.x*256 + threadIdx.x;   // 40 blocks = 10240 threads
  int lane = idx & 63;
  int nt   = (idx >> 6) & 3;
  int rest = idx >> 8;            // mp*10 + ks
  int ks = rest % 10;
  int mp = rest / 10;             // 0..3
  int p = mp & 1, m = mp >> 1;
  const float* W = m ? Wl2 : Wl1;
  int c = nt*16 + (lane & 15);
  int g = lane >> 4;
  bf16x8 outv;
  #pragma unroll
  for(int j=0;j<8;j++){
    int k = ks*32 + g*8 + j;
    float v = W[k*64 + c];
    __bf16 hb = (__bf16)v;
    if(p==0){ outv[j] = hb; }
    else    { outv[j] = (__bf16)(v - (float)hb); }
  }
  ((bf16x8*)wpk)[idx] = outv;
}

// per edge: w = x@Ww/8 (lane=mul), Y[16] spherical harmonics
__global__ __launch_bounds__(256) void k_edge_pre(
    const float* __restrict__ vectors, const float* __restrict__ x,
    const float* __restrict__ Ww, float* __restrict__ ws){
  int wv = threadIdx.x >> 6, lane = threadIdx.x & 63;
  int e = blockIdx.x*4 + wv;
  const float* w112 = ws + O_W112;
  const float* w213 = ws + O_W213;
  float C2v = ws[678], C3v = ws[679];
  float v0=vectors[e*3], v1=vectors[e*3+1], v2=vectors[e*3+2];
  float len = sqrtf(v0*v0+v1*v1+v2*v2);
  float inv = 1.0f/(len + 1e-12f);
  float s3 = 1.7320508075688772f;
  float y1v[3] = { s3*v0*inv, s3*v1*inv, s3*v2*inv };
  float y2[5];
  #pragma unroll
  for(int k=0;k<5;k++){
    float a=0.f;
    #pragma unroll
    for(int i=0;i<3;i++)
      #pragma unroll
      for(int j=0;j<3;j++) a += y1v[i]*y1v[j]*w112[(i*3+j)*5+k];
    y2[k]=C2v*a;
  }
  float y3[7];
  #pragma unroll
  for(int n=0;n<7;n++){
    float a=0.f;
    #pragma unroll
    for(int i=0;i<5;i++)
      #pragma unroll
      for(int j=0;j<3;j++) a += y2[i]*y1v[j]*w213[(i*3+j)*7+n];
    y3[n]=C3v*a;
  }
  // w
  float acc=0.f;
  for(int k=0;k<64;k++) acc += x[e*64+k]*Ww[k*64+lane];
  ws[WS_W + e*64 + lane] = acc*0.125f;
  if(lane==0){
    float* Yp = ws + WS_Y + e*16;
    Yp[0]=1.0f;
    Yp[1]=y1v[0]; Yp[2]=y1v[1]; Yp[3]=y1v[2];
    Yp[4]=y2[0]; Yp[5]=y2[1]; Yp[6]=y2[2]; Yp[7]=y2[3]; Yp[8]=y2[4];
    Yp[9]=y3[0]; Yp[10]=y3[1]; Yp[11]=y3[2]; Yp[12]=y3[3]; Yp[13]=y3[4]; Yp[15]=y3[6]; Yp[14]=y3[5];
  }
}

// per node: A[n][m][k] = eps * sum_e w[e][m]*Y[e][k]
__global__ __launch_bounds__(64) void k_node_acc(
    const float* __restrict__ ws_w, const float* __restrict__ ws_y,
    const int* __restrict__ sorted, const int* __restrict__ off, const int* __restrict__ cnt,
    float* __restrict__ A){
  int n = blockIdx.x, m = threadIdx.x;
  float acc[16];
  #pragma unroll
  for(int k=0;k<16;k++) acc[k]=0.f;
  int o = off[n], c = cnt[n];
  for(int j=0;j<c;j++){
    int e = sorted[o+j];
    float wm = ws_w[e*64+m];
    const float* Yp = ws_y + e*16;
    #pragma unroll
    for(int k=0;k<16;k++) acc[k] += wm*Yp[k];
  }
  float4* outp = (float4*)(A + n*1024 + m*16);
  outp[0] = make_float4(acc[0]*0.25f, acc[1]*0.25f, acc[2]*0.25f, acc[3]*0.25f);
  outp[1] = make_float4(acc[4]*0.25f, acc[5]*0.25f, acc[6]*0.25f, acc[7]*0.25f);
  outp[2] = make_float4(acc[8]*0.25f, acc[9]*0.25f, acc[10]*0.25f, acc[11]*0.25f);
  outp[3] = make_float4(acc[12]*0.25f, acc[13]*0.25f, acc[14]*0.25f, acc[15]*0.25f);
}

__device__ inline void split8(const float* p, bf16x8& h, bf16x8& l){
  f32x4 a0 = *(const f32x4*)p;
  f32x4 a1 = *(const f32x4*)(p+4);
  float av[8] = {a0[0],a0[1],a0[2],a0[3],a1[0],a1[1],a1[2],a1[3]};
  #pragma unroll
  for(int j=0;j<8;j++){
    __bf16 hb = (__bf16)av[j];
    h[j] = hb;
    l[j] = (__bf16)(av[j] - (float)hb);
  }
}

// main fused kernel: 4 edges per block (sorted order for A-gather locality)
// LDS ~50.0 KB -> 3 blocks/CU; barriers per block: 4.
// pd rows: 0..11 = P (e*3+i), 12..31 = D (12+e*5+j); stride 324 (4-bank row
// rotation keeps A-frag ds_read_b128s conflict-minimal; 16B-aligned rows).
// phase-2 = MFMA (bf16 hi/lo 2-term split, 3 mfma per tile per k-step):
//   GEMM-P: C[16(12 used)][64] = pdP x Wl1;  GEMM-D: 2 M-tiles over 20 rows.
//   error ~2^-15 relative (hi*hi + hi*lo + lo*hi), ~= fp32 reassociation noise.
__global__ __launch_bounds__(256, 3) void k_main(
    const float* __restrict__ vectors, const float* __restrict__ x, const float* __restrict__ V,
    const int* __restrict__ senders,
    const float* __restrict__ W1, const float* __restrict__ W2, const float* __restrict__ W3,
    const float* __restrict__ ws, const int* __restrict__ sorted,
    float* __restrict__ out){
  __shared__ __align__(16) float lds_pd[32*324];   // 41472 B
  __shared__ float lds_h[4*257];                   // 4112 B  h_in = [x | S]
  __shared__ float lds_mlp[2*4*65];                // 2080 B  MLP h1/h2 scratch
  __shared__ float lds_w3j[573];                   // 2292 B
  __shared__ float lds_env[4];
  __shared__ int   lds_eid[4];

  int t = threadIdx.x;
  for(int i=t;i<573;i+=256) lds_w3j[i]=ws[i];
  int wv = t>>6, lane = t&63;
  int eid = sorted[blockIdx.x*4 + wv];
  if(lane==0) lds_eid[wv]=eid;
  __syncthreads();

  const float* lw = lds_w3j;
  // ---- phase 1: per-edge (one wave per edge) ----
  {
    float v0=vectors[eid*3], v1=vectors[eid*3+1], v2=vectors[eid*3+2];
    float d = sqrtf(v0*v0+v1*v1+v2*v2);
    float d2=d*d, d4=d2*d2, d6=d4*d2, d7=d6*d, d8=d7*d;
    float env = 1.0f - 28.0f*d6 + 48.0f*d7 - 21.0f*d8;
    env = (d < 1.0f) ? env : 0.0f;
    if(lane==0) lds_env[wv]=env;
  }
  int snd = senders[eid];
  const float4* Ap4 = (const float4*)(ws + WS_A + snd*1024 + lane*16);
  float4 a0=Ap4[0], a1=Ap4[1], a2=Ap4[2], a3=Ap4[3];
  float wY[16] = {a0.x,a0.y,a0.z,a0.w, a1.x,a1.y,a1.z,a1.w,
                  a2.x,a2.y,a2.z,a2.w, a3.x,a3.y,a3.z,a3.w};
  const float* Vp = V + eid*576;
  float V0 = Vp[lane];
  float V1f[3], V2f[5];
  #pragma unroll
  for(int i=0;i<3;i++) V1f[i]=Vp[64+lane*3+i];
  #pragma unroll
  for(int j=0;j<5;j++) V2f[j]=Vp[256+lane*5+j];
  lds_h[wv*257 + lane] = x[eid*64+lane];
  // scalar channel S
  float s0 = wY[0]*V0*lw[O_W000];
  float s1 = 0.f;
  #pragma unroll
  for(int i=0;i<3;i++)
    #pragma unroll
    for(int j=0;j<3;j++) s1 += wY[1+i]*V1f[j]*lw[O_W110 + i*3+j];
  float s2 = 0.f;
  #pragma unroll
  for(int i=0;i<5;i++)
    #pragma unroll
    for(int j=0;j<5;j++) s2 += wY[4+i]*V2f[j]*lw[O_W220 + i*5+j];
  lds_h[wv*257+64+lane]=s0;
  lds_h[wv*257+128+lane]=s1;
  lds_h[wv*257+192+lane]=s2;
  // P paths (l3=1): i=0..2.  D paths (l3=2): j=0..4.
  float P0[3]={0,0,0}, P1[3]={0,0,0}, P2[3]={0,0,0}, P3[3]={0,0,0}, P4[3]={0,0,0};
  float D0[5]={0,0,0,0,0}, D1[5]={0,0,0,0,0}, D2[5]={0,0,0,0,0}, D3[5]={0,0,0,0,0}, D4[5]={0,0,0,0,0};
  #pragma unroll
  for(int b=0;b<3;b++){ float pb=wY[0]*V1f[b];
    #pragma unroll
    for(int i=0;i<3;i++) P0[i]+= pb*lw[O_W011 + b*3+i]; }
  #pragma unroll
  for(int a=0;a<3;a++){ float pa=wY[1+a]*V0;
    #pragma unroll
    for(int i=0;i<3;i++) P1[i]+= pa*lw[O_W101 + a*3+i]; }
  #pragma unroll
  for(int a=0;a<3;a++)
    #pragma unroll
    for(int b=0;b<5;b++){ float p=wY[1+a]*V2f[b];
      #pragma unroll
      for(int i=0;i<3;i++) P2[i]+= p*lw[O_W121 + (a*5+b)*3+i]; }
  #pragma unroll
  for(int a=0;a<5;a++)
    #pragma unroll
    for(int b=0;b<3;b++){ float p=wY[4+a]*V1f[b];
      #pragma unroll
      for(int i=0;i<3;i++) P3[i]+= p*lw[O_W211 + (a*3+b)*3+i]; }
  #pragma unroll
  for(int a=0;a<7;a++)
    #pragma unroll
    for(int b=0;b<5;b++){ float p=wY[9+a]*V2f[b];
      #pragma unroll
      for(int i=0;i<3;i++) P4[i]+= p*lw[O_W321 + (a*5+b)*3+i]; }
  #pragma unroll
  for(int b=0;b<5;b++){ float pb=wY[0]*V2f[b];
    #pragma unroll
    for(int j=0;j<5;j++) D0[j]+= pb*lw[O_W022 + b*5+j]; }
  #pragma unroll
  for(int a=0;a<3;a++)
    #pragma unroll
    for(int b=0;b<3;b++){ float p=wY[1+a]*V1f[b];
      #pragma unroll
      for(int j=0;j<5;j++) D1[j]+= p*lw[O_W112 + (a*3+b)*5+j]; }
  #pragma unroll
  for(int a=0;a<5;a++){ float pa=wY[4+a]*V0;
    #pragma unroll
    for(int j=0;j<5;j++) D2[j]+= pa*lw[O_W202 + a*5+j]; }
  #pragma unroll
  for(int a=0;a<5;a++)
    #pragma unroll
    for(int b=0;b<5;b++){ float p=wY[4+a]*V2f[b];
      #pragma unroll
      for(int j=0;j<5;j++) D3[j]+= p*lw[O_W222 + (a*5+b)*5+j]; }
  #pragma unroll
  for(int a=0;a<7;a++)
    #pragma unroll
    for(int b=0;b<3;b++){ float p=wY[9+a]*V1f[b];
      #pragma unroll
      for(int j=0;j<5;j++) D4[j]+= p*lw[O_W312 + (a*3+b)*5+j]; }
  // stage into lds_pd (fold sqrt(2*l3+1)); lane stride-1 -> conflict-free.
  // rows: P -> wv*3+i (0..11); D -> 12 + wv*5 + j (12..31)
  {
    const float SQ3 = 1.7320508075688772f, SQ5 = 2.2360679774997896f;
    #pragma unroll
    for(int i=0;i<3;i++){
      lds_pd[(wv*3+i)*324 + 0*64+lane] = SQ3*P0[i];
      lds_pd[(wv*3+i)*324 + 1*64+lane] = SQ3*P1[i];
      lds_pd[(wv*3+i)*324 + 2*64+lane] = SQ3*P2[i];
      lds_pd[(wv*3+i)*324 + 3*64+lane] = SQ3*P3[i];
      lds_pd[(wv*3+i)*324 + 4*64+lane] = SQ3*P4[i];
    }
    #pragma unroll
    for(int j=0;j<5;j++){
      lds_pd[(12+wv*5+j)*324 + 0*64+lane] = SQ5*D0[j];
      lds_pd[(12+wv*5+j)*324 + 1*64+lane] = SQ5*D1[j];
      lds_pd[(12+wv*5+j)*324 + 2*64+lane] = SQ5*D2[j];
      lds_pd[(12+wv*5+j)*324 + 3*64+lane] = SQ5*D3[j];
      lds_pd[(12+wv*5+j)*324 + 4*64+lane] = SQ5*D4[j];
    }
  }
  __syncthreads();

  // ---- MLP (block-level; thread = (edge, feature)) ----
  {
    int eL = t>>6, f = t&63;
    float acc=0.f;
    for(int k=0;k<256;k++) acc += lds_h[eL*257+k]*W1[k*64+f];
    acc *= (1.0f/16.0f);
    float h1 = acc/(1.0f+__expf(-acc));
    float* lh1 = lds_mlp;
    lh1[eL*65+f] = h1;
    __syncthreads();
    acc=0.f;
    for(int k=0;k<64;k++) acc += lh1[eL*65+k]*W2[k*64+f];
    acc *= 0.125f;
    float h2 = acc/(1.0f+__expf(-acc));
    float* lh2 = lds_mlp + 4*65;
    lh2[eL*65+f] = h2;
    __syncthreads();
    acc=0.f;
    for(int k=0;k<64;k++) acc += lh2[eL*65+k]*W3[k*64+f];
    acc *= 0.125f;
    out[lds_eid[eL]*576 + f] = lds_env[eL]*acc;
  }

  // ---- phase 2: MFMA projections. wave = N-tile (nt = wv), 16 u-cols each.
  // A from lds_pd fp32 -> bf16 hi/lo on the fly; B pre-packed in ws+WS_W.
  {
    int g = lane >> 4, r = lane & 15;
    const bf16x8* WB = (const bf16x8*)(ws + WS_W);   // [mp][ks][nt][lane]
    f32x4 accP  = {0.f,0.f,0.f,0.f};
    f32x4 accD0 = {0.f,0.f,0.f,0.f};
    f32x4 accD1 = {0.f,0.f,0.f,0.f};
    int rP  = (r < 12) ? r : 11;          // clamp: C rows 12-15 discarded
    int rD0 = 12 + r;                     // D rows 0..15
    int rD1 = 12 + ((r < 4) ? (16 + r) : 19);  // D rows 16..19; rest clamped
    const float* apP  = lds_pd + rP *324 + g*8;
    const float* apD0 = lds_pd + rD0*324 + g*8;
    const float* apD1 = lds_pd + rD1*324 + g*8;
    #pragma unroll 2
    for(int ks=0; ks<10; ks++){
      int bbase = (ks*4 + wv)*64 + lane;
      bf16x8 b1h = WB[bbase];             // Wl1 hi
      bf16x8 b1l = WB[bbase + 2560];      // Wl1 lo
      bf16x8 b2h = WB[bbase + 5120];      // Wl2 hi
      bf16x8 b2l = WB[bbase + 7680];      // Wl2 lo
      bf16x8 aPh, aPl, aD0h, aD0l, aD1h, aD1l;
      split8(apP  + ks*32, aPh,  aPl);
      split8(apD0 + ks*32, aD0h, aD0l);
      split8(apD1 + ks*32, aD1h, aD1l);
      accP  = __builtin_amdgcn_mfma_f32_16x16x32_bf16(aPh,  b1h, accP,  0,0,0);
      accP  = __builtin_amdgcn_mfma_f32_16x16x32_bf16(aPh,  b1l, accP,  0,0,0);
      accP  = __builtin_amdgcn_mfma_f32_16x16x32_bf16(aPl,  b1h, accP,  0,0,0);
      accD0 = __builtin_amdgcn_mfma_f32_16x16x32_bf16(aD0h, b2h, accD0, 0,0,0);
      accD0 = __builtin_amdgcn_mfma_f32_16x16x32_bf16(aD0h, b2l, accD0, 0,0,0);
      accD0 = __builtin_amdgcn_mfma_f32_16x16x32_bf16(aD0l, b2h, accD0, 0,0,0);
      accD1 = __builtin_amdgcn_mfma_f32_16x16x32_bf16(aD1h, b2h, accD1, 0,0,0);
      accD1 = __builtin_amdgcn_mfma_f32_16x16x32_bf16(aD1h, b2l, accD1, 0,0,0);
      accD1 = __builtin_amdgcn_mfma_f32_16x16x32_bf16(aD1l, b2h, accD1, 0,0,0);
    }
    // C layout (m89-verified): col = lane&15, row = (lane>>4)*4 + reg
    const float sc = 0.05590169943749474f;  // 1/sqrt(320)
    int u = wv*16 + r;
    if(g < 3){
      #pragma unroll
      for(int reg=0; reg<4; reg++){
        int R = g*4 + reg;                 // 0..11 : P row = e*3 + i
        int e_ = R/3, i_ = R - e_*3;
        out[lds_eid[e_]*576 + 64 + u*3 + i_] = accP[reg]*sc;
      }
    }
    #pragma unroll
    for(int reg=0; reg<4; reg++){
      int Dr = g*4 + reg;                  // 0..15 : D row = e*5 + j
      int e_ = Dr/5, j_ = Dr - e_*5;
      out[lds_eid[e_]*576 + 256 + u*5 + j_] = accD0[reg]*sc;
    }
    if(g == 0){
      #pragma unroll
      for(int reg=0; reg<4; reg++){
        int Dr = 16 + reg;                 // 16..19 -> e=3, j=1..4
        int e_ = Dr/5, j_ = Dr - e_*5;
        out[lds_eid[e_]*576 + 256 + u*5 + j_] = accD1[reg]*sc;
      }
    }
  }
}

extern "C" void kernel_launch(void* const* d_in, const int* in_sizes, int n_in,
                              void* d_out, int out_size, void* d_ws, size_t ws_size,
                              hipStream_t stream) {
  const float* vectors=(const float*)d_in[0];
  const float* x      =(const float*)d_in[1];
  const float* V      =(const float*)d_in[2];
  const int*   senders=(const int*)  d_in[3];
  const float* Ww     =(const float*)d_in[4];
  const float* W1     =(const float*)d_in[5];
  const float* W2     =(const float*)d_in[6];
  const float* W3     =(const float*)d_in[7];
  const float* Wl1    =(const float*)d_in[8];
  const float* Wl2    =(const float*)d_in[9];
  float* ws  = (float*)d_ws;
  float* out = (float*)d_out;
  int* cnt    = (int*)(ws + WS_CNT);
  int* off    = (int*)(ws + WS_OFF);
  int* cur    = (int*)(ws + WS_CUR);
  int* sorted = (int*)(ws + WS_SORT);

  k_w3j   <<<14, 128, 0, stream>>>(ws);
  k_c2c3  <<<1, 1, 0, stream>>>(ws);
  k_zero  <<<16, 256, 0, stream>>>(cnt);
  k_count <<<E_EDGES/256, 256, 0, stream>>>(senders, cnt);
  k_scan  <<<1, 1024, 0, stream>>>(cnt, off, cur);
  k_scatter<<<E_EDGES/256, 256, 0, stream>>>(senders, cur, sorted);
  k_edge_pre<<<E_EDGES/4, 256, 0, stream>>>(vectors, x, Ww, ws);
  k_node_acc<<<N_NODES, 64, 0, stream>>>(ws + WS_W, ws + WS_Y, sorted, off, cnt, ws + WS_A);
  // pack AFTER k_node_acc (reuses the then-dead WS_W region)
  k_wpack <<<40, 256, 0, stream>>>(Wl1, Wl2, ws + WS_W);
  k_main  <<<E_EDGES/4, 256, 0, stream>>>(vectors, x, V, senders, W1, W2, W3,
                                          ws, sorted, out);
}

// Round 4
// 661.320 us; speedup vs baseline: 2.9296x; 1.1485x over previous
//
#include <hip/hip_runtime.h>

#define E_EDGES 65536
#define N_NODES 4096

// ---- workspace layout (float offsets) ----
// [0,678)   w3j tensors, [678] C2, [679] C3  (reserve 1024)
#define WS_W     1024                       // E*64   w = x@Ww/8  (dead after k_node_acc; reused for packed weights)
#define WS_Y     (WS_W + E_EDGES*64)        // E*16   Y
#define WS_CNT   (WS_Y + E_EDGES*16)        // 4096 int
#define WS_OFF   (WS_CNT + N_NODES)         // 4096 int
#define WS_CUR   (WS_OFF + N_NODES)         // 4096 int
#define WS_SORT  (WS_CUR + N_NODES)         // E int
#define WS_A     (WS_SORT + E_EDGES)        // N*1024  node accumulator (eps folded)
// high-water: WS_A + 4096*1024 = 9,516,032 floats ~= 38.1 MB

typedef __bf16 bf16x8 __attribute__((ext_vector_type(8)));
typedef float  f32x4  __attribute__((ext_vector_type(4)));

// packed-weight fragment offsets (units of bf16x8 = 16 B), base ws+WS_W
//   Wl1h 0 | Wl1l 2560 | Wl2h 5120 | Wl2l 7680   (10 ks x 4 nt x 64 lanes)
//   W1h 10240 | W1l 12288                        (8 ks x 4 nt x 64)
//   W2h 14336 | W2l 14848 | W3h 15360 | W3l 15872 (2 ks x 4 nt x 64)
#define PK_WL   0
#define PK_W1   10240
#define PK_W2   14336
#define PK_W3   15360

// key order: (0,0,0),(1,1,0),(2,2,0),(0,1,1),(1,0,1),(1,2,1),(2,1,1),(3,2,1),
//            (0,2,2),(1,1,2),(2,0,2),(2,2,2),(3,1,2),(2,1,3)
__constant__ int gK_L1[14] = {0,1,2,0,1,1,2,3,0,1,2,2,3,2};
__constant__ int gK_L2[14] = {0,1,2,1,0,2,1,2,2,1,0,2,1,1};
__constant__ int gK_L3[14] = {0,0,0,1,1,1,1,1,2,2,2,2,2,3};
__constant__ int gK_OFF[14]= {0,1,10,35,44,53,98,143,248,273,318,343,468,573};
__constant__ double gFact[8] = {1.,1.,2.,6.,24.,120.,720.,5040.};

// w3j offsets (compile-time)
#define O_W000 0
#define O_W110 1
#define O_W220 10
#define O_W011 35
#define O_W101 44
#define O_W121 53
#define O_W211 98
#define O_W321 143
#define O_W022 248
#define O_W112 273
#define O_W202 318
#define O_W222 343
#define O_W312 468
#define O_W213 573

__device__ double su2_cg(int j1,int j2,int j3,int m1,int m2,int m3){
  if (m3 != m1+m2) return 0.0;
  double pref = sqrt((double)(2*j3+1)*gFact[j3+j1-j2]*gFact[j3-j1+j2]*gFact[j1+j2-j3]/gFact[j1+j2+j3+1]);
  pref *= sqrt(gFact[j3+m3]*gFact[j3-m3]*gFact[j1-m1]*gFact[j1+m1]*gFact[j2-m2]*gFact[j2+m2]);
  double s=0.0;
  for(int k=0;k<=j1+j2-j3;k++){
    int d1=j1+j2-j3-k, d2=j1-m1-k, d3=j2+m2-k, d4=j3-j2+m1+k, d5=j3-j1-m2+k;
    if(d1<0||d2<0||d3<0||d4<0||d5<0) continue;
    double den=gFact[k]*gFact[d1]*gFact[d2]*gFact[d3]*gFact[d4]*gFact[d5];
    s += (k&1)? (-1.0/den) : (1.0/den);
  }
  return pref*s;
}

__device__ void fill_qmat(int l, double2* q){  // 7x7 row-major, rows=m-basis, cols=real-basis
  for(int i=0;i<49;i++){ q[i].x=0.0; q[i].y=0.0; }
  const double is2 = 0.7071067811865475244;
  for(int m=-l;m<0;m++){
    q[(l+m)*7+(l-m)].x = is2;     // q[l+m, l+|m|] = 1/sqrt2
    q[(l+m)*7+(l+m)].y = -is2;    // q[l+m, l-|m|] = -1j/sqrt2
  }
  q[l*7+l].x = 1.0;
  for(int m=1;m<=l;m++){
    double sg = (m&1)? -1.0 : 1.0;
    q[(l+m)*7+(l+m)].x = sg*is2;
    q[(l+m)*7+(l-m)].y = sg*is2;
  }
  double pr, pi;  // (-i)^l
  switch(l&3){ case 0: pr=1;pi=0;break; case 1: pr=0;pi=-1;break; case 2: pr=-1;pi=0;break; default: pr=0;pi=1;break; }
  for(int i=0;i<49;i++){
    double a=q[i].x, b=q[i].y;
    q[i].x = a*pr - b*pi;
    q[i].y = a*pi + b*pr;
  }
}

__global__ __launch_bounds__(128) void k_w3j(float* __restrict__ ws){
  __shared__ double2 q1[49], q2[49], q3[49];
  __shared__ double C[125], Cr[125];
  __shared__ double red[128];
  int bid = blockIdx.x, t = threadIdx.x;
  int l1=gK_L1[bid], l2=gK_L2[bid], l3=gK_L3[bid];
  int n1=2*l1+1, n2=2*l2+1, n3=2*l3+1, ntot=n1*n2*n3;
  if(t==0){
    fill_qmat(l1,q1); fill_qmat(l2,q2); fill_qmat(l3,q3);
    for(int i=0;i<49;i++) q3[i].y = -q3[i].y;   // conj
  }
  __syncthreads();
  for(int idx=t; idx<ntot; idx+=128){
    int a = idx/(n2*n3), r=idx%(n2*n3), b=r/n3, c=r%n3;
    C[idx] = su2_cg(l1,l2,l3, a-l1, b-l2, c-l3);
  }
  __syncthreads();
  for(int idx=t; idx<ntot; idx+=128){
    int i = idx/(n2*n3), r=idx%(n2*n3), j=r/n3, k=r%n3;
    double ar=0.0;
    for(int a=0;a<n1;a++) for(int b=0;b<n2;b++){
      double2 qa=q1[a*7+i], qb=q2[b*7+j];
      double pr = qa.x*qb.x - qa.y*qb.y;
      double pi = qa.x*qb.y + qa.y*qb.x;
      for(int c=0;c<n3;c++){
        double2 qc=q3[c*7+k];
        double tr = pr*qc.x - pi*qc.y;
        ar += tr*C[(a*n2+b)*n3+c];
      }
    }
    Cr[idx]=ar;
  }
  __syncthreads();
  double ss=0.0;
  for(int idx=t; idx<ntot; idx+=128) ss += Cr[idx]*Cr[idx];
  red[t]=ss; __syncthreads();
  for(int st=64; st>0; st>>=1){ if(t<st) red[t]+=red[t+st]; __syncthreads(); }
  double inv = 1.0/sqrt(red[0]);
  for(int idx=t; idx<ntot; idx+=128) ws[gK_OFF[bid]+idx] = (float)(Cr[idx]*inv);
}

__global__ void k_c2c3(float* __restrict__ ws){
  const float* w112 = ws + O_W112;
  const float* w213 = ws + O_W213;
  double u0=0.3, u1=-0.4, u2=sqrt(0.75);
  double s3=sqrt(3.0);
  double y1[3]={s3*u0, s3*u1, s3*u2};
  double y2r[5]={0,0,0,0,0};
  for(int i=0;i<3;i++) for(int j=0;j<3;j++) for(int k=0;k<5;k++)
    y2r[k] += y1[i]*y1[j]*(double)w112[(i*3+j)*5+k];
  double nn=0; for(int k=0;k<5;k++) nn += y2r[k]*y2r[k];
  double c2 = sqrt(5.0)/sqrt(nn);
  double y2[5]; for(int k=0;k<5;k++) y2[k]=c2*y2r[k];
  double y3r[7]={0,0,0,0,0,0,0};
  for(int i=0;i<5;i++) for(int j=0;j<3;j++) for(int n=0;n<7;n++)
    y3r[n] += y2[i]*y1[j]*(double)w213[(i*3+j)*7+n];
  nn=0; for(int n=0;n<7;n++) nn += y3r[n]*y3r[n];
  double c3 = sqrt(7.0)/sqrt(nn);
  ws[678]=(float)c2; ws[679]=(float)c3;
}

__global__ void k_zero(int* __restrict__ cnt){
  int i = blockIdx.x*256 + threadIdx.x;
  if(i < N_NODES) cnt[i]=0;
}
__global__ void k_count(const int* __restrict__ senders, int* __restrict__ cnt){
  int e = blockIdx.x*256 + threadIdx.x;
  if(e < E_EDGES) atomicAdd(&cnt[senders[e]], 1);
}
__global__ __launch_bounds__(1024) void k_scan(const int* __restrict__ cnt, int* __restrict__ off, int* __restrict__ cur){
  __shared__ int part[1024];
  int t = threadIdx.x;
  int c0=cnt[4*t], c1=cnt[4*t+1], c2=cnt[4*t+2], c3=cnt[4*t+3];
  int l0=0, l1=c0, l2=c0+c1, l3=c0+c1+c2;
  int sum=l3+c3;
  part[t]=sum; __syncthreads();
  for(int st=1; st<1024; st<<=1){
    int v = part[t];
    int add = (t>=st)? part[t-st] : 0;
    __syncthreads();
    part[t] = v + add;
    __syncthreads();
  }
  int pref = (t>0)? part[t-1] : 0;
  off[4*t]=pref+l0; off[4*t+1]=pref+l1; off[4*t+2]=pref+l2; off[4*t+3]=pref+l3;
  cur[4*t]=pref+l0; cur[4*t+1]=pref+l1; cur[4*t+2]=pref+l2; cur[4*t+3]=pref+l3;
}
__global__ void k_scatter(const int* __restrict__ senders, int* __restrict__ cur, int* __restrict__ sorted){
  int e = blockIdx.x*256 + threadIdx.x;
  if(e < E_EDGES){
    int pos = atomicAdd(&cur[senders[e]], 1);
    sorted[pos] = e;
  }
}

// pack Wl1/Wl2/W1/W2/W3 into bf16 hi/lo MFMA B-fragments.
// frag convention (matches A-pack in k_main): col = nt*16 + (lane&15),
// k = ks*32 + (lane>>4)*8 + j.  (consistent A/B k-mapping => correct dot
// product under any HW k-permutation.)
__global__ __launch_bounds__(256) void k_wpack(
    const float* __restrict__ Wl1, const float* __restrict__ Wl2,
    const float* __restrict__ W1, const float* __restrict__ W2,
    const float* __restrict__ W3, float* __restrict__ wpk){
  int idx = blockIdx.x*256 + threadIdx.x;   // 64 blocks = 16384 frags
  int lane = idx & 63;
  const float* W; int part, ks, nt;
  if(idx < PK_W1){                       // Wl1/Wl2: [mp][ks10][nt][lane]
    nt = (idx>>6)&3; int rest = idx>>8; ks = rest%10; int mp = rest/10;
    part = mp&1; W = (mp>>1)? Wl2 : Wl1;
  } else if(idx < PK_W2){                // W1: [part][ks8][nt][lane]
    int rel = idx - PK_W1; part = rel>>11; int r2 = rel & 2047;
    ks = r2>>8; nt = (r2>>6)&3; W = W1;
  } else if(idx < PK_W3){                // W2: [part][ks2][nt][lane]
    int rel = idx - PK_W2; part = rel>>9; int r2 = rel & 511;
    ks = r2>>8; nt = (r2>>6)&3; W = W2;
  } else {                               // W3: [part][ks2][nt][lane]
    int rel = idx - PK_W3; part = rel>>9; int r2 = rel & 511;
    ks = r2>>8; nt = (r2>>6)&3; W = W3;
  }
  int c = nt*16 + (lane & 15);
  int g = lane >> 4;
  bf16x8 outv;
  #pragma unroll
  for(int j=0;j<8;j++){
    int k = ks*32 + g*8 + j;
    float v = W[k*64 + c];
    __bf16 hb = (__bf16)v;
    outv[j] = part ? (__bf16)(v - (float)hb) : hb;
  }
  ((bf16x8*)wpk)[idx] = outv;
}

// per edge: w = x@Ww/8 (lane=mul), Y[16] spherical harmonics
__global__ __launch_bounds__(256) void k_edge_pre(
    const float* __restrict__ vectors, const float* __restrict__ x,
    const float* __restrict__ Ww, float* __restrict__ ws){
  int wv = threadIdx.x >> 6, lane = threadIdx.x & 63;
  int e = blockIdx.x*4 + wv;
  const float* w112 = ws + O_W112;
  const float* w213 = ws + O_W213;
  float C2v = ws[678], C3v = ws[679];
  float v0=vectors[e*3], v1=vectors[e*3+1], v2=vectors[e*3+2];
  float len = sqrtf(v0*v0+v1*v1+v2*v2);
  float inv = 1.0f/(len + 1e-12f);
  float s3 = 1.7320508075688772f;
  float y1v[3] = { s3*v0*inv, s3*v1*inv, s3*v2*inv };
  float y2[5];
  #pragma unroll
  for(int k=0;k<5;k++){
    float a=0.f;
    #pragma unroll
    for(int i=0;i<3;i++)
      #pragma unroll
      for(int j=0;j<3;j++) a += y1v[i]*y1v[j]*w112[(i*3+j)*5+k];
    y2[k]=C2v*a;
  }
  float y3[7];
  #pragma unroll
  for(int n=0;n<7;n++){
    float a=0.f;
    #pragma unroll
    for(int i=0;i<5;i++)
      #pragma unroll
      for(int j=0;j<3;j++) a += y2[i]*y1v[j]*w213[(i*3+j)*7+n];
    y3[n]=C3v*a;
  }
  // w
  float acc=0.f;
  for(int k=0;k<64;k++) acc += x[e*64+k]*Ww[k*64+lane];
  ws[WS_W + e*64 + lane] = acc*0.125f;
  if(lane==0){
    float* Yp = ws + WS_Y + e*16;
    Yp[0]=1.0f;
    Yp[1]=y1v[0]; Yp[2]=y1v[1]; Yp[3]=y1v[2];
    Yp[4]=y2[0]; Yp[5]=y2[1]; Yp[6]=y2[2]; Yp[7]=y2[3]; Yp[8]=y2[4];
    Yp[9]=y3[0]; Yp[10]=y3[1]; Yp[11]=y3[2]; Yp[12]=y3[3]; Yp[13]=y3[4]; Yp[15]=y3[6]; Yp[14]=y3[5];
  }
}

// per node: A[n][m][k] = eps * sum_e w[e][m]*Y[e][k]
__global__ __launch_bounds__(64) void k_node_acc(
    const float* __restrict__ ws_w, const float* __restrict__ ws_y,
    const int* __restrict__ sorted, const int* __restrict__ off, const int* __restrict__ cnt,
    float* __restrict__ A){
  int n = blockIdx.x, m = threadIdx.x;
  float acc[16];
  #pragma unroll
  for(int k=0;k<16;k++) acc[k]=0.f;
  int o = off[n], c = cnt[n];
  for(int j=0;j<c;j++){
    int e = sorted[o+j];
    float wm = ws_w[e*64+m];
    const float* Yp = ws_y + e*16;
    #pragma unroll
    for(int k=0;k<16;k++) acc[k] += wm*Yp[k];
  }
  float4* outp = (float4*)(A + n*1024 + m*16);
  outp[0] = make_float4(acc[0]*0.25f, acc[1]*0.25f, acc[2]*0.25f, acc[3]*0.25f);
  outp[1] = make_float4(acc[4]*0.25f, acc[5]*0.25f, acc[6]*0.25f, acc[7]*0.25f);
  outp[2] = make_float4(acc[8]*0.25f, acc[9]*0.25f, acc[10]*0.25f, acc[11]*0.25f);
  outp[3] = make_float4(acc[12]*0.25f, acc[13]*0.25f, acc[14]*0.25f, acc[15]*0.25f);
}

__device__ inline void split1(float v, __bf16& h, __bf16& l){
  h = (__bf16)v;
  l = (__bf16)(v - (float)h);
}

// main fused kernel: 4 edges per block (sorted order for A-gather locality)
// LDS ~50.7 KB -> 3 blocks/CU; barriers per block: 4.
// pd stored as bf16 hi/lo (converted ONCE at phase-1 write) -> phase-2 reads
// MFMA A-frags directly via ds_read_b128, zero per-k-step conversion VALU.
// MLP also on MFMA: M=4 rows duplicate mod-4 across the 16-row tile, so each
// lane's 4 C-regs hold the 4 edges (reg=edge); g==0 lanes commit results.
// All GEMMs use the bf16 hi/lo 3-term split (hh+hl+lh, ~2^-15 rel err).
__global__ __launch_bounds__(256, 3) void k_main(
    const float* __restrict__ vectors, const float* __restrict__ x, const float* __restrict__ V,
    const int* __restrict__ senders,
    const float* __restrict__ ws, const int* __restrict__ sorted,
    float* __restrict__ out){
  __shared__ __align__(16) __bf16 lds_pdh[32*328];   // 20992 B
  __shared__ __align__(16) __bf16 lds_pdl[32*328];   // 20992 B
  __shared__ __align__(16) __bf16 lds_hh[4*264];     // 2112 B  h=[x|S] hi
  __shared__ __align__(16) __bf16 lds_hl[4*264];     // 2112 B  lo
  __shared__ __align__(16) __bf16 lds_h1h[4*72];     // 576 B
  __shared__ __align__(16) __bf16 lds_h1l[4*72];
  __shared__ __align__(16) __bf16 lds_h2h[4*72];
  __shared__ __align__(16) __bf16 lds_h2l[4*72];
  __shared__ float lds_w3j[573];                     // 2292 B
  __shared__ float lds_env[4];
  __shared__ int   lds_eid[4];

  int t = threadIdx.x;
  for(int i=t;i<573;i+=256) lds_w3j[i]=ws[i];
  int wv = t>>6, lane = t&63;
  int eid = sorted[blockIdx.x*4 + wv];
  if(lane==0) lds_eid[wv]=eid;
  __syncthreads();

  const float* lw = lds_w3j;
  // ---- phase 1: per-edge (one wave per edge) ----
  {
    float v0=vectors[eid*3], v1=vectors[eid*3+1], v2=vectors[eid*3+2];
    float d = sqrtf(v0*v0+v1*v1+v2*v2);
    float d2=d*d, d4=d2*d2, d6=d4*d2, d7=d6*d, d8=d7*d;
    float env = 1.0f - 28.0f*d6 + 48.0f*d7 - 21.0f*d8;
    env = (d < 1.0f) ? env : 0.0f;
    if(lane==0) lds_env[wv]=env;
  }
  int snd = senders[eid];
  const float4* Ap4 = (const float4*)(ws + WS_A + snd*1024 + lane*16);
  float4 a0=Ap4[0], a1=Ap4[1], a2=Ap4[2], a3=Ap4[3];
  float wY[16] = {a0.x,a0.y,a0.z,a0.w, a1.x,a1.y,a1.z,a1.w,
                  a2.x,a2.y,a2.z,a2.w, a3.x,a3.y,a3.z,a3.w};
  const float* Vp = V + eid*576;
  float V0 = Vp[lane];
  float V1f[3], V2f[5];
  #pragma unroll
  for(int i=0;i<3;i++) V1f[i]=Vp[64+lane*3+i];
  #pragma unroll
  for(int j=0;j<5;j++) V2f[j]=Vp[256+lane*5+j];
  // h = [x | S] stored bf16 hi/lo (k index = lane within each 64-segment)
  {
    __bf16 hh, hl;
    split1(x[eid*64+lane], hh, hl);
    lds_hh[wv*264 + lane] = hh; lds_hl[wv*264 + lane] = hl;
  }
  // scalar channel S
  float s0 = wY[0]*V0*lw[O_W000];
  float s1 = 0.f;
  #pragma unroll
  for(int i=0;i<3;i++)
    #pragma unroll
    for(int j=0;j<3;j++) s1 += wY[1+i]*V1f[j]*lw[O_W110 + i*3+j];
  float s2 = 0.f;
  #pragma unroll
  for(int i=0;i<5;i++)
    #pragma unroll
    for(int j=0;j<5;j++) s2 += wY[4+i]*V2f[j]*lw[O_W220 + i*5+j];
  {
    __bf16 hh, hl;
    split1(s0, hh, hl); lds_hh[wv*264+ 64+lane]=hh; lds_hl[wv*264+ 64+lane]=hl;
    split1(s1, hh, hl); lds_hh[wv*264+128+lane]=hh; lds_hl[wv*264+128+lane]=hl;
    split1(s2, hh, hl); lds_hh[wv*264+192+lane]=hh; lds_hl[wv*264+192+lane]=hl;
  }
  // P paths (l3=1): i=0..2.  D paths (l3=2): j=0..4.
  float P0[3]={0,0,0}, P1[3]={0,0,0}, P2[3]={0,0,0}, P3[3]={0,0,0}, P4[3]={0,0,0};
  float D0[5]={0,0,0,0,0}, D1[5]={0,0,0,0,0}, D2[5]={0,0,0,0,0}, D3[5]={0,0,0,0,0}, D4[5]={0,0,0,0,0};
  #pragma unroll
  for(int b=0;b<3;b++){ float pb=wY[0]*V1f[b];
    #pragma unroll
    for(int i=0;i<3;i++) P0[i]+= pb*lw[O_W011 + b*3+i]; }
  #pragma unroll
  for(int a=0;a<3;a++){ float pa=wY[1+a]*V0;
    #pragma unroll
    for(int i=0;i<3;i++) P1[i]+= pa*lw[O_W101 + a*3+i]; }
  #pragma unroll
  for(int a=0;a<3;a++)
    #pragma unroll
    for(int b=0;b<5;b++){ float p=wY[1+a]*V2f[b];
      #pragma unroll
      for(int i=0;i<3;i++) P2[i]+= p*lw[O_W121 + (a*5+b)*3+i]; }
  #pragma unroll
  for(int a=0;a<5;a++)
    #pragma unroll
    for(int b=0;b<3;b++){ float p=wY[4+a]*V1f[b];
      #pragma unroll
      for(int i=0;i<3;i++) P3[i]+= p*lw[O_W211 + (a*3+b)*3+i]; }
  #pragma unroll
  for(int a=0;a<7;a++)
    #pragma unroll
    for(int b=0;b<5;b++){ float p=wY[9+a]*V2f[b];
      #pragma unroll
      for(int i=0;i<3;i++) P4[i]+= p*lw[O_W321 + (a*5+b)*3+i]; }
  #pragma unroll
  for(int b=0;b<5;b++){ float pb=wY[0]*V2f[b];
    #pragma unroll
    for(int j=0;j<5;j++) D0[j]+= pb*lw[O_W022 + b*5+j]; }
  #pragma unroll
  for(int a=0;a<3;a++)
    #pragma unroll
    for(int b=0;b<3;b++){ float p=wY[1+a]*V1f[b];
      #pragma unroll
      for(int j=0;j<5;j++) D1[j]+= p*lw[O_W112 + (a*3+b)*5+j]; }
  #pragma unroll
  for(int a=0;a<5;a++){ float pa=wY[4+a]*V0;
    #pragma unroll
    for(int j=0;j<5;j++) D2[j]+= pa*lw[O_W202 + a*5+j]; }
  #pragma unroll
  for(int a=0;a<5;a++)
    #pragma unroll
    for(int b=0;b<5;b++){ float p=wY[4+a]*V2f[b];
      #pragma unroll
      for(int j=0;j<5;j++) D3[j]+= p*lw[O_W222 + (a*5+b)*5+j]; }
  #pragma unroll
  for(int a=0;a<7;a++)
    #pragma unroll
    for(int b=0;b<3;b++){ float p=wY[9+a]*V1f[b];
      #pragma unroll
      for(int j=0;j<5;j++) D4[j]+= p*lw[O_W312 + (a*3+b)*5+j]; }
  // stage into lds_pd hi/lo (fold sqrt(2*l3+1)); lane stride-1 writes.
  // rows: P -> wv*3+i (0..11); D -> 12 + wv*5 + j (12..31)
  {
    const float SQ3 = 1.7320508075688772f, SQ5 = 2.2360679774997896f;
    #pragma unroll
    for(int i=0;i<3;i++){
      int row = wv*3+i;
      float vals[5] = {SQ3*P0[i], SQ3*P1[i], SQ3*P2[i], SQ3*P3[i], SQ3*P4[i]};
      #pragma unroll
      for(int p=0;p<5;p++){
        __bf16 h,l; split1(vals[p],h,l);
        lds_pdh[row*328 + p*64 + lane] = h;
        lds_pdl[row*328 + p*64 + lane] = l;
      }
    }
    #pragma unroll
    for(int j=0;j<5;j++){
      int row = 12 + wv*5 + j;
      float vals[5] = {SQ5*D0[j], SQ5*D1[j], SQ5*D2[j], SQ5*D3[j], SQ5*D4[j]};
      #pragma unroll
      for(int p=0;p<5;p++){
        __bf16 h,l; split1(vals[p],h,l);
        lds_pdh[row*328 + p*64 + lane] = h;
        lds_pdl[row*328 + p*64 + lane] = l;
      }
    }
  }
  __syncthreads();

  int g = lane >> 4, r = lane & 15;
  const bf16x8* WB = (const bf16x8*)(ws + WS_W);

  // ---- MLP on MFMA (A rows = edge, duplicated mod 4; reg = edge in C) ----
  {
    int he = r & 3;
    f32x4 acc = {0.f,0.f,0.f,0.f};
    #pragma unroll
    for(int ks=0; ks<8; ks++){
      bf16x8 ah = *(const bf16x8*)(lds_hh + he*264 + ks*32 + g*8);
      bf16x8 al = *(const bf16x8*)(lds_hl + he*264 + ks*32 + g*8);
      bf16x8 bh = WB[PK_W1        + (ks*4+wv)*64 + lane];
      bf16x8 bl = WB[PK_W1 + 2048 + (ks*4+wv)*64 + lane];
      acc = __builtin_amdgcn_mfma_f32_16x16x32_bf16(ah, bh, acc, 0,0,0);
      acc = __builtin_amdgcn_mfma_f32_16x16x32_bf16(ah, bl, acc, 0,0,0);
      acc = __builtin_amdgcn_mfma_f32_16x16x32_bf16(al, bh, acc, 0,0,0);
    }
    if(g==0){
      #pragma unroll
      for(int e_=0;e_<4;e_++){
        float a = acc[e_]*(1.0f/16.0f);
        float h1 = a/(1.0f+__expf(-a));
        __bf16 hh,hl; split1(h1,hh,hl);
        lds_h1h[e_*72 + wv*16 + r] = hh;
        lds_h1l[e_*72 + wv*16 + r] = hl;
      }
    }
    __syncthreads();
    acc = (f32x4){0.f,0.f,0.f,0.f};
    #pragma unroll
    for(int ks=0; ks<2; ks++){
      bf16x8 ah = *(const bf16x8*)(lds_h1h + he*72 + ks*32 + g*8);
      bf16x8 al = *(const bf16x8*)(lds_h1l + he*72 + ks*32 + g*8);
      bf16x8 bh = WB[PK_W2       + (ks*4+wv)*64 + lane];
      bf16x8 bl = WB[PK_W2 + 512 + (ks*4+wv)*64 + lane];
      acc = __builtin_amdgcn_mfma_f32_16x16x32_bf16(ah, bh, acc, 0,0,0);
      acc = __builtin_amdgcn_mfma_f32_16x16x32_bf16(ah, bl, acc, 0,0,0);
      acc = __builtin_amdgcn_mfma_f32_16x16x32_bf16(al, bh, acc, 0,0,0);
    }
    if(g==0){
      #pragma unroll
      for(int e_=0;e_<4;e_++){
        float a = acc[e_]*0.125f;
        float h2 = a/(1.0f+__expf(-a));
        __bf16 hh,hl; split1(h2,hh,hl);
        lds_h2h[e_*72 + wv*16 + r] = hh;
        lds_h2l[e_*72 + wv*16 + r] = hl;
      }
    }
    __syncthreads();
    acc = (f32x4){0.f,0.f,0.f,0.f};
    #pragma unroll
    for(int ks=0; ks<2; ks++){
      bf16x8 ah = *(const bf16x8*)(lds_h2h + he*72 + ks*32 + g*8);
      bf16x8 al = *(const bf16x8*)(lds_h2l + he*72 + ks*32 + g*8);
      bf16x8 bh = WB[PK_W3       + (ks*4+wv)*64 + lane];
      bf16x8 bl = WB[PK_W3 + 512 + (ks*4+wv)*64 + lane];
      acc = __builtin_amdgcn_mfma_f32_16x16x32_bf16(ah, bh, acc, 0,0,0);
      acc = __builtin_amdgcn_mfma_f32_16x16x32_bf16(ah, bl, acc, 0,0,0);
      acc = __builtin_amdgcn_mfma_f32_16x16x32_bf16(al, bh, acc, 0,0,0);
    }
    if(g==0){
      #pragma unroll
      for(int e_=0;e_<4;e_++)
        out[lds_eid[e_]*576 + wv*16 + r] = lds_env[e_]*acc[e_]*0.125f;
    }
  }

  // ---- phase 2: MFMA projections. wave = N-tile (nt = wv), 16 u-cols each.
  // A-frags read directly as bf16 hi/lo from LDS (no conversions).
  {
    f32x4 accP  = {0.f,0.f,0.f,0.f};
    f32x4 accD0 = {0.f,0.f,0.f,0.f};
    f32x4 accD1 = {0.f,0.f,0.f,0.f};
    int rP  = (r < 12) ? r : 11;          // clamp: C rows 12-15 discarded
    int rD0 = 12 + r;                     // D rows 0..15
    int rD1 = 12 + ((r < 4) ? (16 + r) : 19);  // D rows 16..19; rest clamped
    const __bf16* pPh  = lds_pdh + rP *328 + g*8;
    const __bf16* pPl  = lds_pdl + rP *328 + g*8;
    const __bf16* pD0h = lds_pdh + rD0*328 + g*8;
    const __bf16* pD0l = lds_pdl + rD0*328 + g*8;
    const __bf16* pD1h = lds_pdh + rD1*328 + g*8;
    const __bf16* pD1l = lds_pdl + rD1*328 + g*8;
    #pragma unroll 2
    for(int ks=0; ks<10; ks++){
      int bbase = (ks*4 + wv)*64 + lane;
      bf16x8 b1h = WB[bbase];             // Wl1 hi
      bf16x8 b1l = WB[bbase + 2560];      // Wl1 lo
      bf16x8 b2h = WB[bbase + 5120];      // Wl2 hi
      bf16x8 b2l = WB[bbase + 7680];      // Wl2 lo
      bf16x8 aPh  = *(const bf16x8*)(pPh  + ks*32);
      bf16x8 aPl  = *(const bf16x8*)(pPl  + ks*32);
      bf16x8 aD0h = *(const bf16x8*)(pD0h + ks*32);
      bf16x8 aD0l = *(const bf16x8*)(pD0l + ks*32);
      bf16x8 aD1h = *(const bf16x8*)(pD1h + ks*32);
      bf16x8 aD1l = *(const bf16x8*)(pD1l + ks*32);
      accP  = __builtin_amdgcn_mfma_f32_16x16x32_bf16(aPh,  b1h, accP,  0,0,0);
      accP  = __builtin_amdgcn_mfma_f32_16x16x32_bf16(aPh,  b1l, accP,  0,0,0);
      accP  = __builtin_amdgcn_mfma_f32_16x16x32_bf16(aPl,  b1h, accP,  0,0,0);
      accD0 = __builtin_amdgcn_mfma_f32_16x16x32_bf16(aD0h, b2h, accD0, 0,0,0);
      accD0 = __builtin_amdgcn_mfma_f32_16x16x32_bf16(aD0h, b2l, accD0, 0,0,0);
      accD0 = __builtin_amdgcn_mfma_f32_16x16x32_bf16(aD0l, b2h, accD0, 0,0,0);
      accD1 = __builtin_amdgcn_mfma_f32_16x16x32_bf16(aD1h, b2h, accD1, 0,0,0);
      accD1 = __builtin_amdgcn_mfma_f32_16x16x32_bf16(aD1h, b2l, accD1, 0,0,0);
      accD1 = __builtin_amdgcn_mfma_f32_16x16x32_bf16(aD1l, b2h, accD1, 0,0,0);
    }
    // C layout (m89-verified): col = lane&15, row = (lane>>4)*4 + reg
    const float sc = 0.05590169943749474f;  // 1/sqrt(320)
    int u = wv*16 + r;
    if(g < 3){
      #pragma unroll
      for(int reg=0; reg<4; reg++){
        int R = g*4 + reg;                 // 0..11 : P row = e*3 + i
        int e_ = R/3, i_ = R - e_*3;
        out[lds_eid[e_]*576 + 64 + u*3 + i_] = accP[reg]*sc;
      }
    }
    #pragma unroll
    for(int reg=0; reg<4; reg++){
      int Dr = g*4 + reg;                  // 0..15 : D row = e*5 + j
      int e_ = Dr/5, j_ = Dr - e_*5;
      out[lds_eid[e_]*576 + 256 + u*5 + j_] = accD0[reg]*sc;
    }
    if(g == 0){
      #pragma unroll
      for(int reg=0; reg<4; reg++){
        int Dr = 16 + reg;                 // 16..19 -> e=3, j=1..4
        int e_ = Dr/5, j_ = Dr - e_*5;
        out[lds_eid[e_]*576 + 256 + u*5 + j_] = accD1[reg]*sc;
      }
    }
  }
}

extern "C" void kernel_launch(void* const* d_in, const int* in_sizes, int n_in,
                              void* d_out, int out_size, void* d_ws, size_t ws_size,
                              hipStream_t stream) {
  const float* vectors=(const float*)d_in[0];
  const float* x      =(const float*)d_in[1];
  const float* V      =(const float*)d_in[2];
  const int*   senders=(const int*)  d_in[3];
  const float* Ww     =(const float*)d_in[4];
  const float* W1     =(const float*)d_in[5];
  const float* W2     =(const float*)d_in[6];
  const float* W3     =(const float*)d_in[7];
  const float* Wl1    =(const float*)d_in[8];
  const float* Wl2    =(const float*)d_in[9];
  float* ws  = (float*)d_ws;
  float* out = (float*)d_out;
  int* cnt    = (int*)(ws + WS_CNT);
  int* off    = (int*)(ws + WS_OFF);
  int* cur    = (int*)(ws + WS_CUR);
  int* sorted = (int*)(ws + WS_SORT);

  k_w3j   <<<14, 128, 0, stream>>>(ws);
  k_c2c3  <<<1, 1, 0, stream>>>(ws);
  k_zero  <<<16, 256, 0, stream>>>(cnt);
  k_count <<<E_EDGES/256, 256, 0, stream>>>(senders, cnt);
  k_scan  <<<1, 1024, 0, stream>>>(cnt, off, cur);
  k_scatter<<<E_EDGES/256, 256, 0, stream>>>(senders, cur, sorted);
  k_edge_pre<<<E_EDGES/4, 256, 0, stream>>>(vectors, x, Ww, ws);
  k_node_acc<<<N_NODES, 64, 0, stream>>>(ws + WS_W, ws + WS_Y, sorted, off, cnt, ws + WS_A);
  // pack AFTER k_node_acc (reuses the then-dead WS_W region)
  k_wpack <<<64, 256, 0, stream>>>(Wl1, Wl2, W1, W2, W3, ws + WS_W);
  k_main  <<<E_EDGES/4, 256, 0, stream>>>(vectors, x, V, senders,
                                          ws, sorted, out);
}

// Round 5
// 645.768 us; speedup vs baseline: 3.0002x; 1.0241x over previous
//
#include <hip/hip_runtime.h>

#define E_EDGES 65536
#define N_NODES 4096

// ---- workspace layout (float offsets) ----
// [0,678)   w3j tensors, [678] C2, [679] C3  (reserve 1024)
#define WS_W     1024                       // E*64   w = x@Ww/8  (dead after k_node_acc; reused for packed weights)
#define WS_Y     (WS_W + E_EDGES*64)        // E*16   Y
#define WS_CNT   (WS_Y + E_EDGES*16)        // 4096 int
#define WS_OFF   (WS_CNT + N_NODES)         // 4096 int
#define WS_CUR   (WS_OFF + N_NODES)         // 4096 int
#define WS_SORT  (WS_CUR + N_NODES)         // E int
#define WS_A     (WS_SORT + E_EDGES)        // N*1024  node accumulator (eps folded)
// high-water: WS_A + 4096*1024 = 9,516,032 floats ~= 38.1 MB

typedef __bf16 bf16x8 __attribute__((ext_vector_type(8)));
typedef float  f32x4  __attribute__((ext_vector_type(4)));

// packed-weight fragment offsets (units of bf16x8 = 16 B), base ws+WS_W
//   Wl1h 0 | Wl1l 2560 | Wl2h 5120 | Wl2l 7680   (10 ks x 4 nt x 64 lanes)
//   W1h 10240 | W1l 12288                        (8 ks x 4 nt x 64)
//   W2h 14336 | W2l 14848 | W3h 15360 | W3l 15872 (2 ks x 4 nt x 64)
#define PK_WL   0
#define PK_W1   10240
#define PK_W2   14336
#define PK_W3   15360

// key order: (0,0,0),(1,1,0),(2,2,0),(0,1,1),(1,0,1),(1,2,1),(2,1,1),(3,2,1),
//            (0,2,2),(1,1,2),(2,0,2),(2,2,2),(3,1,2),(2,1,3)
__constant__ int gK_L1[14] = {0,1,2,0,1,1,2,3,0,1,2,2,3,2};
__constant__ int gK_L2[14] = {0,1,2,1,0,2,1,2,2,1,0,2,1,1};
__constant__ int gK_L3[14] = {0,0,0,1,1,1,1,1,2,2,2,2,2,3};
__constant__ int gK_OFF[14]= {0,1,10,35,44,53,98,143,248,273,318,343,468,573};
__constant__ double gFact[8] = {1.,1.,2.,6.,24.,120.,720.,5040.};

// w3j offsets (compile-time)
#define O_W000 0
#define O_W110 1
#define O_W220 10
#define O_W011 35
#define O_W101 44
#define O_W121 53
#define O_W211 98
#define O_W321 143
#define O_W022 248
#define O_W112 273
#define O_W202 318
#define O_W222 343
#define O_W312 468
#define O_W213 573

__device__ double su2_cg(int j1,int j2,int j3,int m1,int m2,int m3){
  if (m3 != m1+m2) return 0.0;
  double pref = sqrt((double)(2*j3+1)*gFact[j3+j1-j2]*gFact[j3-j1+j2]*gFact[j1+j2-j3]/gFact[j1+j2+j3+1]);
  pref *= sqrt(gFact[j3+m3]*gFact[j3-m3]*gFact[j1-m1]*gFact[j1+m1]*gFact[j2-m2]*gFact[j2+m2]);
  double s=0.0;
  for(int k=0;k<=j1+j2-j3;k++){
    int d1=j1+j2-j3-k, d2=j1-m1-k, d3=j2+m2-k, d4=j3-j2+m1+k, d5=j3-j1-m2+k;
    if(d1<0||d2<0||d3<0||d4<0||d5<0) continue;
    double den=gFact[k]*gFact[d1]*gFact[d2]*gFact[d3]*gFact[d4]*gFact[d5];
    s += (k&1)? (-1.0/den) : (1.0/den);
  }
  return pref*s;
}

__device__ void fill_qmat(int l, double2* q){  // 7x7 row-major, rows=m-basis, cols=real-basis
  for(int i=0;i<49;i++){ q[i].x=0.0; q[i].y=0.0; }
  const double is2 = 0.7071067811865475244;
  for(int m=-l;m<0;m++){
    q[(l+m)*7+(l-m)].x = is2;     // q[l+m, l+|m|] = 1/sqrt2
    q[(l+m)*7+(l+m)].y = -is2;    // q[l+m, l-|m|] = -1j/sqrt2
  }
  q[l*7+l].x = 1.0;
  for(int m=1;m<=l;m++){
    double sg = (m&1)? -1.0 : 1.0;
    q[(l+m)*7+(l+m)].x = sg*is2;
    q[(l+m)*7+(l-m)].y = sg*is2;
  }
  double pr, pi;  // (-i)^l
  switch(l&3){ case 0: pr=1;pi=0;break; case 1: pr=0;pi=-1;break; case 2: pr=-1;pi=0;break; default: pr=0;pi=1;break; }
  for(int i=0;i<49;i++){
    double a=q[i].x, b=q[i].y;
    q[i].x = a*pr - b*pi;
    q[i].y = a*pi + b*pr;
  }
}

__global__ __launch_bounds__(128) void k_w3j(float* __restrict__ ws){
  __shared__ double2 q1[49], q2[49], q3[49];
  __shared__ double C[125], Cr[125];
  __shared__ double red[128];
  int bid = blockIdx.x, t = threadIdx.x;
  int l1=gK_L1[bid], l2=gK_L2[bid], l3=gK_L3[bid];
  int n1=2*l1+1, n2=2*l2+1, n3=2*l3+1, ntot=n1*n2*n3;
  if(t==0){
    fill_qmat(l1,q1); fill_qmat(l2,q2); fill_qmat(l3,q3);
    for(int i=0;i<49;i++) q3[i].y = -q3[i].y;   // conj
  }
  __syncthreads();
  for(int idx=t; idx<ntot; idx+=128){
    int a = idx/(n2*n3), r=idx%(n2*n3), b=r/n3, c=r%n3;
    C[idx] = su2_cg(l1,l2,l3, a-l1, b-l2, c-l3);
  }
  __syncthreads();
  for(int idx=t; idx<ntot; idx+=128){
    int i = idx/(n2*n3), r=idx%(n2*n3), j=r/n3, k=r%n3;
    double ar=0.0;
    for(int a=0;a<n1;a++) for(int b=0;b<n2;b++){
      double2 qa=q1[a*7+i], qb=q2[b*7+j];
      double pr = qa.x*qb.x - qa.y*qb.y;
      double pi = qa.x*qb.y + qa.y*qb.x;
      for(int c=0;c<n3;c++){
        double2 qc=q3[c*7+k];
        double tr = pr*qc.x - pi*qc.y;
        ar += tr*C[(a*n2+b)*n3+c];
      }
    }
    Cr[idx]=ar;
  }
  __syncthreads();
  double ss=0.0;
  for(int idx=t; idx<ntot; idx+=128) ss += Cr[idx]*Cr[idx];
  red[t]=ss; __syncthreads();
  for(int st=64; st>0; st>>=1){ if(t<st) red[t]+=red[t+st]; __syncthreads(); }
  double inv = 1.0/sqrt(red[0]);
  for(int idx=t; idx<ntot; idx+=128) ws[gK_OFF[bid]+idx] = (float)(Cr[idx]*inv);
}

__global__ void k_c2c3(float* __restrict__ ws){
  const float* w112 = ws + O_W112;
  const float* w213 = ws + O_W213;
  double u0=0.3, u1=-0.4, u2=sqrt(0.75);
  double s3=sqrt(3.0);
  double y1[3]={s3*u0, s3*u1, s3*u2};
  double y2r[5]={0,0,0,0,0};
  for(int i=0;i<3;i++) for(int j=0;j<3;j++) for(int k=0;k<5;k++)
    y2r[k] += y1[i]*y1[j]*(double)w112[(i*3+j)*5+k];
  double nn=0; for(int k=0;k<5;k++) nn += y2r[k]*y2r[k];
  double c2 = sqrt(5.0)/sqrt(nn);
  double y2[5]; for(int k=0;k<5;k++) y2[k]=c2*y2r[k];
  double y3r[7]={0,0,0,0,0,0,0};
  for(int i=0;i<5;i++) for(int j=0;j<3;j++) for(int n=0;n<7;n++)
    y3r[n] += y2[i]*y1[j]*(double)w213[(i*3+j)*7+n];
  nn=0; for(int n=0;n<7;n++) nn += y3r[n]*y3r[n];
  double c3 = sqrt(7.0)/sqrt(nn);
  ws[678]=(float)c2; ws[679]=(float)c3;
}

__global__ void k_zero(int* __restrict__ cnt){
  int i = blockIdx.x*256 + threadIdx.x;
  if(i < N_NODES) cnt[i]=0;
}
__global__ void k_count(const int* __restrict__ senders, int* __restrict__ cnt){
  int e = blockIdx.x*256 + threadIdx.x;
  if(e < E_EDGES) atomicAdd(&cnt[senders[e]], 1);
}
__global__ __launch_bounds__(1024) void k_scan(const int* __restrict__ cnt, int* __restrict__ off, int* __restrict__ cur){
  __shared__ int part[1024];
  int t = threadIdx.x;
  int c0=cnt[4*t], c1=cnt[4*t+1], c2=cnt[4*t+2], c3=cnt[4*t+3];
  int l0=0, l1=c0, l2=c0+c1, l3=c0+c1+c2;
  int sum=l3+c3;
  part[t]=sum; __syncthreads();
  for(int st=1; st<1024; st<<=1){
    int v = part[t];
    int add = (t>=st)? part[t-st] : 0;
    __syncthreads();
    part[t] = v + add;
    __syncthreads();
  }
  int pref = (t>0)? part[t-1] : 0;
  off[4*t]=pref+l0; off[4*t+1]=pref+l1; off[4*t+2]=pref+l2; off[4*t+3]=pref+l3;
  cur[4*t]=pref+l0; cur[4*t+1]=pref+l1; cur[4*t+2]=pref+l2; cur[4*t+3]=pref+l3;
}
__global__ void k_scatter(const int* __restrict__ senders, int* __restrict__ cur, int* __restrict__ sorted){
  int e = blockIdx.x*256 + threadIdx.x;
  if(e < E_EDGES){
    int pos = atomicAdd(&cur[senders[e]], 1);
    sorted[pos] = e;
  }
}

// pack Wl1/Wl2/W1/W2/W3 into bf16 hi/lo MFMA B-fragments.
// frag convention (matches A-pack in k_main): col = nt*16 + (lane&15),
// k = ks*32 + (lane>>4)*8 + j.  (consistent A/B k-mapping => correct dot
// product under any HW k-permutation.)
__global__ __launch_bounds__(256) void k_wpack(
    const float* __restrict__ Wl1, const float* __restrict__ Wl2,
    const float* __restrict__ W1, const float* __restrict__ W2,
    const float* __restrict__ W3, float* __restrict__ wpk){
  int idx = blockIdx.x*256 + threadIdx.x;   // 64 blocks = 16384 frags
  int lane = idx & 63;
  const float* W; int part, ks, nt;
  if(idx < PK_W1){                       // Wl1/Wl2: [mp][ks10][nt][lane]
    nt = (idx>>6)&3; int rest = idx>>8; ks = rest%10; int mp = rest/10;
    part = mp&1; W = (mp>>1)? Wl2 : Wl1;
  } else if(idx < PK_W2){                // W1: [part][ks8][nt][lane]
    int rel = idx - PK_W1; part = rel>>11; int r2 = rel & 2047;
    ks = r2>>8; nt = (r2>>6)&3; W = W1;
  } else if(idx < PK_W3){                // W2: [part][ks2][nt][lane]
    int rel = idx - PK_W2; part = rel>>9; int r2 = rel & 511;
    ks = r2>>8; nt = (r2>>6)&3; W = W2;
  } else {                               // W3: [part][ks2][nt][lane]
    int rel = idx - PK_W3; part = rel>>9; int r2 = rel & 511;
    ks = r2>>8; nt = (r2>>6)&3; W = W3;
  }
  int c = nt*16 + (lane & 15);
  int g = lane >> 4;
  bf16x8 outv;
  #pragma unroll
  for(int j=0;j<8;j++){
    int k = ks*32 + g*8 + j;
    float v = W[k*64 + c];
    __bf16 hb = (__bf16)v;
    outv[j] = part ? (__bf16)(v - (float)hb) : hb;
  }
  ((bf16x8*)wpk)[idx] = outv;
}

// per edge: w = x@Ww/8 (lane=mul), Y[16] spherical harmonics
__global__ __launch_bounds__(256) void k_edge_pre(
    const float* __restrict__ vectors, const float* __restrict__ x,
    const float* __restrict__ Ww, float* __restrict__ ws){
  int wv = threadIdx.x >> 6, lane = threadIdx.x & 63;
  int e = blockIdx.x*4 + wv;
  const float* w112 = ws + O_W112;
  const float* w213 = ws + O_W213;
  float C2v = ws[678], C3v = ws[679];
  float v0=vectors[e*3], v1=vectors[e*3+1], v2=vectors[e*3+2];
  float len = sqrtf(v0*v0+v1*v1+v2*v2);
  float inv = 1.0f/(len + 1e-12f);
  float s3 = 1.7320508075688772f;
  float y1v[3] = { s3*v0*inv, s3*v1*inv, s3*v2*inv };
  float y2[5];
  #pragma unroll
  for(int k=0;k<5;k++){
    float a=0.f;
    #pragma unroll
    for(int i=0;i<3;i++)
      #pragma unroll
      for(int j=0;j<3;j++) a += y1v[i]*y1v[j]*w112[(i*3+j)*5+k];
    y2[k]=C2v*a;
  }
  float y3[7];
  #pragma unroll
  for(int n=0;n<7;n++){
    float a=0.f;
    #pragma unroll
    for(int i=0;i<5;i++)
      #pragma unroll
      for(int j=0;j<3;j++) a += y2[i]*y1v[j]*w213[(i*3+j)*7+n];
    y3[n]=C3v*a;
  }
  // w = x@Ww/8 : x row via float4 uniform loads (4x fewer VMEM issues)
  float acc=0.f;
  const float4* xp4 = (const float4*)(x + e*64);
  #pragma unroll
  for(int k4=0;k4<16;k4++){
    float4 xv = xp4[k4];
    acc += xv.x*Ww[(k4*4+0)*64+lane];
    acc += xv.y*Ww[(k4*4+1)*64+lane];
    acc += xv.z*Ww[(k4*4+2)*64+lane];
    acc += xv.w*Ww[(k4*4+3)*64+lane];
  }
  ws[WS_W + e*64 + lane] = acc*0.125f;
  if(lane==0){
    float* Yp = ws + WS_Y + e*16;
    Yp[0]=1.0f;
    Yp[1]=y1v[0]; Yp[2]=y1v[1]; Yp[3]=y1v[2];
    Yp[4]=y2[0]; Yp[5]=y2[1]; Yp[6]=y2[2]; Yp[7]=y2[3]; Yp[8]=y2[4];
    Yp[9]=y3[0]; Yp[10]=y3[1]; Yp[11]=y3[2]; Yp[12]=y3[3]; Yp[13]=y3[4]; Yp[15]=y3[6]; Yp[14]=y3[5];
  }
}

// per node: A[n][m][k] = eps * sum_e w[e][m]*Y[e][k]
__global__ __launch_bounds__(64) void k_node_acc(
    const float* __restrict__ ws_w, const float* __restrict__ ws_y,
    const int* __restrict__ sorted, const int* __restrict__ off, const int* __restrict__ cnt,
    float* __restrict__ A){
  int n = blockIdx.x, m = threadIdx.x;
  float acc[16];
  #pragma unroll
  for(int k=0;k<16;k++) acc[k]=0.f;
  int o = off[n], c = cnt[n];
  for(int j=0;j<c;j++){
    int e = sorted[o+j];
    float wm = ws_w[e*64+m];
    const float4* Yp4 = (const float4*)(ws_y + e*16);
    float4 y0=Yp4[0], y1=Yp4[1], y2=Yp4[2], y3=Yp4[3];
    acc[0] += wm*y0.x; acc[1] += wm*y0.y; acc[2] += wm*y0.z; acc[3] += wm*y0.w;
    acc[4] += wm*y1.x; acc[5] += wm*y1.y; acc[6] += wm*y1.z; acc[7] += wm*y1.w;
    acc[8] += wm*y2.x; acc[9] += wm*y2.y; acc[10]+= wm*y2.z; acc[11]+= wm*y2.w;
    acc[12]+= wm*y3.x; acc[13]+= wm*y3.y; acc[14]+= wm*y3.z; acc[15]+= wm*y3.w;
  }
  float4* outp = (float4*)(A + n*1024 + m*16);
  outp[0] = make_float4(acc[0]*0.25f, acc[1]*0.25f, acc[2]*0.25f, acc[3]*0.25f);
  outp[1] = make_float4(acc[4]*0.25f, acc[5]*0.25f, acc[6]*0.25f, acc[7]*0.25f);
  outp[2] = make_float4(acc[8]*0.25f, acc[9]*0.25f, acc[10]*0.25f, acc[11]*0.25f);
  outp[3] = make_float4(acc[12]*0.25f, acc[13]*0.25f, acc[14]*0.25f, acc[15]*0.25f);
}

__device__ inline void split1(float v, __bf16& h, __bf16& l){
  h = (__bf16)v;
  l = (__bf16)(v - (float)h);
}

// main fused kernel: 4 edges per block (sorted order for A-gather locality)
// LDS ~48.9 KB -> 3 blocks/CU; barriers per block: 4.
// w3j coefficients read DIRECTLY from global ws with compile-time indices:
// wave-uniform + const __restrict__ -> backend emits SMEM s_loads (constant
// cache), keeping ~800 per-FMA coefficient reads OFF the LDS pipe (which is
// shared with pd/MLP fragment traffic and was co-saturated).
// pd stored as bf16 hi/lo (converted ONCE at phase-1 write) -> phase-2 reads
// MFMA A-frags directly via ds_read_b128, zero per-k-step conversion VALU.
// MLP also on MFMA: M=4 rows duplicate mod-4 across the 16-row tile.
// All GEMMs use the bf16 hi/lo 3-term split (hh+hl+lh, ~2^-15 rel err).
__global__ __launch_bounds__(256, 3) void k_main(
    const float* __restrict__ vectors, const float* __restrict__ x, const float* __restrict__ V,
    const int* __restrict__ senders,
    const float* __restrict__ ws, const int* __restrict__ sorted,
    float* __restrict__ out){
  __shared__ __align__(16) __bf16 lds_pdh[32*328];   // 20992 B
  __shared__ __align__(16) __bf16 lds_pdl[32*328];   // 20992 B
  __shared__ __align__(16) __bf16 lds_hh[4*264];     // 2112 B  h=[x|S] hi
  __shared__ __align__(16) __bf16 lds_hl[4*264];     // 2112 B  lo
  __shared__ __align__(16) __bf16 lds_h1h[4*72];     // 576 B
  __shared__ __align__(16) __bf16 lds_h1l[4*72];
  __shared__ __align__(16) __bf16 lds_h2h[4*72];
  __shared__ __align__(16) __bf16 lds_h2l[4*72];
  __shared__ float lds_env[4];
  __shared__ int   lds_eid[4];

  int t = threadIdx.x;
  int wv = t>>6, lane = t&63;
  int eid = sorted[blockIdx.x*4 + wv];
  if(lane==0) lds_eid[wv]=eid;
  __syncthreads();

  const float* lw = ws;   // w3j via SMEM (compile-time offsets, uniform)
  // ---- phase 1: per-edge (one wave per edge) ----
  {
    float v0=vectors[eid*3], v1=vectors[eid*3+1], v2=vectors[eid*3+2];
    float d = sqrtf(v0*v0+v1*v1+v2*v2);
    float d2=d*d, d4=d2*d2, d6=d4*d2, d7=d6*d, d8=d7*d;
    float env = 1.0f - 28.0f*d6 + 48.0f*d7 - 21.0f*d8;
    env = (d < 1.0f) ? env : 0.0f;
    if(lane==0) lds_env[wv]=env;
  }
  int snd = senders[eid];
  const float4* Ap4 = (const float4*)(ws + WS_A + snd*1024 + lane*16);
  float4 a0=Ap4[0], a1=Ap4[1], a2=Ap4[2], a3=Ap4[3];
  float wY[16] = {a0.x,a0.y,a0.z,a0.w, a1.x,a1.y,a1.z,a1.w,
                  a2.x,a2.y,a2.z,a2.w, a3.x,a3.y,a3.z,a3.w};
  const float* Vp = V + eid*576;
  float V0 = Vp[lane];
  float V1f[3], V2f[5];
  #pragma unroll
  for(int i=0;i<3;i++) V1f[i]=Vp[64+lane*3+i];
  #pragma unroll
  for(int j=0;j<5;j++) V2f[j]=Vp[256+lane*5+j];
  // h = [x | S] stored bf16 hi/lo (k index = lane within each 64-segment)
  {
    __bf16 hh, hl;
    split1(x[eid*64+lane], hh, hl);
    lds_hh[wv*264 + lane] = hh; lds_hl[wv*264 + lane] = hl;
  }
  // scalar channel S
  float s0 = wY[0]*V0*lw[O_W000];
  float s1 = 0.f;
  #pragma unroll
  for(int i=0;i<3;i++)
    #pragma unroll
    for(int j=0;j<3;j++) s1 += wY[1+i]*V1f[j]*lw[O_W110 + i*3+j];
  float s2 = 0.f;
  #pragma unroll
  for(int i=0;i<5;i++)
    #pragma unroll
    for(int j=0;j<5;j++) s2 += wY[4+i]*V2f[j]*lw[O_W220 + i*5+j];
  {
    __bf16 hh, hl;
    split1(s0, hh, hl); lds_hh[wv*264+ 64+lane]=hh; lds_hl[wv*264+ 64+lane]=hl;
    split1(s1, hh, hl); lds_hh[wv*264+128+lane]=hh; lds_hl[wv*264+128+lane]=hl;
    split1(s2, hh, hl); lds_hh[wv*264+192+lane]=hh; lds_hl[wv*264+192+lane]=hl;
  }
  // P paths (l3=1): i=0..2.  D paths (l3=2): j=0..4.
  float P0[3]={0,0,0}, P1[3]={0,0,0}, P2[3]={0,0,0}, P3[3]={0,0,0}, P4[3]={0,0,0};
  float D0[5]={0,0,0,0,0}, D1[5]={0,0,0,0,0}, D2[5]={0,0,0,0,0}, D3[5]={0,0,0,0,0}, D4[5]={0,0,0,0,0};
  #pragma unroll
  for(int b=0;b<3;b++){ float pb=wY[0]*V1f[b];
    #pragma unroll
    for(int i=0;i<3;i++) P0[i]+= pb*lw[O_W011 + b*3+i]; }
  #pragma unroll
  for(int a=0;a<3;a++){ float pa=wY[1+a]*V0;
    #pragma unroll
    for(int i=0;i<3;i++) P1[i]+= pa*lw[O_W101 + a*3+i]; }
  #pragma unroll
  for(int a=0;a<3;a++)
    #pragma unroll
    for(int b=0;b<5;b++){ float p=wY[1+a]*V2f[b];
      #pragma unroll
      for(int i=0;i<3;i++) P2[i]+= p*lw[O_W121 + (a*5+b)*3+i]; }
  #pragma unroll
  for(int a=0;a<5;a++)
    #pragma unroll
    for(int b=0;b<3;b++){ float p=wY[4+a]*V1f[b];
      #pragma unroll
      for(int i=0;i<3;i++) P3[i]+= p*lw[O_W211 + (a*3+b)*3+i]; }
  #pragma unroll
  for(int a=0;a<7;a++)
    #pragma unroll
    for(int b=0;b<5;b++){ float p=wY[9+a]*V2f[b];
      #pragma unroll
      for(int i=0;i<3;i++) P4[i]+= p*lw[O_W321 + (a*5+b)*3+i]; }
  #pragma unroll
  for(int b=0;b<5;b++){ float pb=wY[0]*V2f[b];
    #pragma unroll
    for(int j=0;j<5;j++) D0[j]+= pb*lw[O_W022 + b*5+j]; }
  #pragma unroll
  for(int a=0;a<3;a++)
    #pragma unroll
    for(int b=0;b<3;b++){ float p=wY[1+a]*V1f[b];
      #pragma unroll
      for(int j=0;j<5;j++) D1[j]+= p*lw[O_W112 + (a*3+b)*5+j]; }
  #pragma unroll
  for(int a=0;a<5;a++){ float pa=wY[4+a]*V0;
    #pragma unroll
    for(int j=0;j<5;j++) D2[j]+= pa*lw[O_W202 + a*5+j]; }
  #pragma unroll
  for(int a=0;a<5;a++)
    #pragma unroll
    for(int b=0;b<5;b++){ float p=wY[4+a]*V2f[b];
      #pragma unroll
      for(int j=0;j<5;j++) D3[j]+= p*lw[O_W222 + (a*5+b)*5+j]; }
  #pragma unroll
  for(int a=0;a<7;a++)
    #pragma unroll
    for(int b=0;b<3;b++){ float p=wY[9+a]*V1f[b];
      #pragma unroll
      for(int j=0;j<5;j++) D4[j]+= p*lw[O_W312 + (a*3+b)*5+j]; }
  // stage into lds_pd hi/lo (fold sqrt(2*l3+1)); lane stride-1 writes.
  // rows: P -> wv*3+i (0..11); D -> 12 + wv*5 + j (12..31)
  {
    const float SQ3 = 1.7320508075688772f, SQ5 = 2.2360679774997896f;
    #pragma unroll
    for(int i=0;i<3;i++){
      int row = wv*3+i;
      float vals[5] = {SQ3*P0[i], SQ3*P1[i], SQ3*P2[i], SQ3*P3[i], SQ3*P4[i]};
      #pragma unroll
      for(int p=0;p<5;p++){
        __bf16 h,l; split1(vals[p],h,l);
        lds_pdh[row*328 + p*64 + lane] = h;
        lds_pdl[row*328 + p*64 + lane] = l;
      }
    }
    #pragma unroll
    for(int j=0;j<5;j++){
      int row = 12 + wv*5 + j;
      float vals[5] = {SQ5*D0[j], SQ5*D1[j], SQ5*D2[j], SQ5*D3[j], SQ5*D4[j]};
      #pragma unroll
      for(int p=0;p<5;p++){
        __bf16 h,l; split1(vals[p],h,l);
        lds_pdh[row*328 + p*64 + lane] = h;
        lds_pdl[row*328 + p*64 + lane] = l;
      }
    }
  }
  __syncthreads();

  int g = lane >> 4, r = lane & 15;
  const bf16x8* WB = (const bf16x8*)(ws + WS_W);

  // ---- MLP on MFMA (A rows = edge, duplicated mod 4; reg = edge in C) ----
  {
    int he = r & 3;
    f32x4 acc = {0.f,0.f,0.f,0.f};
    #pragma unroll
    for(int ks=0; ks<8; ks++){
      bf16x8 ah = *(const bf16x8*)(lds_hh + he*264 + ks*32 + g*8);
      bf16x8 al = *(const bf16x8*)(lds_hl + he*264 + ks*32 + g*8);
      bf16x8 bh = WB[PK_W1        + (ks*4+wv)*64 + lane];
      bf16x8 bl = WB[PK_W1 + 2048 + (ks*4+wv)*64 + lane];
      acc = __builtin_amdgcn_mfma_f32_16x16x32_bf16(ah, bh, acc, 0,0,0);
      acc = __builtin_amdgcn_mfma_f32_16x16x32_bf16(ah, bl, acc, 0,0,0);
      acc = __builtin_amdgcn_mfma_f32_16x16x32_bf16(al, bh, acc, 0,0,0);
    }
    if(g==0){
      #pragma unroll
      for(int e_=0;e_<4;e_++){
        float a = acc[e_]*(1.0f/16.0f);
        float h1 = a/(1.0f+__expf(-a));
        __bf16 hh,hl; split1(h1,hh,hl);
        lds_h1h[e_*72 + wv*16 + r] = hh;
        lds_h1l[e_*72 + wv*16 + r] = hl;
      }
    }
    __syncthreads();
    acc = (f32x4){0.f,0.f,0.f,0.f};
    #pragma unroll
    for(int ks=0; ks<2; ks++){
      bf16x8 ah = *(const bf16x8*)(lds_h1h + he*72 + ks*32 + g*8);
      bf16x8 al = *(const bf16x8*)(lds_h1l + he*72 + ks*32 + g*8);
      bf16x8 bh = WB[PK_W2       + (ks*4+wv)*64 + lane];
      bf16x8 bl = WB[PK_W2 + 512 + (ks*4+wv)*64 + lane];
      acc = __builtin_amdgcn_mfma_f32_16x16x32_bf16(ah, bh, acc, 0,0,0);
      acc = __builtin_amdgcn_mfma_f32_16x16x32_bf16(ah, bl, acc, 0,0,0);
      acc = __builtin_amdgcn_mfma_f32_16x16x32_bf16(al, bh, acc, 0,0,0);
    }
    if(g==0){
      #pragma unroll
      for(int e_=0;e_<4;e_++){
        float a = acc[e_]*0.125f;
        float h2 = a/(1.0f+__expf(-a));
        __bf16 hh,hl; split1(h2,hh,hl);
        lds_h2h[e_*72 + wv*16 + r] = hh;
        lds_h2l[e_*72 + wv*16 + r] = hl;
      }
    }
    __syncthreads();
    acc = (f32x4){0.f,0.f,0.f,0.f};
    #pragma unroll
    for(int ks=0; ks<2; ks++){
      bf16x8 ah = *(const bf16x8*)(lds_h2h + he*72 + ks*32 + g*8);
      bf16x8 al = *(const bf16x8*)(lds_h2l + he*72 + ks*32 + g*8);
      bf16x8 bh = WB[PK_W3       + (ks*4+wv)*64 + lane];
      bf16x8 bl = WB[PK_W3 + 512 + (ks*4+wv)*64 + lane];
      acc = __builtin_amdgcn_mfma_f32_16x16x32_bf16(ah, bh, acc, 0,0,0);
      acc = __builtin_amdgcn_mfma_f32_16x16x32_bf16(ah, bl, acc, 0,0,0);
      acc = __builtin_amdgcn_mfma_f32_16x16x32_bf16(al, bh, acc, 0,0,0);
    }
    if(g==0){
      #pragma unroll
      for(int e_=0;e_<4;e_++)
        out[lds_eid[e_]*576 + wv*16 + r] = lds_env[e_]*acc[e_]*0.125f;
    }
  }

  // ---- phase 2: MFMA projections. wave = N-tile (nt = wv), 16 u-cols each.
  // A-frags read directly as bf16 hi/lo from LDS (no conversions).
  {
    f32x4 accP  = {0.f,0.f,0.f,0.f};
    f32x4 accD0 = {0.f,0.f,0.f,0.f};
    f32x4 accD1 = {0.f,0.f,0.f,0.f};
    int rP  = (r < 12) ? r : 11;          // clamp: C rows 12-15 discarded
    int rD0 = 12 + r;                     // D rows 0..15
    int rD1 = 12 + ((r < 4) ? (16 + r) : 19);  // D rows 16..19; rest clamped
    const __bf16* pPh  = lds_pdh + rP *328 + g*8;
    const __bf16* pPl  = lds_pdl + rP *328 + g*8;
    const __bf16* pD0h = lds_pdh + rD0*328 + g*8;
    const __bf16* pD0l = lds_pdl + rD0*328 + g*8;
    const __bf16* pD1h = lds_pdh + rD1*328 + g*8;
    const __bf16* pD1l = lds_pdl + rD1*328 + g*8;
    #pragma unroll 2
    for(int ks=0; ks<10; ks++){
      int bbase = (ks*4 + wv)*64 + lane;
      bf16x8 b1h = WB[bbase];             // Wl1 hi
      bf16x8 b1l = WB[bbase + 2560];      // Wl1 lo
      bf16x8 b2h = WB[bbase + 5120];      // Wl2 hi
      bf16x8 b2l = WB[bbase + 7680];      // Wl2 lo
      bf16x8 aPh  = *(const bf16x8*)(pPh  + ks*32);
      bf16x8 aPl  = *(const bf16x8*)(pPl  + ks*32);
      bf16x8 aD0h = *(const bf16x8*)(pD0h + ks*32);
      bf16x8 aD0l = *(const bf16x8*)(pD0l + ks*32);
      bf16x8 aD1h = *(const bf16x8*)(pD1h + ks*32);
      bf16x8 aD1l = *(const bf16x8*)(pD1l + ks*32);
      accP  = __builtin_amdgcn_mfma_f32_16x16x32_bf16(aPh,  b1h, accP,  0,0,0);
      accP  = __builtin_amdgcn_mfma_f32_16x16x32_bf16(aPh,  b1l, accP,  0,0,0);
      accP  = __builtin_amdgcn_mfma_f32_16x16x32_bf16(aPl,  b1h, accP,  0,0,0);
      accD0 = __builtin_amdgcn_mfma_f32_16x16x32_bf16(aD0h, b2h, accD0, 0,0,0);
      accD0 = __builtin_amdgcn_mfma_f32_16x16x32_bf16(aD0h, b2l, accD0, 0,0,0);
      accD0 = __builtin_amdgcn_mfma_f32_16x16x32_bf16(aD0l, b2h, accD0, 0,0,0);
      accD1 = __builtin_amdgcn_mfma_f32_16x16x32_bf16(aD1h, b2h, accD1, 0,0,0);
      accD1 = __builtin_amdgcn_mfma_f32_16x16x32_bf16(aD1h, b2l, accD1, 0,0,0);
      accD1 = __builtin_amdgcn_mfma_f32_16x16x32_bf16(aD1l, b2h, accD1, 0,0,0);
    }
    // C layout (m89-verified): col = lane&15, row = (lane>>4)*4 + reg
    const float sc = 0.05590169943749474f;  // 1/sqrt(320)
    int u = wv*16 + r;
    if(g < 3){
      #pragma unroll
      for(int reg=0; reg<4; reg++){
        int R = g*4 + reg;                 // 0..11 : P row = e*3 + i
        int e_ = R/3, i_ = R - e_*3;
        out[lds_eid[e_]*576 + 64 + u*3 + i_] = accP[reg]*sc;
      }
    }
    #pragma unroll
    for(int reg=0; reg<4; reg++){
      int Dr = g*4 + reg;                  // 0..15 : D row = e*5 + j
      int e_ = Dr/5, j_ = Dr - e_*5;
      out[lds_eid[e_]*576 + 256 + u*5 + j_] = accD0[reg]*sc;
    }
    if(g == 0){
      #pragma unroll
      for(int reg=0; reg<4; reg++){
        int Dr = 16 + reg;                 // 16..19 -> e=3, j=1..4
        int e_ = Dr/5, j_ = Dr - e_*5;
        out[lds_eid[e_]*576 + 256 + u*5 + j_] = accD1[reg]*sc;
      }
    }
  }
}

extern "C" void kernel_launch(void* const* d_in, const int* in_sizes, int n_in,
                              void* d_out, int out_size, void* d_ws, size_t ws_size,
                              hipStream_t stream) {
  const float* vectors=(const float*)d_in[0];
  const float* x      =(const float*)d_in[1];
  const float* V      =(const float*)d_in[2];
  const int*   senders=(const int*)  d_in[3];
  const float* Ww     =(const float*)d_in[4];
  const float* W1     =(const float*)d_in[5];
  const float* W2     =(const float*)d_in[6];
  const float* W3     =(const float*)d_in[7];
  const float* Wl1    =(const float*)d_in[8];
  const float* Wl2    =(const float*)d_in[9];
  float* ws  = (float*)d_ws;
  float* out = (float*)d_out;
  int* cnt    = (int*)(ws + WS_CNT);
  int* off    = (int*)(ws + WS_OFF);
  int* cur    = (int*)(ws + WS_CUR);
  int* sorted = (int*)(ws + WS_SORT);

  k_w3j   <<<14, 128, 0, stream>>>(ws);
  k_c2c3  <<<1, 1, 0, stream>>>(ws);
  k_zero  <<<16, 256, 0, stream>>>(cnt);
  k_count <<<E_EDGES/256, 256, 0, stream>>>(senders, cnt);
  k_scan  <<<1, 1024, 0, stream>>>(cnt, off, cur);
  k_scatter<<<E_EDGES/256, 256, 0, stream>>>(senders, cur, sorted);
  k_edge_pre<<<E_EDGES/4, 256, 0, stream>>>(vectors, x, Ww, ws);
  k_node_acc<<<N_NODES, 64, 0, stream>>>(ws + WS_W, ws + WS_Y, sorted, off, cnt, ws + WS_A);
  // pack AFTER k_node_acc (reuses the then-dead WS_W region)
  k_wpack <<<64, 256, 0, stream>>>(Wl1, Wl2, W1, W2, W3, ws + WS_W);
  k_main  <<<E_EDGES/4, 256, 0, stream>>>(vectors, x, V, senders,
                                          ws, sorted, out);
}

// Round 6
// 621.805 us; speedup vs baseline: 3.1158x; 1.0385x over previous
//
#include <hip/hip_runtime.h>

#define E_EDGES 65536
#define N_NODES 4096

// ---- workspace layout (float offsets) ----
// [0,678)   w3j tensors, [678] C2, [679] C3  (reserve 1024)
#define WS_W     1024                       // E*64   w = x@Ww/8  (dead after k_node_acc; reused for packed weights)
#define WS_Y     (WS_W + E_EDGES*64)        // E*16   Y
#define WS_CNT   (WS_Y + E_EDGES*16)        // 4096 int
#define WS_OFF   (WS_CNT + N_NODES)         // 4096 int
#define WS_CUR   (WS_OFF + N_NODES)         // 4096 int (dead after k_scatter; reused for packed Ww frags = 16 KB exactly)
#define WS_SORT  (WS_CUR + N_NODES)         // E int
#define WS_A     (WS_SORT + E_EDGES)        // N*1024  node accumulator (eps folded)
// high-water: WS_A + 4096*1024 = 9,516,032 floats ~= 38.1 MB

typedef __bf16 bf16x8 __attribute__((ext_vector_type(8)));
typedef float  f32x4  __attribute__((ext_vector_type(4)));

// packed-weight fragment offsets (units of bf16x8 = 16 B), base ws+WS_W
//   Wl1h 0 | Wl1l 2560 | Wl2h 5120 | Wl2l 7680   (10 ks x 4 nt x 64 lanes)
//   W1h 10240 | W1l 12288                        (8 ks x 4 nt x 64)
//   W2h 14336 | W2l 14848 | W3h 15360 | W3l 15872 (2 ks x 4 nt x 64)
#define PK_WL   0
#define PK_W1   10240
#define PK_W2   14336
#define PK_W3   15360

// key order: (0,0,0),(1,1,0),(2,2,0),(0,1,1),(1,0,1),(1,2,1),(2,1,1),(3,2,1),
//            (0,2,2),(1,1,2),(2,0,2),(2,2,2),(3,1,2),(2,1,3)
__constant__ int gK_L1[14] = {0,1,2,0,1,1,2,3,0,1,2,2,3,2};
__constant__ int gK_L2[14] = {0,1,2,1,0,2,1,2,2,1,0,2,1,1};
__constant__ int gK_L3[14] = {0,0,0,1,1,1,1,1,2,2,2,2,2,3};
__constant__ int gK_OFF[14]= {0,1,10,35,44,53,98,143,248,273,318,343,468,573};
__constant__ double gFact[8] = {1.,1.,2.,6.,24.,120.,720.,5040.};

// w3j offsets (compile-time)
#define O_W000 0
#define O_W110 1
#define O_W220 10
#define O_W011 35
#define O_W101 44
#define O_W121 53
#define O_W211 98
#define O_W321 143
#define O_W022 248
#define O_W112 273
#define O_W202 318
#define O_W222 343
#define O_W312 468
#define O_W213 573

__device__ double su2_cg(int j1,int j2,int j3,int m1,int m2,int m3){
  if (m3 != m1+m2) return 0.0;
  double pref = sqrt((double)(2*j3+1)*gFact[j3+j1-j2]*gFact[j3-j1+j2]*gFact[j1+j2-j3]/gFact[j1+j2+j3+1]);
  pref *= sqrt(gFact[j3+m3]*gFact[j3-m3]*gFact[j1-m1]*gFact[j1+m1]*gFact[j2-m2]*gFact[j2+m2]);
  double s=0.0;
  for(int k=0;k<=j1+j2-j3;k++){
    int d1=j1+j2-j3-k, d2=j1-m1-k, d3=j2+m2-k, d4=j3-j2+m1+k, d5=j3-j1-m2+k;
    if(d1<0||d2<0||d3<0||d4<0||d5<0) continue;
    double den=gFact[k]*gFact[d1]*gFact[d2]*gFact[d3]*gFact[d4]*gFact[d5];
    s += (k&1)? (-1.0/den) : (1.0/den);
  }
  return pref*s;
}

__device__ void fill_qmat(int l, double2* q){  // 7x7 row-major, rows=m-basis, cols=real-basis
  for(int i=0;i<49;i++){ q[i].x=0.0; q[i].y=0.0; }
  const double is2 = 0.7071067811865475244;
  for(int m=-l;m<0;m++){
    q[(l+m)*7+(l-m)].x = is2;     // q[l+m, l+|m|] = 1/sqrt2
    q[(l+m)*7+(l+m)].y = -is2;    // q[l+m, l-|m|] = -1j/sqrt2
  }
  q[l*7+l].x = 1.0;
  for(int m=1;m<=l;m++){
    double sg = (m&1)? -1.0 : 1.0;
    q[(l+m)*7+(l+m)].x = sg*is2;
    q[(l+m)*7+(l-m)].y = sg*is2;
  }
  double pr, pi;  // (-i)^l
  switch(l&3){ case 0: pr=1;pi=0;break; case 1: pr=0;pi=-1;break; case 2: pr=-1;pi=0;break; default: pr=0;pi=1;break; }
  for(int i=0;i<49;i++){
    double a=q[i].x, b=q[i].y;
    q[i].x = a*pr - b*pi;
    q[i].y = a*pi + b*pr;
  }
}

__global__ __launch_bounds__(128) void k_w3j(float* __restrict__ ws){
  __shared__ double2 q1[49], q2[49], q3[49];
  __shared__ double C[125], Cr[125];
  __shared__ double red[128];
  int bid = blockIdx.x, t = threadIdx.x;
  int l1=gK_L1[bid], l2=gK_L2[bid], l3=gK_L3[bid];
  int n1=2*l1+1, n2=2*l2+1, n3=2*l3+1, ntot=n1*n2*n3;
  if(t==0){
    fill_qmat(l1,q1); fill_qmat(l2,q2); fill_qmat(l3,q3);
    for(int i=0;i<49;i++) q3[i].y = -q3[i].y;   // conj
  }
  __syncthreads();
  for(int idx=t; idx<ntot; idx+=128){
    int a = idx/(n2*n3), r=idx%(n2*n3), b=r/n3, c=r%n3;
    C[idx] = su2_cg(l1,l2,l3, a-l1, b-l2, c-l3);
  }
  __syncthreads();
  for(int idx=t; idx<ntot; idx+=128){
    int i = idx/(n2*n3), r=idx%(n2*n3), j=r/n3, k=r%n3;
    double ar=0.0;
    for(int a=0;a<n1;a++) for(int b=0;b<n2;b++){
      double2 qa=q1[a*7+i], qb=q2[b*7+j];
      double pr = qa.x*qb.x - qa.y*qb.y;
      double pi = qa.x*qb.y + qa.y*qb.x;
      for(int c=0;c<n3;c++){
        double2 qc=q3[c*7+k];
        double tr = pr*qc.x - pi*qc.y;
        ar += tr*C[(a*n2+b)*n3+c];
      }
    }
    Cr[idx]=ar;
  }
  __syncthreads();
  double ss=0.0;
  for(int idx=t; idx<ntot; idx+=128) ss += Cr[idx]*Cr[idx];
  red[t]=ss; __syncthreads();
  for(int st=64; st>0; st>>=1){ if(t<st) red[t]+=red[t+st]; __syncthreads(); }
  double inv = 1.0/sqrt(red[0]);
  for(int idx=t; idx<ntot; idx+=128) ws[gK_OFF[bid]+idx] = (float)(Cr[idx]*inv);
}

__device__ void do_c2c3(float* ws){
  const float* w112 = ws + O_W112;
  const float* w213 = ws + O_W213;
  double u0=0.3, u1=-0.4, u2=sqrt(0.75);
  double s3=sqrt(3.0);
  double y1[3]={s3*u0, s3*u1, s3*u2};
  double y2r[5]={0,0,0,0,0};
  for(int i=0;i<3;i++) for(int j=0;j<3;j++) for(int k=0;k<5;k++)
    y2r[k] += y1[i]*y1[j]*(double)w112[(i*3+j)*5+k];
  double nn=0; for(int k=0;k<5;k++) nn += y2r[k]*y2r[k];
  double c2 = sqrt(5.0)/sqrt(nn);
  double y2[5]; for(int k=0;k<5;k++) y2[k]=c2*y2r[k];
  double y3r[7]={0,0,0,0,0,0,0};
  for(int i=0;i<5;i++) for(int j=0;j<3;j++) for(int n=0;n<7;n++)
    y3r[n] += y2[i]*y1[j]*(double)w213[(i*3+j)*7+n];
  nn=0; for(int n=0;n<7;n++) nn += y3r[n]*y3r[n];
  double c3 = sqrt(7.0)/sqrt(nn);
  ws[678]=(float)c2; ws[679]=(float)c3;
}

__global__ void k_zero(int* __restrict__ cnt){
  int i = blockIdx.x*256 + threadIdx.x;
  if(i < N_NODES) cnt[i]=0;
}
__global__ void k_count(const int* __restrict__ senders, int* __restrict__ cnt){
  int e = blockIdx.x*256 + threadIdx.x;
  if(e < E_EDGES) atomicAdd(&cnt[senders[e]], 1);
}
__global__ __launch_bounds__(1024) void k_scan(const int* __restrict__ cnt, int* __restrict__ off, int* __restrict__ cur){
  __shared__ int part[1024];
  int t = threadIdx.x;
  int c0=cnt[4*t], c1=cnt[4*t+1], c2=cnt[4*t+2], c3=cnt[4*t+3];
  int l0=0, l1=c0, l2=c0+c1, l3=c0+c1+c2;
  int sum=l3+c3;
  part[t]=sum; __syncthreads();
  for(int st=1; st<1024; st<<=1){
    int v = part[t];
    int add = (t>=st)? part[t-st] : 0;
    __syncthreads();
    part[t] = v + add;
    __syncthreads();
  }
  int pref = (t>0)? part[t-1] : 0;
  off[4*t]=pref+l0; off[4*t+1]=pref+l1; off[4*t+2]=pref+l2; off[4*t+3]=pref+l3;
  cur[4*t]=pref+l0; cur[4*t+1]=pref+l1; cur[4*t+2]=pref+l2; cur[4*t+3]=pref+l3;
}
__global__ void k_scatter(const int* __restrict__ senders, int* __restrict__ cur, int* __restrict__ sorted){
  int e = blockIdx.x*256 + threadIdx.x;
  if(e < E_EDGES){
    int pos = atomicAdd(&cur[senders[e]], 1);
    sorted[pos] = e;
  }
}

// pack Ww (64x64) into bf16 hi/lo B-frags at WS_CUR (dead after k_scatter).
// layout [part(2)][ks(2)][nt(4)][lane(64)] = 1024 frags = 16 KB exactly.
// block 4: computes C2/C3 (merged former k_c2c3 launch).
__global__ __launch_bounds__(256) void k_wwpack(const float* __restrict__ Ww, float* __restrict__ ws){
  if(blockIdx.x == 4){
    if(threadIdx.x == 0) do_c2c3(ws);
    return;
  }
  int idx = blockIdx.x*256 + threadIdx.x;   // 0..1023
  int lane = idx & 63, nt = (idx>>6)&3, ks = (idx>>8)&1, part = idx>>9;
  int c = nt*16 + (lane & 15);
  int g = lane >> 4;
  bf16x8 outv;
  #pragma unroll
  for(int j=0;j<8;j++){
    int k = ks*32 + g*8 + j;
    float v = Ww[k*64 + c];
    __bf16 hb = (__bf16)v;
    outv[j] = part ? (__bf16)(v - (float)hb) : hb;
  }
  ((bf16x8*)(ws + WS_CUR))[idx] = outv;
}

// pack Wl1/Wl2/W1/W2/W3 into bf16 hi/lo MFMA B-fragments.
// frag convention (matches A-pack in k_main): col = nt*16 + (lane&15),
// k = ks*32 + (lane>>4)*8 + j.  (consistent A/B k-mapping => correct dot
// product under any HW k-permutation.)
__global__ __launch_bounds__(256) void k_wpack(
    const float* __restrict__ Wl1, const float* __restrict__ Wl2,
    const float* __restrict__ W1, const float* __restrict__ W2,
    const float* __restrict__ W3, float* __restrict__ wpk){
  int idx = blockIdx.x*256 + threadIdx.x;   // 64 blocks = 16384 frags
  int lane = idx & 63;
  const float* W; int part, ks, nt;
  if(idx < PK_W1){                       // Wl1/Wl2: [mp][ks10][nt][lane]
    nt = (idx>>6)&3; int rest = idx>>8; ks = rest%10; int mp = rest/10;
    part = mp&1; W = (mp>>1)? Wl2 : Wl1;
  } else if(idx < PK_W2){                // W1: [part][ks8][nt][lane]
    int rel = idx - PK_W1; part = rel>>11; int r2 = rel & 2047;
    ks = r2>>8; nt = (r2>>6)&3; W = W1;
  } else if(idx < PK_W3){                // W2: [part][ks2][nt][lane]
    int rel = idx - PK_W2; part = rel>>9; int r2 = rel & 511;
    ks = r2>>8; nt = (r2>>6)&3; W = W2;
  } else {                               // W3: [part][ks2][nt][lane]
    int rel = idx - PK_W3; part = rel>>9; int r2 = rel & 511;
    ks = r2>>8; nt = (r2>>6)&3; W = W3;
  }
  int c = nt*16 + (lane & 15);
  int g = lane >> 4;
  bf16x8 outv;
  #pragma unroll
  for(int j=0;j<8;j++){
    int k = ks*32 + g*8 + j;
    float v = W[k*64 + c];
    __bf16 hb = (__bf16)v;
    outv[j] = part ? (__bf16)(v - (float)hb) : hb;
  }
  ((bf16x8*)wpk)[idx] = outv;
}

__device__ inline void split1(float v, __bf16& h, __bf16& l){
  h = (__bf16)v;
  l = (__bf16)(v - (float)h);
}

// per edge: Y[16] spherical harmonics (wave = edge, lane0 writes);
// w = x@Ww/8 on MFMA: wave = N-tile (16 muls), A rows = 4 block-edges
// duplicated mod 4 (same proven trick as k_main's MLP); 6 MFMA/wave replaces
// 64 VMEM Ww loads + a 64-deep serial FMA chain per thread.
__global__ __launch_bounds__(256) void k_edge_pre(
    const float* __restrict__ vectors, const float* __restrict__ x,
    float* __restrict__ ws){
  int t = threadIdx.x;
  int wv = t >> 6, lane = t & 63;
  int e = blockIdx.x*4 + wv;
  const float* w112 = ws + O_W112;
  const float* w213 = ws + O_W213;
  float C2v = ws[678], C3v = ws[679];
  float v0=vectors[e*3], v1=vectors[e*3+1], v2=vectors[e*3+2];
  float len = sqrtf(v0*v0+v1*v1+v2*v2);
  float inv = 1.0f/(len + 1e-12f);
  float s3 = 1.7320508075688772f;
  float y1v[3] = { s3*v0*inv, s3*v1*inv, s3*v2*inv };
  float y2[5];
  #pragma unroll
  for(int k=0;k<5;k++){
    float a=0.f;
    #pragma unroll
    for(int i=0;i<3;i++)
      #pragma unroll
      for(int j=0;j<3;j++) a += y1v[i]*y1v[j]*w112[(i*3+j)*5+k];
    y2[k]=C2v*a;
  }
  float y3[7];
  #pragma unroll
  for(int n=0;n<7;n++){
    float a=0.f;
    #pragma unroll
    for(int i=0;i<5;i++)
      #pragma unroll
      for(int j=0;j<3;j++) a += y2[i]*y1v[j]*w213[(i*3+j)*7+n];
    y3[n]=C3v*a;
  }
  // w = x@Ww/8 via MFMA (3-term bf16 hi/lo split)
  {
    int g = lane >> 4, r = lane & 15, he = r & 3;
    const float* xrow = x + (blockIdx.x*4 + he)*64;
    const bf16x8* WWP = (const bf16x8*)(ws + WS_CUR);  // [part][ks][nt][lane]
    f32x4 acc = {0.f,0.f,0.f,0.f};
    #pragma unroll
    for(int ks=0; ks<2; ks++){
      const float* xp = xrow + ks*32 + g*8;
      bf16x8 ah, al;
      #pragma unroll
      for(int j=0;j<8;j++){
        __bf16 h,l; split1(xp[j],h,l);
        ah[j]=h; al[j]=l;
      }
      bf16x8 bh = WWP[      ks*256 + wv*64 + lane];
      bf16x8 bl = WWP[512 + ks*256 + wv*64 + lane];
      acc = __builtin_amdgcn_mfma_f32_16x16x32_bf16(ah, bh, acc, 0,0,0);
      acc = __builtin_amdgcn_mfma_f32_16x16x32_bf16(ah, bl, acc, 0,0,0);
      acc = __builtin_amdgcn_mfma_f32_16x16x32_bf16(al, bh, acc, 0,0,0);
    }
    // C: col = lane&15 (mul u = wv*16+r), row = g*4+reg -> edge = reg (mod 4)
    if(g==0){
      #pragma unroll
      for(int reg=0; reg<4; reg++)
        ws[WS_W + (blockIdx.x*4+reg)*64 + wv*16 + r] = acc[reg]*0.125f;
    }
  }
  if(lane==0){
    float* Yp = ws + WS_Y + e*16;
    Yp[0]=1.0f;
    Yp[1]=y1v[0]; Yp[2]=y1v[1]; Yp[3]=y1v[2];
    Yp[4]=y2[0]; Yp[5]=y2[1]; Yp[6]=y2[2]; Yp[7]=y2[3]; Yp[8]=y2[4];
    Yp[9]=y3[0]; Yp[10]=y3[1]; Yp[11]=y3[2]; Yp[12]=y3[3]; Yp[13]=y3[4]; Yp[15]=y3[6]; Yp[14]=y3[5];
  }
}

// per node: A[n][m][k] = eps * sum_e w[e][m]*Y[e][k]
// software-pipelined: next sorted[] index loaded while current edge processes.
__global__ __launch_bounds__(64) void k_node_acc(
    const float* __restrict__ ws_w, const float* __restrict__ ws_y,
    const int* __restrict__ sorted, const int* __restrict__ off, const int* __restrict__ cnt,
    float* __restrict__ A){
  int n = blockIdx.x, m = threadIdx.x;
  float acc[16];
  #pragma unroll
  for(int k=0;k<16;k++) acc[k]=0.f;
  int o = off[n], c = cnt[n];
  if(c > 0){
    int e = sorted[o];
    for(int j=0;j<c;j++){
      int e_nx = (j+1<c) ? sorted[o+j+1] : 0;
      float wm = ws_w[e*64+m];
      const float4* Yp4 = (const float4*)(ws_y + e*16);
      float4 y0=Yp4[0], y1=Yp4[1], y2=Yp4[2], y3=Yp4[3];
      acc[0] += wm*y0.x; acc[1] += wm*y0.y; acc[2] += wm*y0.z; acc[3] += wm*y0.w;
      acc[4] += wm*y1.x; acc[5] += wm*y1.y; acc[6] += wm*y1.z; acc[7] += wm*y1.w;
      acc[8] += wm*y2.x; acc[9] += wm*y2.y; acc[10]+= wm*y2.z; acc[11]+= wm*y2.w;
      acc[12]+= wm*y3.x; acc[13]+= wm*y3.y; acc[14]+= wm*y3.z; acc[15]+= wm*y3.w;
      e = e_nx;
    }
  }
  float4* outp = (float4*)(A + n*1024 + m*16);
  outp[0] = make_float4(acc[0]*0.25f, acc[1]*0.25f, acc[2]*0.25f, acc[3]*0.25f);
  outp[1] = make_float4(acc[4]*0.25f, acc[5]*0.25f, acc[6]*0.25f, acc[7]*0.25f);
  outp[2] = make_float4(acc[8]*0.25f, acc[9]*0.25f, acc[10]*0.25f, acc[11]*0.25f);
  outp[3] = make_float4(acc[12]*0.25f, acc[13]*0.25f, acc[14]*0.25f, acc[15]*0.25f);
}

// main fused kernel: 4 edges per block (sorted order for A-gather locality)
// LDS ~48.9 KB -> 3 blocks/CU; barriers per block: 4.
// w3j coefficients read directly from global ws with compile-time offsets
// (wave-uniform -> SMEM s_loads off the LDS pipe).
// pd stored as bf16 hi/lo (converted ONCE at phase-1 write) -> phase-2 reads
// MFMA A-frags directly via ds_read_b128, zero per-k-step conversion VALU.
// MLP also on MFMA: M=4 rows duplicate mod-4 across the 16-row tile.
// All GEMMs use the bf16 hi/lo 3-term split (hh+hl+lh, ~2^-15 rel err).
__global__ __launch_bounds__(256, 3) void k_main(
    const float* __restrict__ vectors, const float* __restrict__ x, const float* __restrict__ V,
    const int* __restrict__ senders,
    const float* __restrict__ ws, const int* __restrict__ sorted,
    float* __restrict__ out){
  __shared__ __align__(16) __bf16 lds_pdh[32*328];   // 20992 B
  __shared__ __align__(16) __bf16 lds_pdl[32*328];   // 20992 B
  __shared__ __align__(16) __bf16 lds_hh[4*264];     // 2112 B  h=[x|S] hi
  __shared__ __align__(16) __bf16 lds_hl[4*264];     // 2112 B  lo
  __shared__ __align__(16) __bf16 lds_h1h[4*72];     // 576 B
  __shared__ __align__(16) __bf16 lds_h1l[4*72];
  __shared__ __align__(16) __bf16 lds_h2h[4*72];
  __shared__ __align__(16) __bf16 lds_h2l[4*72];
  __shared__ float lds_env[4];
  __shared__ int   lds_eid[4];

  int t = threadIdx.x;
  int wv = t>>6, lane = t&63;
  int eid = sorted[blockIdx.x*4 + wv];
  if(lane==0) lds_eid[wv]=eid;
  __syncthreads();

  const float* lw = ws;   // w3j via SMEM (compile-time offsets, uniform)
  // ---- phase 1: per-edge (one wave per edge) ----
  {
    float v0=vectors[eid*3], v1=vectors[eid*3+1], v2=vectors[eid*3+2];
    float d = sqrtf(v0*v0+v1*v1+v2*v2);
    float d2=d*d, d4=d2*d2, d6=d4*d2, d7=d6*d, d8=d7*d;
    float env = 1.0f - 28.0f*d6 + 48.0f*d7 - 21.0f*d8;
    env = (d < 1.0f) ? env : 0.0f;
    if(lane==0) lds_env[wv]=env;
  }
  int snd = senders[eid];
  const float4* Ap4 = (const float4*)(ws + WS_A + snd*1024 + lane*16);
  float4 a0=Ap4[0], a1=Ap4[1], a2=Ap4[2], a3=Ap4[3];
  float wY[16] = {a0.x,a0.y,a0.z,a0.w, a1.x,a1.y,a1.z,a1.w,
                  a2.x,a2.y,a2.z,a2.w, a3.x,a3.y,a3.z,a3.w};
  const float* Vp = V + eid*576;
  float V0 = Vp[lane];
  float V1f[3], V2f[5];
  #pragma unroll
  for(int i=0;i<3;i++) V1f[i]=Vp[64+lane*3+i];
  #pragma unroll
  for(int j=0;j<5;j++) V2f[j]=Vp[256+lane*5+j];
  // h = [x | S] stored bf16 hi/lo (k index = lane within each 64-segment)
  {
    __bf16 hh, hl;
    split1(x[eid*64+lane], hh, hl);
    lds_hh[wv*264 + lane] = hh; lds_hl[wv*264 + lane] = hl;
  }
  // scalar channel S
  float s0 = wY[0]*V0*lw[O_W000];
  float s1 = 0.f;
  #pragma unroll
  for(int i=0;i<3;i++)
    #pragma unroll
    for(int j=0;j<3;j++) s1 += wY[1+i]*V1f[j]*lw[O_W110 + i*3+j];
  float s2 = 0.f;
  #pragma unroll
  for(int i=0;i<5;i++)
    #pragma unroll
    for(int j=0;j<5;j++) s2 += wY[4+i]*V2f[j]*lw[O_W220 + i*5+j];
  {
    __bf16 hh, hl;
    split1(s0, hh, hl); lds_hh[wv*264+ 64+lane]=hh; lds_hl[wv*264+ 64+lane]=hl;
    split1(s1, hh, hl); lds_hh[wv*264+128+lane]=hh; lds_hl[wv*264+128+lane]=hl;
    split1(s2, hh, hl); lds_hh[wv*264+192+lane]=hh; lds_hl[wv*264+192+lane]=hl;
  }
  // P paths (l3=1): i=0..2.  D paths (l3=2): j=0..4.
  float P0[3]={0,0,0}, P1[3]={0,0,0}, P2[3]={0,0,0}, P3[3]={0,0,0}, P4[3]={0,0,0};
  float D0[5]={0,0,0,0,0}, D1[5]={0,0,0,0,0}, D2[5]={0,0,0,0,0}, D3[5]={0,0,0,0,0}, D4[5]={0,0,0,0,0};
  #pragma unroll
  for(int b=0;b<3;b++){ float pb=wY[0]*V1f[b];
    #pragma unroll
    for(int i=0;i<3;i++) P0[i]+= pb*lw[O_W011 + b*3+i]; }
  #pragma unroll
  for(int a=0;a<3;a++){ float pa=wY[1+a]*V0;
    #pragma unroll
    for(int i=0;i<3;i++) P1[i]+= pa*lw[O_W101 + a*3+i]; }
  #pragma unroll
  for(int a=0;a<3;a++)
    #pragma unroll
    for(int b=0;b<5;b++){ float p=wY[1+a]*V2f[b];
      #pragma unroll
      for(int i=0;i<3;i++) P2[i]+= p*lw[O_W121 + (a*5+b)*3+i]; }
  #pragma unroll
  for(int a=0;a<5;a++)
    #pragma unroll
    for(int b=0;b<3;b++){ float p=wY[4+a]*V1f[b];
      #pragma unroll
      for(int i=0;i<3;i++) P3[i]+= p*lw[O_W211 + (a*3+b)*3+i]; }
  #pragma unroll
  for(int a=0;a<7;a++)
    #pragma unroll
    for(int b=0;b<5;b++){ float p=wY[9+a]*V2f[b];
      #pragma unroll
      for(int i=0;i<3;i++) P4[i]+= p*lw[O_W321 + (a*5+b)*3+i]; }
  #pragma unroll
  for(int b=0;b<5;b++){ float pb=wY[0]*V2f[b];
    #pragma unroll
    for(int j=0;j<5;j++) D0[j]+= pb*lw[O_W022 + b*5+j]; }
  #pragma unroll
  for(int a=0;a<3;a++)
    #pragma unroll
    for(int b=0;b<3;b++){ float p=wY[1+a]*V1f[b];
      #pragma unroll
      for(int j=0;j<5;j++) D1[j]+= p*lw[O_W112 + (a*3+b)*5+j]; }
  #pragma unroll
  for(int a=0;a<5;a++){ float pa=wY[4+a]*V0;
    #pragma unroll
    for(int j=0;j<5;j++) D2[j]+= pa*lw[O_W202 + a*5+j]; }
  #pragma unroll
  for(int a=0;a<5;a++)
    #pragma unroll
    for(int b=0;b<5;b++){ float p=wY[4+a]*V2f[b];
      #pragma unroll
      for(int j=0;j<5;j++) D3[j]+= p*lw[O_W222 + (a*5+b)*5+j]; }
  #pragma unroll
  for(int a=0;a<7;a++)
    #pragma unroll
    for(int b=0;b<3;b++){ float p=wY[9+a]*V1f[b];
      #pragma unroll
      for(int j=0;j<5;j++) D4[j]+= p*lw[O_W312 + (a*3+b)*5+j]; }
  // stage into lds_pd hi/lo (fold sqrt(2*l3+1)); lane stride-1 writes.
  // rows: P -> wv*3+i (0..11); D -> 12 + wv*5 + j (12..31)
  {
    const float SQ3 = 1.7320508075688772f, SQ5 = 2.2360679774997896f;
    #pragma unroll
    for(int i=0;i<3;i++){
      int row = wv*3+i;
      float vals[5] = {SQ3*P0[i], SQ3*P1[i], SQ3*P2[i], SQ3*P3[i], SQ3*P4[i]};
      #pragma unroll
      for(int p=0;p<5;p++){
        __bf16 h,l; split1(vals[p],h,l);
        lds_pdh[row*328 + p*64 + lane] = h;
        lds_pdl[row*328 + p*64 + lane] = l;
      }
    }
    #pragma unroll
    for(int j=0;j<5;j++){
      int row = 12 + wv*5 + j;
      float vals[5] = {SQ5*D0[j], SQ5*D1[j], SQ5*D2[j], SQ5*D3[j], SQ5*D4[j]};
      #pragma unroll
      for(int p=0;p<5;p++){
        __bf16 h,l; split1(vals[p],h,l);
        lds_pdh[row*328 + p*64 + lane] = h;
        lds_pdl[row*328 + p*64 + lane] = l;
      }
    }
  }
  __syncthreads();

  int g = lane >> 4, r = lane & 15;
  const bf16x8* WB = (const bf16x8*)(ws + WS_W);

  // ---- MLP on MFMA (A rows = edge, duplicated mod 4; reg = edge in C) ----
  {
    int he = r & 3;
    f32x4 acc = {0.f,0.f,0.f,0.f};
    #pragma unroll
    for(int ks=0; ks<8; ks++){
      bf16x8 ah = *(const bf16x8*)(lds_hh + he*264 + ks*32 + g*8);
      bf16x8 al = *(const bf16x8*)(lds_hl + he*264 + ks*32 + g*8);
      bf16x8 bh = WB[PK_W1        + (ks*4+wv)*64 + lane];
      bf16x8 bl = WB[PK_W1 + 2048 + (ks*4+wv)*64 + lane];
      acc = __builtin_amdgcn_mfma_f32_16x16x32_bf16(ah, bh, acc, 0,0,0);
      acc = __builtin_amdgcn_mfma_f32_16x16x32_bf16(ah, bl, acc, 0,0,0);
      acc = __builtin_amdgcn_mfma_f32_16x16x32_bf16(al, bh, acc, 0,0,0);
    }
    if(g==0){
      #pragma unroll
      for(int e_=0;e_<4;e_++){
        float a = acc[e_]*(1.0f/16.0f);
        float h1 = a/(1.0f+__expf(-a));
        __bf16 hh,hl; split1(h1,hh,hl);
        lds_h1h[e_*72 + wv*16 + r] = hh;
        lds_h1l[e_*72 + wv*16 + r] = hl;
      }
    }
    __syncthreads();
    acc = (f32x4){0.f,0.f,0.f,0.f};
    #pragma unroll
    for(int ks=0; ks<2; ks++){
      bf16x8 ah = *(const bf16x8*)(lds_h1h + he*72 + ks*32 + g*8);
      bf16x8 al = *(const bf16x8*)(lds_h1l + he*72 + ks*32 + g*8);
      bf16x8 bh = WB[PK_W2       + (ks*4+wv)*64 + lane];
      bf16x8 bl = WB[PK_W2 + 512 + (ks*4+wv)*64 + lane];
      acc = __builtin_amdgcn_mfma_f32_16x16x32_bf16(ah, bh, acc, 0,0,0);
      acc = __builtin_amdgcn_mfma_f32_16x16x32_bf16(ah, bl, acc, 0,0,0);
      acc = __builtin_amdgcn_mfma_f32_16x16x32_bf16(al, bh, acc, 0,0,0);
    }
    if(g==0){
      #pragma unroll
      for(int e_=0;e_<4;e_++){
        float a = acc[e_]*0.125f;
        float h2 = a/(1.0f+__expf(-a));
        __bf16 hh,hl; split1(h2,hh,hl);
        lds_h2h[e_*72 + wv*16 + r] = hh;
        lds_h2l[e_*72 + wv*16 + r] = hl;
      }
    }
    __syncthreads();
    acc = (f32x4){0.f,0.f,0.f,0.f};
    #pragma unroll
    for(int ks=0; ks<2; ks++){
      bf16x8 ah = *(const bf16x8*)(lds_h2h + he*72 + ks*32 + g*8);
      bf16x8 al = *(const bf16x8*)(lds_h2l + he*72 + ks*32 + g*8);
      bf16x8 bh = WB[PK_W3       + (ks*4+wv)*64 + lane];
      bf16x8 bl = WB[PK_W3 + 512 + (ks*4+wv)*64 + lane];
      acc = __builtin_amdgcn_mfma_f32_16x16x32_bf16(ah, bh, acc, 0,0,0);
      acc = __builtin_amdgcn_mfma_f32_16x16x32_bf16(ah, bl, acc, 0,0,0);
      acc = __builtin_amdgcn_mfma_f32_16x16x32_bf16(al, bh, acc, 0,0,0);
    }
    if(g==0){
      #pragma unroll
      for(int e_=0;e_<4;e_++)
        out[lds_eid[e_]*576 + wv*16 + r] = lds_env[e_]*acc[e_]*0.125f;
    }
  }

  // ---- phase 2: MFMA projections. wave = N-tile (nt = wv), 16 u-cols each.
  // A-frags read directly as bf16 hi/lo from LDS (no conversions).
  {
    f32x4 accP  = {0.f,0.f,0.f,0.f};
    f32x4 accD0 = {0.f,0.f,0.f,0.f};
    f32x4 accD1 = {0.f,0.f,0.f,0.f};
    int rP  = (r < 12) ? r : 11;          // clamp: C rows 12-15 discarded
    int rD0 = 12 + r;                     // D rows 0..15
    int rD1 = 12 + ((r < 4) ? (16 + r) : 19);  // D rows 16..19; rest clamped
    const __bf16* pPh  = lds_pdh + rP *328 + g*8;
    const __bf16* pPl  = lds_pdl + rP *328 + g*8;
    const __bf16* pD0h = lds_pdh + rD0*328 + g*8;
    const __bf16* pD0l = lds_pdl + rD0*328 + g*8;
    const __bf16* pD1h = lds_pdh + rD1*328 + g*8;
    const __bf16* pD1l = lds_pdl + rD1*328 + g*8;
    #pragma unroll 2
    for(int ks=0; ks<10; ks++){
      int bbase = (ks*4 + wv)*64 + lane;
      bf16x8 b1h = WB[bbase];             // Wl1 hi
      bf16x8 b1l = WB[bbase + 2560];      // Wl1 lo
      bf16x8 b2h = WB[bbase + 5120];      // Wl2 hi
      bf16x8 b2l = WB[bbase + 7680];      // Wl2 lo
      bf16x8 aPh  = *(const bf16x8*)(pPh  + ks*32);
      bf16x8 aPl  = *(const bf16x8*)(pPl  + ks*32);
      bf16x8 aD0h = *(const bf16x8*)(pD0h + ks*32);
      bf16x8 aD0l = *(const bf16x8*)(pD0l + ks*32);
      bf16x8 aD1h = *(const bf16x8*)(pD1h + ks*32);
      bf16x8 aD1l = *(const bf16x8*)(pD1l + ks*32);
      accP  = __builtin_amdgcn_mfma_f32_16x16x32_bf16(aPh,  b1h, accP,  0,0,0);
      accP  = __builtin_amdgcn_mfma_f32_16x16x32_bf16(aPh,  b1l, accP,  0,0,0);
      accP  = __builtin_amdgcn_mfma_f32_16x16x32_bf16(aPl,  b1h, accP,  0,0,0);
      accD0 = __builtin_amdgcn_mfma_f32_16x16x32_bf16(aD0h, b2h, accD0, 0,0,0);
      accD0 = __builtin_amdgcn_mfma_f32_16x16x32_bf16(aD0h, b2l, accD0, 0,0,0);
      accD0 = __builtin_amdgcn_mfma_f32_16x16x32_bf16(aD0l, b2h, accD0, 0,0,0);
      accD1 = __builtin_amdgcn_mfma_f32_16x16x32_bf16(aD1h, b2h, accD1, 0,0,0);
      accD1 = __builtin_amdgcn_mfma_f32_16x16x32_bf16(aD1h, b2l, accD1, 0,0,0);
      accD1 = __builtin_amdgcn_mfma_f32_16x16x32_bf16(aD1l, b2h, accD1, 0,0,0);
    }
    // C layout (m89-verified): col = lane&15, row = (lane>>4)*4 + reg
    const float sc = 0.05590169943749474f;  // 1/sqrt(320)
    int u = wv*16 + r;
    if(g < 3){
      #pragma unroll
      for(int reg=0; reg<4; reg++){
        int R = g*4 + reg;                 // 0..11 : P row = e*3 + i
        int e_ = R/3, i_ = R - e_*3;
        out[lds_eid[e_]*576 + 64 + u*3 + i_] = accP[reg]*sc;
      }
    }
    #pragma unroll
    for(int reg=0; reg<4; reg++){
      int Dr = g*4 + reg;                  // 0..15 : D row = e*5 + j
      int e_ = Dr/5, j_ = Dr - e_*5;
      out[lds_eid[e_]*576 + 256 + u*5 + j_] = accD0[reg]*sc;
    }
    if(g == 0){
      #pragma unroll
      for(int reg=0; reg<4; reg++){
        int Dr = 16 + reg;                 // 16..19 -> e=3, j=1..4
        int e_ = Dr/5, j_ = Dr - e_*5;
        out[lds_eid[e_]*576 + 256 + u*5 + j_] = accD1[reg]*sc;
      }
    }
  }
}

extern "C" void kernel_launch(void* const* d_in, const int* in_sizes, int n_in,
                              void* d_out, int out_size, void* d_ws, size_t ws_size,
                              hipStream_t stream) {
  const float* vectors=(const float*)d_in[0];
  const float* x      =(const float*)d_in[1];
  const float* V      =(const float*)d_in[2];
  const int*   senders=(const int*)  d_in[3];
  const float* Ww     =(const float*)d_in[4];
  const float* W1     =(const float*)d_in[5];
  const float* W2     =(const float*)d_in[6];
  const float* W3     =(const float*)d_in[7];
  const float* Wl1    =(const float*)d_in[8];
  const float* Wl2    =(const float*)d_in[9];
  float* ws  = (float*)d_ws;
  float* out = (float*)d_out;
  int* cnt    = (int*)(ws + WS_CNT);
  int* off    = (int*)(ws + WS_OFF);
  int* cur    = (int*)(ws + WS_CUR);
  int* sorted = (int*)(ws + WS_SORT);

  k_w3j   <<<14, 128, 0, stream>>>(ws);
  k_zero  <<<16, 256, 0, stream>>>(cnt);
  k_count <<<E_EDGES/256, 256, 0, stream>>>(senders, cnt);
  k_scan  <<<1, 1024, 0, stream>>>(cnt, off, cur);
  k_scatter<<<E_EDGES/256, 256, 0, stream>>>(senders, cur, sorted);
  // packs Ww frags into WS_CUR (dead after scatter) + computes C2/C3 (block 4)
  k_wwpack<<<5, 256, 0, stream>>>(Ww, ws);
  k_edge_pre<<<E_EDGES/4, 256, 0, stream>>>(vectors, x, ws);
  k_node_acc<<<N_NODES, 64, 0, stream>>>(ws + WS_W, ws + WS_Y, sorted, off, cnt, ws + WS_A);
  // pack AFTER k_node_acc (reuses the then-dead WS_W region)
  k_wpack <<<64, 256, 0, stream>>>(Wl1, Wl2, W1, W2, W3, ws + WS_W);
  k_main  <<<E_EDGES/4, 256, 0, stream>>>(vectors, x, V, senders,
                                          ws, sorted, out);
}

// Round 7
// 597.613 us; speedup vs baseline: 3.2419x; 1.0405x over previous
//
#include <hip/hip_runtime.h>

#define E_EDGES 65536
#define N_NODES 4096

// ---- workspace layout (float offsets) ----
// [0,678)   w3j tensors, [678] C2, [679] C3  (reserve 1024)
#define WS_W     1024                       // E*64   w = x@Ww/8  (dead after k_node_acc; reused for packed weights)
#define WS_Y     (WS_W + E_EDGES*64)        // E*16   Y
#define WS_CNT   (WS_Y + E_EDGES*16)        // 4096 int
#define WS_OFF   (WS_CNT + N_NODES)         // 4096 int
#define WS_CUR   (WS_OFF + N_NODES)         // 4096 int (dead after k_scatter; reused for packed Ww frags = 16 KB exactly)
#define WS_SORT  (WS_CUR + N_NODES)         // E int
#define WS_A     (WS_SORT + E_EDGES)        // N*1024  node accumulator (eps folded)
// high-water: WS_A + 4096*1024 = 9,516,032 floats ~= 38.1 MB

typedef __bf16 bf16x8 __attribute__((ext_vector_type(8)));
typedef float  f32x4  __attribute__((ext_vector_type(4)));

// packed-weight fragment offsets (units of bf16x8 = 16 B), base ws+WS_W
#define PK_WL   0
#define PK_W1   10240
#define PK_W2   14336
#define PK_W3   15360

// real-basis CG sparsity: w3j_real[i,j,k] can be nonzero only if
//  (a) |m| triangle: |mk| == |mi|+|mj| or ||mi|-|mj||  (q mixes only +-m)
//  (b) even number of sin-type (m<0) indices (phi-integral parity)
// Both are exact vanishing theorems -> no false negatives; false positives
// just FMA a stored zero. Guarded FMAs with constant indices fold at compile.
__host__ __device__ constexpr bool nz(int l1,int l2,int l3,int i,int j,int k){
  int m1=i-l1, m2=j-l2, m3=k-l3;
  int a1=m1<0?-m1:m1, a2=m2<0?-m2:m2, a3=m3<0?-m3:m3;
  bool tri = (a1+a2==a3)||(a2+a3==a1)||(a3+a1==a2);
  int s=(m1<0)+(m2<0)+(m3<0);
  return tri && ((s&1)==0);
}

// key order: (0,0,0),(1,1,0),(2,2,0),(0,1,1),(1,0,1),(1,2,1),(2,1,1),(3,2,1),
//            (0,2,2),(1,1,2),(2,0,2),(2,2,2),(3,1,2),(2,1,3)
__constant__ int gK_L1[14] = {0,1,2,0,1,1,2,3,0,1,2,2,3,2};
__constant__ int gK_L2[14] = {0,1,2,1,0,2,1,2,2,1,0,2,1,1};
__constant__ int gK_L3[14] = {0,0,0,1,1,1,1,1,2,2,2,2,2,3};
__constant__ int gK_OFF[14]= {0,1,10,35,44,53,98,143,248,273,318,343,468,573};
__constant__ double gFact[8] = {1.,1.,2.,6.,24.,120.,720.,5040.};

// w3j offsets (compile-time)
#define O_W000 0
#define O_W110 1
#define O_W220 10
#define O_W011 35
#define O_W101 44
#define O_W121 53
#define O_W211 98
#define O_W321 143
#define O_W022 248
#define O_W112 273
#define O_W202 318
#define O_W222 343
#define O_W312 468
#define O_W213 573

__device__ double su2_cg(int j1,int j2,int j3,int m1,int m2,int m3){
  if (m3 != m1+m2) return 0.0;
  double pref = sqrt((double)(2*j3+1)*gFact[j3+j1-j2]*gFact[j3-j1+j2]*gFact[j1+j2-j3]/gFact[j1+j2+j3+1]);
  pref *= sqrt(gFact[j3+m3]*gFact[j3-m3]*gFact[j1-m1]*gFact[j1+m1]*gFact[j2-m2]*gFact[j2+m2]);
  double s=0.0;
  for(int k=0;k<=j1+j2-j3;k++){
    int d1=j1+j2-j3-k, d2=j1-m1-k, d3=j2+m2-k, d4=j3-j2+m1+k, d5=j3-j1-m2+k;
    if(d1<0||d2<0||d3<0||d4<0||d5<0) continue;
    double den=gFact[k]*gFact[d1]*gFact[d2]*gFact[d3]*gFact[d4]*gFact[d5];
    s += (k&1)? (-1.0/den) : (1.0/den);
  }
  return pref*s;
}

__device__ void fill_qmat(int l, double2* q){  // 7x7 row-major, rows=m-basis, cols=real-basis
  for(int i=0;i<49;i++){ q[i].x=0.0; q[i].y=0.0; }
  const double is2 = 0.7071067811865475244;
  for(int m=-l;m<0;m++){
    q[(l+m)*7+(l-m)].x = is2;     // q[l+m, l+|m|] = 1/sqrt2
    q[(l+m)*7+(l+m)].y = -is2;    // q[l+m, l-|m|] = -1j/sqrt2
  }
  q[l*7+l].x = 1.0;
  for(int m=1;m<=l;m++){
    double sg = (m&1)? -1.0 : 1.0;
    q[(l+m)*7+(l+m)].x = sg*is2;
    q[(l+m)*7+(l-m)].y = sg*is2;
  }
  double pr, pi;  // (-i)^l
  switch(l&3){ case 0: pr=1;pi=0;break; case 1: pr=0;pi=-1;break; case 2: pr=-1;pi=0;break; default: pr=0;pi=1;break; }
  for(int i=0;i<49;i++){
    double a=q[i].x, b=q[i].y;
    q[i].x = a*pr - b*pi;
    q[i].y = a*pi + b*pr;
  }
}

__global__ __launch_bounds__(128) void k_w3j(float* __restrict__ ws){
  __shared__ double2 q1[49], q2[49], q3[49];
  __shared__ double C[125], Cr[125];
  __shared__ double red[128];
  int bid = blockIdx.x, t = threadIdx.x;
  int l1=gK_L1[bid], l2=gK_L2[bid], l3=gK_L3[bid];
  int n1=2*l1+1, n2=2*l2+1, n3=2*l3+1, ntot=n1*n2*n3;
  if(t==0){
    fill_qmat(l1,q1); fill_qmat(l2,q2); fill_qmat(l3,q3);
    for(int i=0;i<49;i++) q3[i].y = -q3[i].y;   // conj
  }
  __syncthreads();
  for(int idx=t; idx<ntot; idx+=128){
    int a = idx/(n2*n3), r=idx%(n2*n3), b=r/n3, c=r%n3;
    C[idx] = su2_cg(l1,l2,l3, a-l1, b-l2, c-l3);
  }
  __syncthreads();
  for(int idx=t; idx<ntot; idx+=128){
    int i = idx/(n2*n3), r=idx%(n2*n3), j=r/n3, k=r%n3;
    double ar=0.0;
    for(int a=0;a<n1;a++) for(int b=0;b<n2;b++){
      double2 qa=q1[a*7+i], qb=q2[b*7+j];
      double pr = qa.x*qb.x - qa.y*qb.y;
      double pi = qa.x*qb.y + qa.y*qb.x;
      for(int c=0;c<n3;c++){
        double2 qc=q3[c*7+k];
        double tr = pr*qc.x - pi*qc.y;
        ar += tr*C[(a*n2+b)*n3+c];
      }
    }
    Cr[idx]=ar;
  }
  __syncthreads();
  double ss=0.0;
  for(int idx=t; idx<ntot; idx+=128) ss += Cr[idx]*Cr[idx];
  red[t]=ss; __syncthreads();
  for(int st=64; st>0; st>>=1){ if(t<st) red[t]+=red[t+st]; __syncthreads(); }
  double inv = 1.0/sqrt(red[0]);
  for(int idx=t; idx<ntot; idx+=128) ws[gK_OFF[bid]+idx] = (float)(Cr[idx]*inv);
}

__device__ void do_c2c3(float* ws){
  const float* w112 = ws + O_W112;
  const float* w213 = ws + O_W213;
  double u0=0.3, u1=-0.4, u2=sqrt(0.75);
  double s3=sqrt(3.0);
  double y1[3]={s3*u0, s3*u1, s3*u2};
  double y2r[5]={0,0,0,0,0};
  for(int i=0;i<3;i++) for(int j=0;j<3;j++) for(int k=0;k<5;k++)
    y2r[k] += y1[i]*y1[j]*(double)w112[(i*3+j)*5+k];
  double nn=0; for(int k=0;k<5;k++) nn += y2r[k]*y2r[k];
  double c2 = sqrt(5.0)/sqrt(nn);
  double y2[5]; for(int k=0;k<5;k++) y2[k]=c2*y2r[k];
  double y3r[7]={0,0,0,0,0,0,0};
  for(int i=0;i<5;i++) for(int j=0;j<3;j++) for(int n=0;n<7;n++)
    y3r[n] += y2[i]*y1[j]*(double)w213[(i*3+j)*7+n];
  nn=0; for(int n=0;n<7;n++) nn += y3r[n]*y3r[n];
  double c3 = sqrt(7.0)/sqrt(nn);
  ws[678]=(float)c2; ws[679]=(float)c3;
}

__global__ void k_zero(int* __restrict__ cnt){
  int i = blockIdx.x*256 + threadIdx.x;
  if(i < N_NODES) cnt[i]=0;
}
__global__ void k_count(const int* __restrict__ senders, int* __restrict__ cnt){
  int e = blockIdx.x*256 + threadIdx.x;
  if(e < E_EDGES) atomicAdd(&cnt[senders[e]], 1);
}
__global__ __launch_bounds__(1024) void k_scan(const int* __restrict__ cnt, int* __restrict__ off, int* __restrict__ cur){
  __shared__ int part[1024];
  int t = threadIdx.x;
  int c0=cnt[4*t], c1=cnt[4*t+1], c2=cnt[4*t+2], c3=cnt[4*t+3];
  int l0=0, l1=c0, l2=c0+c1, l3=c0+c1+c2;
  int sum=l3+c3;
  part[t]=sum; __syncthreads();
  for(int st=1; st<1024; st<<=1){
    int v = part[t];
    int add = (t>=st)? part[t-st] : 0;
    __syncthreads();
    part[t] = v + add;
    __syncthreads();
  }
  int pref = (t>0)? part[t-1] : 0;
  off[4*t]=pref+l0; off[4*t+1]=pref+l1; off[4*t+2]=pref+l2; off[4*t+3]=pref+l3;
  cur[4*t]=pref+l0; cur[4*t+1]=pref+l1; cur[4*t+2]=pref+l2; cur[4*t+3]=pref+l3;
}
__global__ void k_scatter(const int* __restrict__ senders, int* __restrict__ cur, int* __restrict__ sorted){
  int e = blockIdx.x*256 + threadIdx.x;
  if(e < E_EDGES){
    int pos = atomicAdd(&cur[senders[e]], 1);
    sorted[pos] = e;
  }
}

// pack Ww (64x64) into bf16 hi/lo B-frags at WS_CUR (dead after k_scatter).
// block 4: computes C2/C3.
__global__ __launch_bounds__(256) void k_wwpack(const float* __restrict__ Ww, float* __restrict__ ws){
  if(blockIdx.x == 4){
    if(threadIdx.x == 0) do_c2c3(ws);
    return;
  }
  int idx = blockIdx.x*256 + threadIdx.x;   // 0..1023
  int lane = idx & 63, nt = (idx>>6)&3, ks = (idx>>8)&1, part = idx>>9;
  int c = nt*16 + (lane & 15);
  int g = lane >> 4;
  bf16x8 outv;
  #pragma unroll
  for(int j=0;j<8;j++){
    int k = ks*32 + g*8 + j;
    float v = Ww[k*64 + c];
    __bf16 hb = (__bf16)v;
    outv[j] = part ? (__bf16)(v - (float)hb) : hb;
  }
  ((bf16x8*)(ws + WS_CUR))[idx] = outv;
}

// pack Wl1/Wl2/W1/W2/W3 into bf16 hi/lo MFMA B-fragments.
__global__ __launch_bounds__(256) void k_wpack(
    const float* __restrict__ Wl1, const float* __restrict__ Wl2,
    const float* __restrict__ W1, const float* __restrict__ W2,
    const float* __restrict__ W3, float* __restrict__ wpk){
  int idx = blockIdx.x*256 + threadIdx.x;   // 64 blocks = 16384 frags
  int lane = idx & 63;
  const float* W; int part, ks, nt;
  if(idx < PK_W1){                       // Wl1/Wl2: [mp][ks10][nt][lane]
    nt = (idx>>6)&3; int rest = idx>>8; ks = rest%10; int mp = rest/10;
    part = mp&1; W = (mp>>1)? Wl2 : Wl1;
  } else if(idx < PK_W2){                // W1: [part][ks8][nt][lane]
    int rel = idx - PK_W1; part = rel>>11; int r2 = rel & 2047;
    ks = r2>>8; nt = (r2>>6)&3; W = W1;
  } else if(idx < PK_W3){                // W2: [part][ks2][nt][lane]
    int rel = idx - PK_W2; part = rel>>9; int r2 = rel & 511;
    ks = r2>>8; nt = (r2>>6)&3; W = W2;
  } else {                               // W3: [part][ks2][nt][lane]
    int rel = idx - PK_W3; part = rel>>9; int r2 = rel & 511;
    ks = r2>>8; nt = (r2>>6)&3; W = W3;
  }
  int c = nt*16 + (lane & 15);
  int g = lane >> 4;
  bf16x8 outv;
  #pragma unroll
  for(int j=0;j<8;j++){
    int k = ks*32 + g*8 + j;
    float v = W[k*64 + c];
    __bf16 hb = (__bf16)v;
    outv[j] = part ? (__bf16)(v - (float)hb) : hb;
  }
  ((bf16x8*)wpk)[idx] = outv;
}

__device__ inline void split1(float v, __bf16& h, __bf16& l){
  h = (__bf16)v;
  l = (__bf16)(v - (float)h);
}

// per edge: Y[16] spherical harmonics (nz-pruned einsums); w = x@Ww/8 on MFMA.
__global__ __launch_bounds__(256) void k_edge_pre(
    const float* __restrict__ vectors, const float* __restrict__ x,
    float* __restrict__ ws){
  int t = threadIdx.x;
  int wv = t >> 6, lane = t & 63;
  int e = blockIdx.x*4 + wv;
  const float* w112 = ws + O_W112;
  const float* w213 = ws + O_W213;
  float C2v = ws[678], C3v = ws[679];
  float v0=vectors[e*3], v1=vectors[e*3+1], v2=vectors[e*3+2];
  float len = sqrtf(v0*v0+v1*v1+v2*v2);
  float inv = 1.0f/(len + 1e-12f);
  float s3 = 1.7320508075688772f;
  float y1v[3] = { s3*v0*inv, s3*v1*inv, s3*v2*inv };
  float y2[5];
  #pragma unroll
  for(int k=0;k<5;k++){
    float a=0.f;
    #pragma unroll
    for(int i=0;i<3;i++)
      #pragma unroll
      for(int j=0;j<3;j++) if(nz(1,1,2,i,j,k)) a += y1v[i]*y1v[j]*w112[(i*3+j)*5+k];
    y2[k]=C2v*a;
  }
  float y3[7];
  #pragma unroll
  for(int n=0;n<7;n++){
    float a=0.f;
    #pragma unroll
    for(int i=0;i<5;i++)
      #pragma unroll
      for(int j=0;j<3;j++) if(nz(2,1,3,i,j,n)) a += y2[i]*y1v[j]*w213[(i*3+j)*7+n];
    y3[n]=C3v*a;
  }
  // w = x@Ww/8 via MFMA (3-term bf16 hi/lo split)
  {
    int g = lane >> 4, r = lane & 15, he = r & 3;
    const float* xrow = x + (blockIdx.x*4 + he)*64;
    const bf16x8* WWP = (const bf16x8*)(ws + WS_CUR);  // [part][ks][nt][lane]
    f32x4 acc = {0.f,0.f,0.f,0.f};
    #pragma unroll
    for(int ks=0; ks<2; ks++){
      const float* xp = xrow + ks*32 + g*8;
      bf16x8 ah, al;
      #pragma unroll
      for(int j=0;j<8;j++){
        __bf16 h,l; split1(xp[j],h,l);
        ah[j]=h; al[j]=l;
      }
      bf16x8 bh = WWP[      ks*256 + wv*64 + lane];
      bf16x8 bl = WWP[512 + ks*256 + wv*64 + lane];
      acc = __builtin_amdgcn_mfma_f32_16x16x32_bf16(ah, bh, acc, 0,0,0);
      acc = __builtin_amdgcn_mfma_f32_16x16x32_bf16(ah, bl, acc, 0,0,0);
      acc = __builtin_amdgcn_mfma_f32_16x16x32_bf16(al, bh, acc, 0,0,0);
    }
    if(g==0){
      #pragma unroll
      for(int reg=0; reg<4; reg++)
        ws[WS_W + (blockIdx.x*4+reg)*64 + wv*16 + r] = acc[reg]*0.125f;
    }
  }
  if(lane==0){
    float* Yp = ws + WS_Y + e*16;
    Yp[0]=1.0f;
    Yp[1]=y1v[0]; Yp[2]=y1v[1]; Yp[3]=y1v[2];
    Yp[4]=y2[0]; Yp[5]=y2[1]; Yp[6]=y2[2]; Yp[7]=y2[3]; Yp[8]=y2[4];
    Yp[9]=y3[0]; Yp[10]=y3[1]; Yp[11]=y3[2]; Yp[12]=y3[3]; Yp[13]=y3[4]; Yp[15]=y3[6]; Yp[14]=y3[5];
  }
}

// per node: A[n][m][k] = eps * sum_e w[e][m]*Y[e][k]
__global__ __launch_bounds__(64) void k_node_acc(
    const float* __restrict__ ws_w, const float* __restrict__ ws_y,
    const int* __restrict__ sorted, const int* __restrict__ off, const int* __restrict__ cnt,
    float* __restrict__ A){
  int n = blockIdx.x, m = threadIdx.x;
  float acc[16];
  #pragma unroll
  for(int k=0;k<16;k++) acc[k]=0.f;
  int o = off[n], c = cnt[n];
  if(c > 0){
    int e = sorted[o];
    for(int j=0;j<c;j++){
      int e_nx = (j+1<c) ? sorted[o+j+1] : 0;
      float wm = ws_w[e*64+m];
      const float4* Yp4 = (const float4*)(ws_y + e*16);
      float4 y0=Yp4[0], y1=Yp4[1], y2=Yp4[2], y3=Yp4[3];
      acc[0] += wm*y0.x; acc[1] += wm*y0.y; acc[2] += wm*y0.z; acc[3] += wm*y0.w;
      acc[4] += wm*y1.x; acc[5] += wm*y1.y; acc[6] += wm*y1.z; acc[7] += wm*y1.w;
      acc[8] += wm*y2.x; acc[9] += wm*y2.y; acc[10]+= wm*y2.z; acc[11]+= wm*y2.w;
      acc[12]+= wm*y3.x; acc[13]+= wm*y3.y; acc[14]+= wm*y3.z; acc[15]+= wm*y3.w;
      e = e_nx;
    }
  }
  float4* outp = (float4*)(A + n*1024 + m*16);
  outp[0] = make_float4(acc[0]*0.25f, acc[1]*0.25f, acc[2]*0.25f, acc[3]*0.25f);
  outp[1] = make_float4(acc[4]*0.25f, acc[5]*0.25f, acc[6]*0.25f, acc[7]*0.25f);
  outp[2] = make_float4(acc[8]*0.25f, acc[9]*0.25f, acc[10]*0.25f, acc[11]*0.25f);
  outp[3] = make_float4(acc[12]*0.25f, acc[13]*0.25f, acc[14]*0.25f, acc[15]*0.25f);
}

// main fused kernel. TP loops nz-pruned (~700 -> ~330 FMA/thread); only the
// pd barrier + 2 MLP barriers remain (eid/env consumed after pd barrier).
__global__ __launch_bounds__(256, 3) void k_main(
    const float* __restrict__ vectors, const float* __restrict__ x, const float* __restrict__ V,
    const int* __restrict__ senders,
    const float* __restrict__ ws, const int* __restrict__ sorted,
    float* __restrict__ out){
  __shared__ __align__(16) __bf16 lds_pdh[32*328];   // 20992 B
  __shared__ __align__(16) __bf16 lds_pdl[32*328];   // 20992 B
  __shared__ __align__(16) __bf16 lds_hh[4*264];     // 2112 B  h=[x|S] hi
  __shared__ __align__(16) __bf16 lds_hl[4*264];     // 2112 B  lo
  __shared__ __align__(16) __bf16 lds_h1h[4*72];     // 576 B
  __shared__ __align__(16) __bf16 lds_h1l[4*72];
  __shared__ __align__(16) __bf16 lds_h2h[4*72];
  __shared__ __align__(16) __bf16 lds_h2l[4*72];
  __shared__ float lds_env[4];
  __shared__ int   lds_eid[4];

  int t = threadIdx.x;
  int wv = t>>6, lane = t&63;
  int eid = sorted[blockIdx.x*4 + wv];
  if(lane==0) lds_eid[wv]=eid;
  // no barrier here: lds_eid/lds_env consumed only after the pd barrier

  const float* lw = ws;   // w3j via SMEM (compile-time offsets, uniform)
  // ---- phase 1: per-edge (one wave per edge) ----
  {
    float v0=vectors[eid*3], v1=vectors[eid*3+1], v2=vectors[eid*3+2];
    float d = sqrtf(v0*v0+v1*v1+v2*v2);
    float d2=d*d, d4=d2*d2, d6=d4*d2, d7=d6*d, d8=d7*d;
    float env = 1.0f - 28.0f*d6 + 48.0f*d7 - 21.0f*d8;
    env = (d < 1.0f) ? env : 0.0f;
    if(lane==0) lds_env[wv]=env;
  }
  int snd = senders[eid];
  const float4* Ap4 = (const float4*)(ws + WS_A + snd*1024 + lane*16);
  float4 a0=Ap4[0], a1=Ap4[1], a2=Ap4[2], a3=Ap4[3];
  float wY[16] = {a0.x,a0.y,a0.z,a0.w, a1.x,a1.y,a1.z,a1.w,
                  a2.x,a2.y,a2.z,a2.w, a3.x,a3.y,a3.z,a3.w};
  const float* Vp = V + eid*576;
  float V0 = Vp[lane];
  float V1f[3], V2f[5];
  #pragma unroll
  for(int i=0;i<3;i++) V1f[i]=Vp[64+lane*3+i];
  #pragma unroll
  for(int j=0;j<5;j++) V2f[j]=Vp[256+lane*5+j];
  // h = [x | S] stored bf16 hi/lo
  {
    __bf16 hh, hl;
    split1(x[eid*64+lane], hh, hl);
    lds_hh[wv*264 + lane] = hh; lds_hl[wv*264 + lane] = hl;
  }
  // scalar channel S (nz-pruned: w110/w220 are diagonal)
  float s0 = wY[0]*V0*lw[O_W000];
  float s1 = 0.f;
  #pragma unroll
  for(int i=0;i<3;i++)
    #pragma unroll
    for(int j=0;j<3;j++) if(nz(1,1,0,i,j,0)) s1 += wY[1+i]*V1f[j]*lw[O_W110 + i*3+j];
  float s2 = 0.f;
  #pragma unroll
  for(int i=0;i<5;i++)
    #pragma unroll
    for(int j=0;j<5;j++) if(nz(2,2,0,i,j,0)) s2 += wY[4+i]*V2f[j]*lw[O_W220 + i*5+j];
  {
    __bf16 hh, hl;
    split1(s0, hh, hl); lds_hh[wv*264+ 64+lane]=hh; lds_hl[wv*264+ 64+lane]=hl;
    split1(s1, hh, hl); lds_hh[wv*264+128+lane]=hh; lds_hl[wv*264+128+lane]=hl;
    split1(s2, hh, hl); lds_hh[wv*264+192+lane]=hh; lds_hl[wv*264+192+lane]=hl;
  }
  // P paths (l3=1), D paths (l3=2) — all nz-pruned
  float P0[3]={0,0,0}, P1[3]={0,0,0}, P2[3]={0,0,0}, P3[3]={0,0,0}, P4[3]={0,0,0};
  float D0[5]={0,0,0,0,0}, D1[5]={0,0,0,0,0}, D2[5]={0,0,0,0,0}, D3[5]={0,0,0,0,0}, D4[5]={0,0,0,0,0};
  #pragma unroll
  for(int b=0;b<3;b++){ float pb=wY[0]*V1f[b];
    #pragma unroll
    for(int i=0;i<3;i++) if(nz(0,1,1,0,b,i)) P0[i]+= pb*lw[O_W011 + b*3+i]; }
  #pragma unroll
  for(int a=0;a<3;a++){ float pa=wY[1+a]*V0;
    #pragma unroll
    for(int i=0;i<3;i++) if(nz(1,0,1,a,0,i)) P1[i]+= pa*lw[O_W101 + a*3+i]; }
  #pragma unroll
  for(int a=0;a<3;a++)
    #pragma unroll
    for(int b=0;b<5;b++){ float p=wY[1+a]*V2f[b];
      #pragma unroll
      for(int i=0;i<3;i++) if(nz(1,2,1,a,b,i)) P2[i]+= p*lw[O_W121 + (a*5+b)*3+i]; }
  #pragma unroll
  for(int a=0;a<5;a++)
    #pragma unroll
    for(int b=0;b<3;b++){ float p=wY[4+a]*V1f[b];
      #pragma unroll
      for(int i=0;i<3;i++) if(nz(2,1,1,a,b,i)) P3[i]+= p*lw[O_W211 + (a*3+b)*3+i]; }
  #pragma unroll
  for(int a=0;a<7;a++)
    #pragma unroll
    for(int b=0;b<5;b++){ float p=wY[9+a]*V2f[b];
      #pragma unroll
      for(int i=0;i<3;i++) if(nz(3,2,1,a,b,i)) P4[i]+= p*lw[O_W321 + (a*5+b)*3+i]; }
  #pragma unroll
  for(int b=0;b<5;b++){ float pb=wY[0]*V2f[b];
    #pragma unroll
    for(int j=0;j<5;j++) if(nz(0,2,2,0,b,j)) D0[j]+= pb*lw[O_W022 + b*5+j]; }
  #pragma unroll
  for(int a=0;a<3;a++)
    #pragma unroll
    for(int b=0;b<3;b++){ float p=wY[1+a]*V1f[b];
      #pragma unroll
      for(int j=0;j<5;j++) if(nz(1,1,2,a,b,j)) D1[j]+= p*lw[O_W112 + (a*3+b)*5+j]; }
  #pragma unroll
  for(int a=0;a<5;a++){ float pa=wY[4+a]*V0;
    #pragma unroll
    for(int j=0;j<5;j++) if(nz(2,0,2,a,0,j)) D2[j]+= pa*lw[O_W202 + a*5+j]; }
  #pragma unroll
  for(int a=0;a<5;a++)
    #pragma unroll
    for(int b=0;b<5;b++){ float p=wY[4+a]*V2f[b];
      #pragma unroll
      for(int j=0;j<5;j++) if(nz(2,2,2,a,b,j)) D3[j]+= p*lw[O_W222 + (a*5+b)*5+j]; }
  #pragma unroll
  for(int a=0;a<7;a++)
    #pragma unroll
    for(int b=0;b<3;b++){ float p=wY[9+a]*V1f[b];
      #pragma unroll
      for(int j=0;j<5;j++) if(nz(3,1,2,a,b,j)) D4[j]+= p*lw[O_W312 + (a*3+b)*5+j]; }
  // stage into lds_pd hi/lo (fold sqrt(2*l3+1)); lane stride-1 writes.
  {
    const float SQ3 = 1.7320508075688772f, SQ5 = 2.2360679774997896f;
    #pragma unroll
    for(int i=0;i<3;i++){
      int row = wv*3+i;
      float vals[5] = {SQ3*P0[i], SQ3*P1[i], SQ3*P2[i], SQ3*P3[i], SQ3*P4[i]};
      #pragma unroll
      for(int p=0;p<5;p++){
        __bf16 h,l; split1(vals[p],h,l);
        lds_pdh[row*328 + p*64 + lane] = h;
        lds_pdl[row*328 + p*64 + lane] = l;
      }
    }
    #pragma unroll
    for(int j=0;j<5;j++){
      int row = 12 + wv*5 + j;
      float vals[5] = {SQ5*D0[j], SQ5*D1[j], SQ5*D2[j], SQ5*D3[j], SQ5*D4[j]};
      #pragma unroll
      for(int p=0;p<5;p++){
        __bf16 h,l; split1(vals[p],h,l);
        lds_pdh[row*328 + p*64 + lane] = h;
        lds_pdl[row*328 + p*64 + lane] = l;
      }
    }
  }
  __syncthreads();

  int g = lane >> 4, r = lane & 15;
  const bf16x8* WB = (const bf16x8*)(ws + WS_W);

  // ---- MLP on MFMA (A rows = edge, duplicated mod 4; reg = edge in C) ----
  {
    int he = r & 3;
    f32x4 acc = {0.f,0.f,0.f,0.f};
    #pragma unroll
    for(int ks=0; ks<8; ks++){
      bf16x8 ah = *(const bf16x8*)(lds_hh + he*264 + ks*32 + g*8);
      bf16x8 al = *(const bf16x8*)(lds_hl + he*264 + ks*32 + g*8);
      bf16x8 bh = WB[PK_W1        + (ks*4+wv)*64 + lane];
      bf16x8 bl = WB[PK_W1 + 2048 + (ks*4+wv)*64 + lane];
      acc = __builtin_amdgcn_mfma_f32_16x16x32_bf16(ah, bh, acc, 0,0,0);
      acc = __builtin_amdgcn_mfma_f32_16x16x32_bf16(ah, bl, acc, 0,0,0);
      acc = __builtin_amdgcn_mfma_f32_16x16x32_bf16(al, bh, acc, 0,0,0);
    }
    if(g==0){
      #pragma unroll
      for(int e_=0;e_<4;e_++){
        float a = acc[e_]*(1.0f/16.0f);
        float h1 = a/(1.0f+__expf(-a));
        __bf16 hh,hl; split1(h1,hh,hl);
        lds_h1h[e_*72 + wv*16 + r] = hh;
        lds_h1l[e_*72 + wv*16 + r] = hl;
      }
    }
    __syncthreads();
    acc = (f32x4){0.f,0.f,0.f,0.f};
    #pragma unroll
    for(int ks=0; ks<2; ks++){
      bf16x8 ah = *(const bf16x8*)(lds_h1h + he*72 + ks*32 + g*8);
      bf16x8 al = *(const bf16x8*)(lds_h1l + he*72 + ks*32 + g*8);
      bf16x8 bh = WB[PK_W2       + (ks*4+wv)*64 + lane];
      bf16x8 bl = WB[PK_W2 + 512 + (ks*4+wv)*64 + lane];
      acc = __builtin_amdgcn_mfma_f32_16x16x32_bf16(ah, bh, acc, 0,0,0);
      acc = __builtin_amdgcn_mfma_f32_16x16x32_bf16(ah, bl, acc, 0,0,0);
      acc = __builtin_amdgcn_mfma_f32_16x16x32_bf16(al, bh, acc, 0,0,0);
    }
    if(g==0){
      #pragma unroll
      for(int e_=0;e_<4;e_++){
        float a = acc[e_]*0.125f;
        float h2 = a/(1.0f+__expf(-a));
        __bf16 hh,hl; split1(h2,hh,hl);
        lds_h2h[e_*72 + wv*16 + r] = hh;
        lds_h2l[e_*72 + wv*16 + r] = hl;
      }
    }
    __syncthreads();
    acc = (f32x4){0.f,0.f,0.f,0.f};
    #pragma unroll
    for(int ks=0; ks<2; ks++){
      bf16x8 ah = *(const bf16x8*)(lds_h2h + he*72 + ks*32 + g*8);
      bf16x8 al = *(const bf16x8*)(lds_h2l + he*72 + ks*32 + g*8);
      bf16x8 bh = WB[PK_W3       + (ks*4+wv)*64 + lane];
      bf16x8 bl = WB[PK_W3 + 512 + (ks*4+wv)*64 + lane];
      acc = __builtin_amdgcn_mfma_f32_16x16x32_bf16(ah, bh, acc, 0,0,0);
      acc = __builtin_amdgcn_mfma_f32_16x16x32_bf16(ah, bl, acc, 0,0,0);
      acc = __builtin_amdgcn_mfma_f32_16x16x32_bf16(al, bh, acc, 0,0,0);
    }
    if(g==0){
      #pragma unroll
      for(int e_=0;e_<4;e_++)
        out[lds_eid[e_]*576 + wv*16 + r] = lds_env[e_]*acc[e_]*0.125f;
    }
  }

  // ---- phase 2: MFMA projections. wave = N-tile (nt = wv), 16 u-cols each.
  {
    f32x4 accP  = {0.f,0.f,0.f,0.f};
    f32x4 accD0 = {0.f,0.f,0.f,0.f};
    f32x4 accD1 = {0.f,0.f,0.f,0.f};
    int rP  = (r < 12) ? r : 11;          // clamp: C rows 12-15 discarded
    int rD0 = 12 + r;                     // D rows 0..15
    int rD1 = 12 + ((r < 4) ? (16 + r) : 19);  // D rows 16..19; rest clamped
    const __bf16* pPh  = lds_pdh + rP *328 + g*8;
    const __bf16* pPl  = lds_pdl + rP *328 + g*8;
    const __bf16* pD0h = lds_pdh + rD0*328 + g*8;
    const __bf16* pD0l = lds_pdl + rD0*328 + g*8;
    const __bf16* pD1h = lds_pdh + rD1*328 + g*8;
    const __bf16* pD1l = lds_pdl + rD1*328 + g*8;
    #pragma unroll 2
    for(int ks=0; ks<10; ks++){
      int bbase = (ks*4 + wv)*64 + lane;
      bf16x8 b1h = WB[bbase];             // Wl1 hi
      bf16x8 b1l = WB[bbase + 2560];      // Wl1 lo
      bf16x8 b2h = WB[bbase + 5120];      // Wl2 hi
      bf16x8 b2l = WB[bbase + 7680];      // Wl2 lo
      bf16x8 aPh  = *(const bf16x8*)(pPh  + ks*32);
      bf16x8 aPl  = *(const bf16x8*)(pPl  + ks*32);
      bf16x8 aD0h = *(const bf16x8*)(pD0h + ks*32);
      bf16x8 aD0l = *(const bf16x8*)(pD0l + ks*32);
      bf16x8 aD1h = *(const bf16x8*)(pD1h + ks*32);
      bf16x8 aD1l = *(const bf16x8*)(pD1l + ks*32);
      accP  = __builtin_amdgcn_mfma_f32_16x16x32_bf16(aPh,  b1h, accP,  0,0,0);
      accP  = __builtin_amdgcn_mfma_f32_16x16x32_bf16(aPh,  b1l, accP,  0,0,0);
      accP  = __builtin_amdgcn_mfma_f32_16x16x32_bf16(aPl,  b1h, accP,  0,0,0);
      accD0 = __builtin_amdgcn_mfma_f32_16x16x32_bf16(aD0h, b2h, accD0, 0,0,0);
      accD0 = __builtin_amdgcn_mfma_f32_16x16x32_bf16(aD0h, b2l, accD0, 0,0,0);
      accD0 = __builtin_amdgcn_mfma_f32_16x16x32_bf16(aD0l, b2h, accD0, 0,0,0);
      accD1 = __builtin_amdgcn_mfma_f32_16x16x32_bf16(aD1h, b2h, accD1, 0,0,0);
      accD1 = __builtin_amdgcn_mfma_f32_16x16x32_bf16(aD1h, b2l, accD1, 0,0,0);
      accD1 = __builtin_amdgcn_mfma_f32_16x16x32_bf16(aD1l, b2h, accD1, 0,0,0);
    }
    // C layout (m89-verified): col = lane&15, row = (lane>>4)*4 + reg
    const float sc = 0.05590169943749474f;  // 1/sqrt(320)
    int u = wv*16 + r;
    if(g < 3){
      #pragma unroll
      for(int reg=0; reg<4; reg++){
        int R = g*4 + reg;                 // 0..11 : P row = e*3 + i
        int e_ = R/3, i_ = R - e_*3;
        out[lds_eid[e_]*576 + 64 + u*3 + i_] = accP[reg]*sc;
      }
    }
    #pragma unroll
    for(int reg=0; reg<4; reg++){
      int Dr = g*4 + reg;                  // 0..15 : D row = e*5 + j
      int e_ = Dr/5, j_ = Dr - e_*5;
      out[lds_eid[e_]*576 + 256 + u*5 + j_] = accD0[reg]*sc;
    }
    if(g == 0){
      #pragma unroll
      for(int reg=0; reg<4; reg++){
        int Dr = 16 + reg;                 // 16..19 -> e=3, j=1..4
        int e_ = Dr/5, j_ = Dr - e_*5;
        out[lds_eid[e_]*576 + 256 + u*5 + j_] = accD1[reg]*sc;
      }
    }
  }
}

extern "C" void kernel_launch(void* const* d_in, const int* in_sizes, int n_in,
                              void* d_out, int out_size, void* d_ws, size_t ws_size,
                              hipStream_t stream) {
  const float* vectors=(const float*)d_in[0];
  const float* x      =(const float*)d_in[1];
  const float* V      =(const float*)d_in[2];
  const int*   senders=(const int*)  d_in[3];
  const float* Ww     =(const float*)d_in[4];
  const float* W1     =(const float*)d_in[5];
  const float* W2     =(const float*)d_in[6];
  const float* W3     =(const float*)d_in[7];
  const float* Wl1    =(const float*)d_in[8];
  const float* Wl2    =(const float*)d_in[9];
  float* ws  = (float*)d_ws;
  float* out = (float*)d_out;
  int* cnt    = (int*)(ws + WS_CNT);
  int* off    = (int*)(ws + WS_OFF);
  int* cur    = (int*)(ws + WS_CUR);
  int* sorted = (int*)(ws + WS_SORT);

  k_w3j   <<<14, 128, 0, stream>>>(ws);
  k_zero  <<<16, 256, 0, stream>>>(cnt);
  k_count <<<E_EDGES/256, 256, 0, stream>>>(senders, cnt);
  k_scan  <<<1, 1024, 0, stream>>>(cnt, off, cur);
  k_scatter<<<E_EDGES/256, 256, 0, stream>>>(senders, cur, sorted);
  // packs Ww frags into WS_CUR (dead after scatter) + computes C2/C3 (block 4)
  k_wwpack<<<5, 256, 0, stream>>>(Ww, ws);
  k_edge_pre<<<E_EDGES/4, 256, 0, stream>>>(vectors, x, ws);
  k_node_acc<<<N_NODES, 64, 0, stream>>>(ws + WS_W, ws + WS_Y, sorted, off, cnt, ws + WS_A);
  // pack AFTER k_node_acc (reuses the then-dead WS_W region)
  k_wpack <<<64, 256, 0, stream>>>(Wl1, Wl2, W1, W2, W3, ws + WS_W);
  k_main  <<<E_EDGES/4, 256, 0, stream>>>(vectors, x, V, senders,
                                          ws, sorted, out);
}